// Round 2
// baseline (4766.114 us; speedup 1.0000x reference)
//
#include <hip/hip_runtime.h>
#include <math.h>

#define BATCH 2
#define TT 16
#define SEQ 4096      // T*H*W = 16*16*16
#define CIN 256
#define KCH 16
#define VCH 128
#define CPE 262

__device__ __forceinline__ float elu_f(float x) {
    return x > 0.0f ? x : (expf(x) - 1.0f);
}

// =================== conv1: o1 = elu(conv2x2x2(elu(res)) + b1) ===================
// grid: (32 slabs [b,t], 4 co-tiles of 64), 256 threads
__global__ __launch_bounds__(256) void conv1_kernel(
    const float* __restrict__ res, const float* __restrict__ w1,
    const float* __restrict__ b1, float* __restrict__ o1)
{
    __shared__ float s_in[8][2][17][17];  // [ci][kd][1+h][1+w], zero border at h=0/w=0
    __shared__ float s_w[64][8][8];       // [co_local][ci][tap]
    const int slab = blockIdx.x;
    const int b = slab >> 4, t = slab & 15;
    const int co_base = blockIdx.y * 64;
    const int tid = threadIdx.x;

    // zero whole padded input buffer once (borders stay zero)
    for (int idx = tid; idx < 8 * 2 * 17 * 17; idx += 256)
        ((float*)s_in)[idx] = 0.0f;
    __syncthreads();

    float acc[4][16];
#pragma unroll
    for (int k = 0; k < 4; ++k)
#pragma unroll
        for (int c = 0; c < 16; ++c) acc[k][c] = 0.0f;

    const int pid = tid & 63;
    const int cg = tid >> 6;

    for (int ci0 = 0; ci0 < CIN; ci0 += 8) {
        // stage elu(input) interior
        for (int idx = tid; idx < 8 * 2 * 256; idx += 256) {
            int ci = idx >> 9;
            int kd = (idx >> 8) & 1;
            int p  = idx & 255;
            int tt = t - 1 + kd;
            float v = 0.0f;
            if (tt >= 0) {
                v = res[((b * CIN + ci0 + ci) * TT + tt) * 256 + p];
                v = elu_f(v);
            }
            s_in[ci][kd][(p >> 4) + 1][(p & 15) + 1] = v;
        }
        // stage weights
        for (int idx = tid; idx < 64 * 8 * 8; idx += 256) {
            int co_l = idx >> 6;
            int ci   = (idx >> 3) & 7;
            int tap  = idx & 7;
            s_w[co_l][ci][tap] = w1[((co_base + co_l) * CIN + ci0 + ci) * 8 + tap];
        }
        __syncthreads();

        for (int ci = 0; ci < 8; ++ci) {
            float vals[4][8];
#pragma unroll
            for (int k = 0; k < 4; ++k) {
                int p = pid + 64 * k;
                int h = p >> 4, w = p & 15;
#pragma unroll
                for (int kd = 0; kd < 2; ++kd)
#pragma unroll
                for (int kh = 0; kh < 2; ++kh)
#pragma unroll
                for (int kw = 0; kw < 2; ++kw)
                    vals[k][kd * 4 + kh * 2 + kw] = s_in[ci][kd][h + kh][w + kw];
            }
#pragma unroll
            for (int cc = 0; cc < 16; ++cc) {
                float wr[8];
#pragma unroll
                for (int tap = 0; tap < 8; ++tap)
                    wr[tap] = s_w[cg * 16 + cc][ci][tap];
#pragma unroll
                for (int k = 0; k < 4; ++k) {
                    float s = acc[k][cc];
#pragma unroll
                    for (int tap = 0; tap < 8; ++tap)
                        s = fmaf(vals[k][tap], wr[tap], s);
                    acc[k][cc] = s;
                }
            }
        }
        __syncthreads();
    }

#pragma unroll
    for (int cc = 0; cc < 16; ++cc) {
        int co = co_base + cg * 16 + cc;
        float bias = b1[co];
#pragma unroll
        for (int k = 0; k < 4; ++k) {
            int p = pid + 64 * k;
            o1[((b * CIN + co) * TT + t) * 256 + p] = elu_f(acc[k][cc] + bias);
        }
    }
}

// ========= conv2 + gate: res += a*sigmoid(g), [a;g] = conv2x2x2(o1) + b2 =========
// grid: (32 slabs, 8 co-tiles of 32 pairs), 256 threads
__global__ __launch_bounds__(256) void conv2_kernel(
    const float* __restrict__ o1, const float* __restrict__ w2,
    const float* __restrict__ b2, float* __restrict__ res)
{
    __shared__ float s_in[8][2][17][17];
    __shared__ float s_w[32][2][8][8];  // [pair][a/g][ci][tap]
    const int slab = blockIdx.x;
    const int b = slab >> 4, t = slab & 15;
    const int co_base = blockIdx.y * 32;
    const int tid = threadIdx.x;

    for (int idx = tid; idx < 8 * 2 * 17 * 17; idx += 256)
        ((float*)s_in)[idx] = 0.0f;
    __syncthreads();

    float acc_a[4][8], acc_g[4][8];
#pragma unroll
    for (int k = 0; k < 4; ++k)
#pragma unroll
        for (int c = 0; c < 8; ++c) { acc_a[k][c] = 0.0f; acc_g[k][c] = 0.0f; }

    const int pid = tid & 63;
    const int cg = tid >> 6;

    for (int ci0 = 0; ci0 < CIN; ci0 += 8) {
        for (int idx = tid; idx < 8 * 2 * 256; idx += 256) {
            int ci = idx >> 9;
            int kd = (idx >> 8) & 1;
            int p  = idx & 255;
            int tt = t - 1 + kd;
            float v = 0.0f;
            if (tt >= 0)
                v = o1[((b * CIN + ci0 + ci) * TT + tt) * 256 + p];
            s_in[ci][kd][(p >> 4) + 1][(p & 15) + 1] = v;
        }
        for (int idx = tid; idx < 32 * 2 * 8 * 8; idx += 256) {
            int pair = idx >> 7;
            int ag   = (idx >> 6) & 1;
            int ci   = (idx >> 3) & 7;
            int tap  = idx & 7;
            int row = co_base + pair + ag * 256;
            s_w[pair][ag][ci][tap] = w2[(row * CIN + ci0 + ci) * 8 + tap];
        }
        __syncthreads();

        for (int ci = 0; ci < 8; ++ci) {
            float vals[4][8];
#pragma unroll
            for (int k = 0; k < 4; ++k) {
                int p = pid + 64 * k;
                int h = p >> 4, w = p & 15;
#pragma unroll
                for (int kd = 0; kd < 2; ++kd)
#pragma unroll
                for (int kh = 0; kh < 2; ++kh)
#pragma unroll
                for (int kw = 0; kw < 2; ++kw)
                    vals[k][kd * 4 + kh * 2 + kw] = s_in[ci][kd][h + kh][w + kw];
            }
#pragma unroll
            for (int cc = 0; cc < 8; ++cc) {
                float wa[8], wg[8];
#pragma unroll
                for (int tap = 0; tap < 8; ++tap) {
                    wa[tap] = s_w[cg * 8 + cc][0][ci][tap];
                    wg[tap] = s_w[cg * 8 + cc][1][ci][tap];
                }
#pragma unroll
                for (int k = 0; k < 4; ++k) {
                    float sa = acc_a[k][cc], sg = acc_g[k][cc];
#pragma unroll
                    for (int tap = 0; tap < 8; ++tap) {
                        sa = fmaf(vals[k][tap], wa[tap], sa);
                        sg = fmaf(vals[k][tap], wg[tap], sg);
                    }
                    acc_a[k][cc] = sa; acc_g[k][cc] = sg;
                }
            }
        }
        __syncthreads();
    }

#pragma unroll
    for (int cc = 0; cc < 8; ++cc) {
        int co = co_base + cg * 8 + cc;
        float ba = b2[co];
        float bg = b2[co + 256];
#pragma unroll
        for (int k = 0; k < 4; ++k) {
            int p = pid + 64 * k;
            float a = acc_a[k][cc] + ba;
            float g = acc_g[k][cc] + bg;
            float sig = 1.0f / (1.0f + expf(-g));
            int idx = ((b * CIN + co) * TT + t) * 256 + p;
            res[idx] = res[idx] + a * sig;
        }
    }
}

// ================= qkv: per-position linear on 262 features =================
// grid: B*160*16 blocks, 256 threads (thread = one position)
__global__ __launch_bounds__(256) void qkv_kernel(
    const float* __restrict__ res, const float* __restrict__ orig,
    const float* __restrict__ qw, const float* __restrict__ qb,
    const float* __restrict__ kw, const float* __restrict__ kb,
    const float* __restrict__ vw, const float* __restrict__ vb,
    float* __restrict__ q, float* __restrict__ k_t, float* __restrict__ v)
{
    int bx = blockIdx.x;
    int b = bx / 2560;
    int oc = (bx >> 4) % 160;
    int chunk = bx & 15;
    int s = chunk * 256 + threadIdx.x;

    const float* wrow;
    float bias;
    if (oc < 16)      { wrow = qw + oc * CPE;        bias = qb[oc]; }
    else if (oc < 32) { wrow = kw + (oc - 16) * CPE; bias = kb[oc - 16]; }
    else              { wrow = vw + (oc - 32) * CPE; bias = vb[oc - 32]; }

    float acc = bias;
    const float* rp = res + (size_t)b * CIN * SEQ + s;
    for (int c = 0; c < CIN; ++c)
        acc = fmaf(wrow[c], rp[c * SEQ], acc);
    const float* op = orig + (size_t)b * 3 * SEQ + s;
#pragma unroll
    for (int c = 0; c < 3; ++c)
        acc = fmaf(wrow[256 + c], op[c * SEQ], acc);
    float zt = -0.5f + (float)(s >> 8) * 0.0625f;
    float zh = -0.5f + (float)((s >> 4) & 15) * 0.0625f;
    float zw = -0.5f + (float)(s & 15) * 0.0625f;
    acc = fmaf(wrow[259], zt, acc);
    acc = fmaf(wrow[260], zh, acc);
    acc = fmaf(wrow[261], zw, acc);

    if (oc < 16)      q[((size_t)b * SEQ + s) * KCH + oc] = acc;
    else if (oc < 32) k_t[((size_t)b * KCH + (oc - 16)) * SEQ + s] = acc;
    else              v[((size_t)b * SEQ + s) * VCH + (oc - 32)] = acc;
}

// =============== attention: one block per (b, query row), exact softmax ===============
// writes elu(att) transposed: att_e[(b*VCH+c)*SEQ + qi]
__global__ __launch_bounds__(256) void attn_kernel(
    const float* __restrict__ q, const float* __restrict__ k_t,
    const float* __restrict__ v, float* __restrict__ att_e)
{
    __shared__ float sc[SEQ];
    __shared__ float qv[KCH];
    __shared__ float red_m[4];
    __shared__ float red_l[4];
    __shared__ float part[256];

    const int b = blockIdx.x >> 12;
    const int qi = blockIdx.x & 4095;
    const int tid = threadIdx.x;

    if (tid < KCH) qv[tid] = q[((size_t)b * SEQ + qi) * KCH + tid];
    __syncthreads();

    const float scale = 1.0f / sqrtf(259.0f);

    for (int j = tid; j < qi; j += 256) {
        float s = 0.0f;
#pragma unroll
        for (int c = 0; c < KCH; ++c)
            s = fmaf(qv[c], k_t[((size_t)b * KCH + c) * SEQ + j], s);
        sc[j] = s * scale;
    }
    __syncthreads();

    // block max
    float m = -3.0e38f;
    for (int j = tid; j < qi; j += 256) m = fmaxf(m, sc[j]);
#pragma unroll
    for (int off = 32; off > 0; off >>= 1)
        m = fmaxf(m, __shfl_down(m, off, 64));
    if ((tid & 63) == 0) red_m[tid >> 6] = m;
    __syncthreads();
    float m_all = fmaxf(fmaxf(red_m[0], red_m[1]), fmaxf(red_m[2], red_m[3]));

    // exp + sum
    float l = 0.0f;
    for (int j = tid; j < qi; j += 256) {
        float e = expf(sc[j] - m_all);
        sc[j] = e;
        l += e;
    }
#pragma unroll
    for (int off = 32; off > 0; off >>= 1)
        l += __shfl_down(l, off, 64);
    if ((tid & 63) == 0) red_l[tid >> 6] = l;
    __syncthreads();
    float l_all = red_l[0] + red_l[1] + red_l[2] + red_l[3];

    // PV
    const int c = tid & 127, half = tid >> 7;
    float acc = 0.0f;
    for (int j = half; j < qi; j += 2)
        acc = fmaf(sc[j], v[((size_t)b * SEQ + j) * VCH + c], acc);
    part[tid] = acc;
    __syncthreads();
    if (half == 0) {
        float tot = part[tid] + part[tid + 128];
        float o = (qi > 0) ? (tot / l_all) : 0.0f;
        att_e[((size_t)b * VCH + c) * SEQ + qi] = elu_f(o);
    }
}

// ====================== elementwise elu ======================
__global__ __launch_bounds__(256) void elu_kernel(
    const float* __restrict__ in, float* __restrict__ out, int n)
{
    int i = blockIdx.x * 256 + threadIdx.x;
    if (i < n) out[i] = elu_f(in[i]);
}

// ======= final_ab: sum2 = elu( elu(attn_w@att_e+attn_b) + elu(resc_w@res_e+resc_b) ) =======
// grid: B*256*16 blocks, 256 threads (thread = one position)
__global__ __launch_bounds__(256) void final_ab_kernel(
    const float* __restrict__ att_e, const float* __restrict__ res_e,
    const float* __restrict__ attn_w, const float* __restrict__ attn_b,
    const float* __restrict__ resc_w, const float* __restrict__ resc_b,
    float* __restrict__ sum2)
{
    int bx = blockIdx.x;
    int b = bx >> 12;
    int co = (bx >> 4) & 255;
    int chunk = bx & 15;
    int s = chunk * 256 + threadIdx.x;

    float acc1 = attn_b[co];
    const float* w1r = attn_w + co * VCH;
    const float* ap = att_e + (size_t)b * VCH * SEQ + s;
    for (int c = 0; c < VCH; ++c)
        acc1 = fmaf(w1r[c], ap[c * SEQ], acc1);

    float acc2 = resc_b[co];
    const float* w2r = resc_w + co * CIN;
    const float* rp = res_e + (size_t)b * CIN * SEQ + s;
    for (int c = 0; c < CIN; ++c)
        acc2 = fmaf(w2r[c], rp[c * SEQ], acc2);

    // NOTE: reference is elu(_c1(elu(res + att), ...)) -> the sum gets an elu
    // BEFORE the out_conv. Store elu(sum) here.
    sum2[((size_t)b * CIN + co) * SEQ + s] = elu_f(elu_f(acc1) + elu_f(acc2));
}

// ====================== final_c: out = elu(out_w@sum2 + out_b) ======================
__global__ __launch_bounds__(256) void final_c_kernel(
    const float* __restrict__ sum2, const float* __restrict__ out_w,
    const float* __restrict__ out_b, float* __restrict__ out)
{
    int bx = blockIdx.x;
    int b = bx >> 12;
    int co = (bx >> 4) & 255;
    int chunk = bx & 15;
    int s = chunk * 256 + threadIdx.x;

    float acc = out_b[co];
    const float* wr = out_w + co * CIN;
    const float* sp = sum2 + (size_t)b * CIN * SEQ + s;
    for (int c = 0; c < CIN; ++c)
        acc = fmaf(wr[c], sp[c * SEQ], acc);

    out[((size_t)b * CIN + co) * SEQ + s] = elu_f(acc);
}

extern "C" void kernel_launch(void* const* d_in, const int* in_sizes, int n_in,
                              void* d_out, int out_size, void* d_ws, size_t ws_size,
                              hipStream_t stream) {
    const float* x      = (const float*)d_in[0];
    const float* orig   = (const float*)d_in[1];
    const float* rb_w1  = (const float*)d_in[2];
    const float* rb_b1  = (const float*)d_in[3];
    const float* rb_w2  = (const float*)d_in[4];
    const float* rb_b2  = (const float*)d_in[5];
    const float* q_w    = (const float*)d_in[6];
    const float* q_b    = (const float*)d_in[7];
    const float* k_w    = (const float*)d_in[8];
    const float* k_b    = (const float*)d_in[9];
    const float* v_w    = (const float*)d_in[10];
    const float* v_b    = (const float*)d_in[11];
    const float* attn_w = (const float*)d_in[12];
    const float* attn_b = (const float*)d_in[13];
    const float* resc_w = (const float*)d_in[14];
    const float* resc_b = (const float*)d_in[15];
    const float* out_w  = (const float*)d_in[16];
    const float* out_b  = (const float*)d_in[17];
    float* out = (float*)d_out;

    float* ws = (float*)d_ws;
    float* res   = ws;                 // 2,097,152
    float* o1    = res  + 2097152;     // 2,097,152
    float* qbuf  = o1   + 2097152;     //   131,072
    float* ktbuf = qbuf + 131072;      //   131,072
    float* vbuf  = ktbuf + 131072;     // 1,048,576
    float* attE  = vbuf + 1048576;     // 1,048,576
    float* resE  = attE + 1048576;     // 2,097,152
    float* sum2  = resE + 2097152;     // 2,097,152

    hipMemcpyAsync(res, x, (size_t)2097152 * sizeof(float),
                   hipMemcpyDeviceToDevice, stream);

    for (int i = 0; i < 4; ++i) {
        conv1_kernel<<<dim3(32, 4), 256, 0, stream>>>(
            res, rb_w1 + (size_t)i * 256 * 256 * 8, rb_b1 + i * 256, o1);
        conv2_kernel<<<dim3(32, 8), 256, 0, stream>>>(
            o1, rb_w2 + (size_t)i * 512 * 256 * 8, rb_b2 + i * 512, res);
    }

    qkv_kernel<<<2 * 160 * 16, 256, 0, stream>>>(
        res, orig, q_w, q_b, k_w, k_b, v_w, v_b, qbuf, ktbuf, vbuf);

    attn_kernel<<<2 * 4096, 256, 0, stream>>>(qbuf, ktbuf, vbuf, attE);

    elu_kernel<<<8192, 256, 0, stream>>>(res, resE, 2097152);

    final_ab_kernel<<<8192, 256, 0, stream>>>(
        attE, resE, attn_w, attn_b, resc_w, resc_b, sum2);

    final_c_kernel<<<8192, 256, 0, stream>>>(sum2, out_w, out_b, out);
}

// Round 3
// 1734.599 us; speedup vs baseline: 2.7477x; 2.7477x over previous
//
#include <hip/hip_runtime.h>
#include <math.h>

#define SEQ 4096
#define CIN 256
#define CPE 262
#define VCH 128

typedef __attribute__((ext_vector_type(8))) short bf16x8;
typedef __attribute__((ext_vector_type(4))) float f32x4;

__device__ __forceinline__ float elu_f(float x) {
    return x > 0.0f ? x : (expf(x) - 1.0f);
}
__device__ __forceinline__ unsigned short f2b(float f) {
    unsigned int u = __float_as_uint(f);
    return (unsigned short)((u + 0x7FFFu + ((u >> 16) & 1u)) >> 16);
}

// element-index swizzles (element = ushort); rows are 128B / 256B
#define SWZ64(row, k)  ((row) * 64  + ((k) ^ (((row) & 7) << 3)))
#define SWZ128(row, k) ((row) * 128 + ((k) ^ (((row) & 7) << 4)))

// ===================== prep: res = x ; eluB = bf16(elu(x)) =====================
__global__ __launch_bounds__(256) void prep_kernel(
    const float* __restrict__ x, float* __restrict__ res,
    unsigned short* __restrict__ elub, int n)
{
    int i = blockIdx.x * 256 + threadIdx.x;
    if (i < n) { float v = x[i]; res[i] = v; elub[i] = f2b(elu_f(v)); }
}

// ===================== weight convert fp32 -> bf16 =====================
__global__ __launch_bounds__(256) void wcvt_kernel(
    const float* __restrict__ w1, const float* __restrict__ w2,
    unsigned short* __restrict__ w1b, unsigned short* __restrict__ w2b,
    int n1, int n2)
{
    int i = blockIdx.x * 256 + threadIdx.x;
    if (i < n1) w1b[i] = f2b(w1[i]);
    if (i < n2) w2b[i] = f2b(w2[i]);
}

// ========== conv1 (MFMA implicit GEMM): o1 = elu(conv2x2x2(eluRes) + b1) ==========
// grid (64 slabs, 4 co-tiles of 64), 256 threads = 4 waves
__global__ __launch_bounds__(256) void conv1_mfma(
    const unsigned short* __restrict__ inb,   // [2][256][16][256] bf16
    const unsigned short* __restrict__ wb,    // [256][2048] bf16 (co, ci*8+tap)
    const float* __restrict__ bias,           // [256]
    unsigned short* __restrict__ outb)        // [2][256][16][256] bf16
{
    __shared__ unsigned short sA[64 * 64];    // [co_local][kk] swizzled
    __shared__ unsigned short sX[128 * 64];   // [n][kk] swizzled

    const int slab = blockIdx.x;
    const int bb = slab >> 5, t = (slab >> 1) & 15, h0 = (slab & 1) * 8;
    const int co0 = blockIdx.y * 64;
    const int tid = threadIdx.x;
    const int lane = tid & 63, wv = tid >> 6;
    const int lr = lane & 15, lg = lane >> 4;

    f32x4 acc[4][2];
#pragma unroll
    for (int mi = 0; mi < 4; ++mi)
#pragma unroll
        for (int ni = 0; ni < 2; ++ni) acc[mi][ni] = (f32x4){0.f, 0.f, 0.f, 0.f};

    const int rA = tid >> 2, kA = (tid & 3) * 16;
    const unsigned short* srcA = wb + (size_t)(co0 + rA) * 2048 + kA;

    for (int kc = 0; kc < 32; ++kc) {
        // stage A (weights) 64x64
        const unsigned short* sa = srcA + kc * 64;
#pragma unroll
        for (int q = 0; q < 4; ++q) {
            ushort4 v4 = *(const ushort4*)(sa + q * 4);
            *(ushort4*)&sA[SWZ64(rA, kA + q * 4)] = v4;
        }
        // stage X (im2col) 64kk x 128n
#pragma unroll
        for (int uu = 0; uu < 2; ++uu) {
            int uid = tid + 256 * uu;
            int kk = uid & 63, hh = uid >> 6;
            int ci = (kc << 3) + (kk >> 3);
            int tap = kk & 7;
            int tt = t - 1 + (tap >> 2);
            int sh = h0 + hh - 1 + ((tap >> 1) & 1);
            int kw = tap & 1;
            const unsigned short* src = inb + (((bb * 256 + ci) * 16 + tt) * 256 + sh * 16);
            bool rowok = (tt >= 0) && (sh >= 0);
#pragma unroll
            for (int w = 0; w < 16; ++w) {
                int sw = w - 1 + kw;
                unsigned short val = (rowok && sw >= 0) ? src[sw] : (unsigned short)0;
                sX[SWZ64(hh * 16 + w, kk)] = val;
            }
        }
        __syncthreads();
#pragma unroll
        for (int ks = 0; ks < 2; ++ks) {
            bf16x8 a[4], bv[2];
#pragma unroll
            for (int mi = 0; mi < 4; ++mi)
                a[mi] = *(const bf16x8*)&sA[SWZ64(mi * 16 + lr, ks * 32 + lg * 8)];
#pragma unroll
            for (int ni = 0; ni < 2; ++ni) {
                int n = wv * 32 + ni * 16 + lr;
                bv[ni] = *(const bf16x8*)&sX[SWZ64(n, ks * 32 + lg * 8)];
            }
#pragma unroll
            for (int mi = 0; mi < 4; ++mi)
#pragma unroll
                for (int ni = 0; ni < 2; ++ni)
                    acc[mi][ni] = __builtin_amdgcn_mfma_f32_16x16x32_bf16(
                        a[mi], bv[ni], acc[mi][ni], 0, 0, 0);
        }
        __syncthreads();
    }
    // epilogue: bias + elu -> bf16
#pragma unroll
    for (int mi = 0; mi < 4; ++mi) {
#pragma unroll
        for (int ni = 0; ni < 2; ++ni) {
            int pos = h0 * 16 + wv * 32 + ni * 16 + lr;
#pragma unroll
            for (int r = 0; r < 4; ++r) {
                int co = co0 + mi * 16 + lg * 4 + r;
                float v = acc[mi][ni][r] + bias[co];
                outb[((bb * 256 + co) * 16 + t) * 256 + pos] = f2b(elu_f(v));
            }
        }
    }
}

// ========== conv2 (MFMA) + gate: res += a*sigmoid(g); eluB = bf16(elu(res)) ==========
// grid (64 slabs, 8 co-tiles of 32 pairs), 256 threads
__global__ __launch_bounds__(256) void conv2_mfma(
    const unsigned short* __restrict__ inb,   // o1 bf16
    const unsigned short* __restrict__ wb,    // [512][2048] bf16
    const float* __restrict__ bias,           // [512]
    float* __restrict__ resf,
    unsigned short* __restrict__ elub)
{
    __shared__ unsigned short sA[64 * 64];
    __shared__ unsigned short sX[128 * 64];

    const int slab = blockIdx.x;
    const int bb = slab >> 5, t = (slab >> 1) & 15, h0 = (slab & 1) * 8;
    const int c0 = blockIdx.y * 32;
    const int tid = threadIdx.x;
    const int lane = tid & 63, wv = tid >> 6;
    const int lr = lane & 15, lg = lane >> 4;

    f32x4 acc[4][2];
#pragma unroll
    for (int mi = 0; mi < 4; ++mi)
#pragma unroll
        for (int ni = 0; ni < 2; ++ni) acc[mi][ni] = (f32x4){0.f, 0.f, 0.f, 0.f};

    const int rA = tid >> 2, kA = (tid & 3) * 16;
    const int rowIdx = (rA < 32) ? (c0 + rA) : (256 + c0 + rA - 32);
    const unsigned short* srcA = wb + (size_t)rowIdx * 2048 + kA;

    for (int kc = 0; kc < 32; ++kc) {
        const unsigned short* sa = srcA + kc * 64;
#pragma unroll
        for (int q = 0; q < 4; ++q) {
            ushort4 v4 = *(const ushort4*)(sa + q * 4);
            *(ushort4*)&sA[SWZ64(rA, kA + q * 4)] = v4;
        }
#pragma unroll
        for (int uu = 0; uu < 2; ++uu) {
            int uid = tid + 256 * uu;
            int kk = uid & 63, hh = uid >> 6;
            int ci = (kc << 3) + (kk >> 3);
            int tap = kk & 7;
            int tt = t - 1 + (tap >> 2);
            int sh = h0 + hh - 1 + ((tap >> 1) & 1);
            int kw = tap & 1;
            const unsigned short* src = inb + (((bb * 256 + ci) * 16 + tt) * 256 + sh * 16);
            bool rowok = (tt >= 0) && (sh >= 0);
#pragma unroll
            for (int w = 0; w < 16; ++w) {
                int sw = w - 1 + kw;
                unsigned short val = (rowok && sw >= 0) ? src[sw] : (unsigned short)0;
                sX[SWZ64(hh * 16 + w, kk)] = val;
            }
        }
        __syncthreads();
#pragma unroll
        for (int ks = 0; ks < 2; ++ks) {
            bf16x8 a[4], bv[2];
#pragma unroll
            for (int mi = 0; mi < 4; ++mi)
                a[mi] = *(const bf16x8*)&sA[SWZ64(mi * 16 + lr, ks * 32 + lg * 8)];
#pragma unroll
            for (int ni = 0; ni < 2; ++ni) {
                int n = wv * 32 + ni * 16 + lr;
                bv[ni] = *(const bf16x8*)&sX[SWZ64(n, ks * 32 + lg * 8)];
            }
#pragma unroll
            for (int mi = 0; mi < 4; ++mi)
#pragma unroll
                for (int ni = 0; ni < 2; ++ni)
                    acc[mi][ni] = __builtin_amdgcn_mfma_f32_16x16x32_bf16(
                        a[mi], bv[ni], acc[mi][ni], 0, 0, 0);
        }
        __syncthreads();
    }
    // epilogue: pair (a,g) -> res += a*sigmoid(g); eluB update
#pragma unroll
    for (int mi = 0; mi < 2; ++mi) {
#pragma unroll
        for (int ni = 0; ni < 2; ++ni) {
            int pos = h0 * 16 + wv * 32 + ni * 16 + lr;
#pragma unroll
            for (int r = 0; r < 4; ++r) {
                int co = c0 + mi * 16 + lg * 4 + r;
                float av = acc[mi][ni][r] + bias[co];
                float gv = acc[mi + 2][ni][r] + bias[co + 256];
                float add = av / (1.0f + expf(-gv));
                size_t idx = (size_t)((bb * 256 + co) * 16 + t) * 256 + pos;
                float rn = resf[idx] + add;
                resf[idx] = rn;
                elub[idx] = f2b(elu_f(rn));
            }
        }
    }
}

// ================= qkv: per-position linear on 262 features =================
__global__ __launch_bounds__(256) void qkv_kernel(
    const float* __restrict__ res, const float* __restrict__ orig,
    const float* __restrict__ qw, const float* __restrict__ qb,
    const float* __restrict__ kw, const float* __restrict__ kb,
    const float* __restrict__ vw, const float* __restrict__ vb,
    float* __restrict__ q, float* __restrict__ k_t, float* __restrict__ v)
{
    int bx = blockIdx.x;
    int b = bx / 2560;
    int oc = (bx >> 4) % 160;
    int chunk = bx & 15;
    int s = chunk * 256 + threadIdx.x;

    const float* wrow;
    float bias;
    if (oc < 16)      { wrow = qw + oc * CPE;        bias = qb[oc]; }
    else if (oc < 32) { wrow = kw + (oc - 16) * CPE; bias = kb[oc - 16]; }
    else              { wrow = vw + (oc - 32) * CPE; bias = vb[oc - 32]; }

    float acc = bias;
    const float* rp = res + (size_t)b * CIN * SEQ + s;
    for (int c = 0; c < CIN; ++c)
        acc = fmaf(wrow[c], rp[c * SEQ], acc);
    const float* op = orig + (size_t)b * 3 * SEQ + s;
#pragma unroll
    for (int c = 0; c < 3; ++c)
        acc = fmaf(wrow[256 + c], op[c * SEQ], acc);
    float zt = -0.5f + (float)(s >> 8) * 0.0625f;
    float zh = -0.5f + (float)((s >> 4) & 15) * 0.0625f;
    float zw = -0.5f + (float)(s & 15) * 0.0625f;
    acc = fmaf(wrow[259], zt, acc);
    acc = fmaf(wrow[260], zh, acc);
    acc = fmaf(wrow[261], zw, acc);

    if (oc < 16)      q[((size_t)b * SEQ + s) * 16 + oc] = acc;
    else if (oc < 32) k_t[((size_t)b * 16 + (oc - 16)) * SEQ + s] = acc;
    else              v[((size_t)b * SEQ + s) * VCH + (oc - 32)] = acc;
}

// ============ flash attention: Q-tile 32, KV-chunk 128, PV via MFMA ============
// writes elu(att) transposed: attE[(b*128+vc)*4096 + qpos]
__global__ __launch_bounds__(256) void attn_flash(
    const float* __restrict__ qbuf,  // [B][4096][16]
    const float* __restrict__ ktb,   // [B][16][4096]
    const float* __restrict__ vbuf,  // [B][4096][128]
    float* __restrict__ attE)
{
    __shared__ float sK[128][20];              // K chunk fp32
    __shared__ float sS[32][129];              // scores fp32
    __shared__ unsigned short sP[32 * 128];    // P bf16 [q][kv] swizzled
    __shared__ unsigned short sV[128 * 128];   // V bf16 [vc][kv] swizzled
    __shared__ float sF[32];
    __shared__ float sL[32];

    const int blk = blockIdx.x;    // 256
    const int b = blk >> 7;
    const int q0 = (blk & 127) * 32;
    const int tid = threadIdx.x;
    const int lane = tid & 63, wv = tid >> 6;
    const int lr = lane & 15, lg = lane >> 4;
    const int qq = tid & 31, dq = tid >> 5;
    const float scale = 1.0f / sqrtf(259.0f);

    float qr[16];
#pragma unroll
    for (int c = 0; c < 16; ++c)
        qr[c] = qbuf[((size_t)(b << 12) + q0 + qq) * 16 + c];

    f32x4 acc[2][2];
#pragma unroll
    for (int mi = 0; mi < 2; ++mi)
#pragma unroll
        for (int ni = 0; ni < 2; ++ni) acc[mi][ni] = (f32x4){0.f, 0.f, 0.f, 0.f};
    float m = -1e30f, l = 0.0f;

    const int nch = q0 / 128 + 1;
    for (int kc = 0; kc < nch; ++kc) {
        const int kv0 = kc * 128;
        __syncthreads();
        // stage K (128x16 fp32)
#pragma unroll
        for (int i = 0; i < 8; ++i) {
            int e = tid + 256 * i;
            int kv = e & 127, c = e >> 7;
            sK[kv][c] = ktb[(size_t)((b * 16 + c) << 12) + kv0 + kv];
        }
        // stage V -> bf16 transposed [vc][kv]
        for (int i = 0; i < 64; ++i) {
            int e = tid + 256 * i;
            int kv = e >> 7, vc = e & 127;
            float vv = vbuf[((size_t)(b << 12) + kv0 + kv) * 128 + vc];
            sV[SWZ128(vc, kv)] = f2b(vv);
        }
        __syncthreads();
        // scores: thread -> q=qq, kv = dq*16 + i
#pragma unroll
        for (int i = 0; i < 16; ++i) {
            int kv = dq * 16 + i;
            float s = -1e30f;
            if (kv0 + kv < q0 + qq) {
                float t0 = 0.f, t1 = 0.f, t2 = 0.f, t3 = 0.f;
#pragma unroll
                for (int c = 0; c < 4; ++c) {
                    t0 = fmaf(qr[c],      sK[kv][c],      t0);
                    t1 = fmaf(qr[4 + c],  sK[kv][4 + c],  t1);
                    t2 = fmaf(qr[8 + c],  sK[kv][8 + c],  t2);
                    t3 = fmaf(qr[12 + c], sK[kv][12 + c], t3);
                }
                s = ((t0 + t1) + (t2 + t3)) * scale;
            }
            sS[qq][kv] = s;
        }
        __syncthreads();
        // softmax update (each of 8 dup threads per row computes identically)
        float mc = -1e30f;
        for (int kv = 0; kv < 128; ++kv) mc = fmaxf(mc, sS[qq][kv]);
        float mn = fmaxf(m, mc);
        float fac = expf(m - mn);
        float lsum = 0.f;
        for (int kv = 0; kv < 128; ++kv) {
            float sv = sS[qq][kv];
            float p = (sv <= -1e29f) ? 0.f : expf(sv - mn);
            lsum += p;
            sP[SWZ128(qq, kv)] = f2b(p);
        }
        l = l * fac + lsum;
        m = mn;
        sF[qq] = fac;
        __syncthreads();
        // rescale accumulators + PV MFMA
#pragma unroll
        for (int mi = 0; mi < 2; ++mi) {
            float f0 = sF[mi * 16 + lg * 4 + 0];
            float f1 = sF[mi * 16 + lg * 4 + 1];
            float f2 = sF[mi * 16 + lg * 4 + 2];
            float f3 = sF[mi * 16 + lg * 4 + 3];
#pragma unroll
            for (int ni = 0; ni < 2; ++ni) {
                acc[mi][ni][0] *= f0; acc[mi][ni][1] *= f1;
                acc[mi][ni][2] *= f2; acc[mi][ni][3] *= f3;
            }
        }
#pragma unroll
        for (int ks = 0; ks < 4; ++ks) {
            bf16x8 pa[2], vb[2];
#pragma unroll
            for (int mi = 0; mi < 2; ++mi)
                pa[mi] = *(const bf16x8*)&sP[SWZ128(mi * 16 + lr, ks * 32 + lg * 8)];
#pragma unroll
            for (int ni = 0; ni < 2; ++ni) {
                int vrow = wv * 32 + ni * 16 + lr;
                vb[ni] = *(const bf16x8*)&sV[SWZ128(vrow, ks * 32 + lg * 8)];
            }
#pragma unroll
            for (int mi = 0; mi < 2; ++mi)
#pragma unroll
                for (int ni = 0; ni < 2; ++ni)
                    acc[mi][ni] = __builtin_amdgcn_mfma_f32_16x16x32_bf16(
                        pa[mi], vb[ni], acc[mi][ni], 0, 0, 0);
        }
    }
    sL[qq] = l;
    __syncthreads();
    // epilogue: O = acc/l, elu, write transposed
#pragma unroll
    for (int mi = 0; mi < 2; ++mi) {
#pragma unroll
        for (int ni = 0; ni < 2; ++ni) {
            int vc = wv * 32 + ni * 16 + lr;
#pragma unroll
            for (int r = 0; r < 4; ++r) {
                int qrow = mi * 16 + lg * 4 + r;
                float lv = sL[qrow];
                float o = (lv > 0.f) ? acc[mi][ni][r] / lv : 0.f;
                attE[(size_t)((b * 128 + vc) << 12) + q0 + qrow] = elu_f(o);
            }
        }
    }
}

// ====================== elementwise elu ======================
__global__ __launch_bounds__(256) void elu_kernel(
    const float* __restrict__ in, float* __restrict__ out, int n)
{
    int i = blockIdx.x * 256 + threadIdx.x;
    if (i < n) out[i] = elu_f(in[i]);
}

// ======= final_ab: sum2 = elu( elu(attn_w@attE+attn_b) + elu(resc_w@resE+resc_b) ) =======
__global__ __launch_bounds__(256) void final_ab_kernel(
    const float* __restrict__ att_e, const float* __restrict__ res_e,
    const float* __restrict__ attn_w, const float* __restrict__ attn_b,
    const float* __restrict__ resc_w, const float* __restrict__ resc_b,
    float* __restrict__ sum2)
{
    int bx = blockIdx.x;
    int b = bx >> 12;
    int co = (bx >> 4) & 255;
    int chunk = bx & 15;
    int s = chunk * 256 + threadIdx.x;

    float acc1 = attn_b[co];
    const float* w1r = attn_w + co * VCH;
    const float* ap = att_e + (size_t)b * VCH * SEQ + s;
    for (int c = 0; c < VCH; ++c)
        acc1 = fmaf(w1r[c], ap[c * SEQ], acc1);

    float acc2 = resc_b[co];
    const float* w2r = resc_w + co * CIN;
    const float* rp = res_e + (size_t)b * CIN * SEQ + s;
    for (int c = 0; c < CIN; ++c)
        acc2 = fmaf(w2r[c], rp[c * SEQ], acc2);

    sum2[((size_t)b * CIN + co) * SEQ + s] = elu_f(elu_f(acc1) + elu_f(acc2));
}

// ====================== final_c: out = elu(out_w@sum2 + out_b) ======================
__global__ __launch_bounds__(256) void final_c_kernel(
    const float* __restrict__ sum2, const float* __restrict__ out_w,
    const float* __restrict__ out_b, float* __restrict__ out)
{
    int bx = blockIdx.x;
    int b = bx >> 12;
    int co = (bx >> 4) & 255;
    int chunk = bx & 15;
    int s = chunk * 256 + threadIdx.x;

    float acc = out_b[co];
    const float* wr = out_w + co * CIN;
    const float* sp = sum2 + (size_t)b * CIN * SEQ + s;
    for (int c = 0; c < CIN; ++c)
        acc = fmaf(wr[c], sp[c * SEQ], acc);

    out[((size_t)b * CIN + co) * SEQ + s] = elu_f(acc);
}

extern "C" void kernel_launch(void* const* d_in, const int* in_sizes, int n_in,
                              void* d_out, int out_size, void* d_ws, size_t ws_size,
                              hipStream_t stream) {
    const float* x      = (const float*)d_in[0];
    const float* orig   = (const float*)d_in[1];
    const float* rb_w1  = (const float*)d_in[2];
    const float* rb_b1  = (const float*)d_in[3];
    const float* rb_w2  = (const float*)d_in[4];
    const float* rb_b2  = (const float*)d_in[5];
    const float* q_w    = (const float*)d_in[6];
    const float* q_b    = (const float*)d_in[7];
    const float* k_w    = (const float*)d_in[8];
    const float* k_b    = (const float*)d_in[9];
    const float* v_w    = (const float*)d_in[10];
    const float* v_b    = (const float*)d_in[11];
    const float* attn_w = (const float*)d_in[12];
    const float* attn_b = (const float*)d_in[13];
    const float* resc_w = (const float*)d_in[14];
    const float* resc_b = (const float*)d_in[15];
    const float* out_w  = (const float*)d_in[16];
    const float* out_b  = (const float*)d_in[17];
    float* out = (float*)d_out;

    float* ws = (float*)d_ws;
    float*          res  = ws;                                       // 2M f
    unsigned short* eluB = (unsigned short*)(res + 2097152);         // 2M us
    unsigned short* o1b  = eluB + 2097152;                           // 2M us
    unsigned short* w1b  = o1b + 2097152;                            // 2M us
    unsigned short* w2b  = w1b + 2097152;                            // 4M us
    float*          qbuf = (float*)(w2b + 4194304);                  // 131072 f
    float*          ktbuf= qbuf + 131072;                            // 131072 f
    float*          vbuf = ktbuf + 131072;                           // 1M f
    float*          resE = vbuf + 1048576;                           // 2M f
    float*          attE = (float*)o1b;   // alias: o1b dead before attention
    float*          sum2 = (float*)w2b;   // alias: w2b dead before final_ab

    prep_kernel<<<8192, 256, 0, stream>>>(x, res, eluB, 2097152);
    wcvt_kernel<<<16384, 256, 0, stream>>>(rb_w1, rb_w2, w1b, w2b,
                                           2097152, 4194304);

    for (int i = 0; i < 4; ++i) {
        conv1_mfma<<<dim3(64, 4), 256, 0, stream>>>(
            eluB, w1b + (size_t)i * 524288, rb_b1 + i * 256, o1b);
        conv2_mfma<<<dim3(64, 8), 256, 0, stream>>>(
            o1b, w2b + (size_t)i * 1048576, rb_b2 + i * 512, res, eluB);
    }

    qkv_kernel<<<2 * 160 * 16, 256, 0, stream>>>(
        res, orig, q_w, q_b, k_w, k_b, v_w, v_b, qbuf, ktbuf, vbuf);

    attn_flash<<<256, 256, 0, stream>>>(qbuf, ktbuf, vbuf, attE);

    elu_kernel<<<8192, 256, 0, stream>>>(res, resE, 2097152);

    final_ab_kernel<<<8192, 256, 0, stream>>>(
        attE, resE, attn_w, attn_b, resc_w, resc_b, sum2);

    final_c_kernel<<<8192, 256, 0, stream>>>(sum2, out_w, out_b, out);
}

// Round 4
// 1359.462 us; speedup vs baseline: 3.5059x; 1.2759x over previous
//
#include <hip/hip_runtime.h>
#include <math.h>

#define SEQ 4096
#define CIN 256

typedef __attribute__((ext_vector_type(8))) short bf16x8;
typedef __attribute__((ext_vector_type(4))) float f32x4;

__device__ __forceinline__ float elu_f(float x) {
    return x > 0.0f ? x : (expf(x) - 1.0f);
}
__device__ __forceinline__ unsigned short f2b(float f) {
    unsigned int u = __float_as_uint(f);
    return (unsigned short)((u + 0x7FFFu + ((u >> 16) & 1u)) >> 16);
}

// element-index swizzle for conv LDS tiles (64-element rows)
#define SWZ64(row, k)  ((row) * 64  + ((k) ^ (((row) & 7) << 3)))

// ===================== prep: res = x ; eluB = bf16(elu(x)) =====================
__global__ __launch_bounds__(256) void prep_kernel(
    const float* __restrict__ x, float* __restrict__ res,
    unsigned short* __restrict__ elub, int n)
{
    int i = blockIdx.x * 256 + threadIdx.x;
    if (i < n) { float v = x[i]; res[i] = v; elub[i] = f2b(elu_f(v)); }
}

// ===================== weight convert fp32 -> bf16 (conv weights) =====================
__global__ __launch_bounds__(256) void wcvt_kernel(
    const float* __restrict__ w1, const float* __restrict__ w2,
    unsigned short* __restrict__ w1b, unsigned short* __restrict__ w2b,
    int n1, int n2)
{
    int i = blockIdx.x * 256 + threadIdx.x;
    if (i < n1) w1b[i] = f2b(w1[i]);
    if (i < n2) w2b[i] = f2b(w2[i]);
}

// ========== conv1 (MFMA implicit GEMM): o1 = elu(conv2x2x2(eluRes) + b1) ==========
__global__ __launch_bounds__(256) void conv1_mfma(
    const unsigned short* __restrict__ inb,
    const unsigned short* __restrict__ wb,
    const float* __restrict__ bias,
    unsigned short* __restrict__ outb)
{
    __shared__ unsigned short sA[64 * 64];
    __shared__ unsigned short sX[128 * 64];

    const int slab = blockIdx.x;
    const int bb = slab >> 5, t = (slab >> 1) & 15, h0 = (slab & 1) * 8;
    const int co0 = blockIdx.y * 64;
    const int tid = threadIdx.x;
    const int lane = tid & 63, wv = tid >> 6;
    const int lr = lane & 15, lg = lane >> 4;

    f32x4 acc[4][2];
#pragma unroll
    for (int mi = 0; mi < 4; ++mi)
#pragma unroll
        for (int ni = 0; ni < 2; ++ni) acc[mi][ni] = (f32x4){0.f, 0.f, 0.f, 0.f};

    const int rA = tid >> 2, kA = (tid & 3) * 16;
    const unsigned short* srcA = wb + (size_t)(co0 + rA) * 2048 + kA;

    for (int kc = 0; kc < 32; ++kc) {
        const unsigned short* sa = srcA + kc * 64;
#pragma unroll
        for (int q = 0; q < 4; ++q) {
            ushort4 v4 = *(const ushort4*)(sa + q * 4);
            *(ushort4*)&sA[SWZ64(rA, kA + q * 4)] = v4;
        }
#pragma unroll
        for (int uu = 0; uu < 2; ++uu) {
            int uid = tid + 256 * uu;
            int kk = uid & 63, hh = uid >> 6;
            int ci = (kc << 3) + (kk >> 3);
            int tap = kk & 7;
            int tt = t - 1 + (tap >> 2);
            int sh = h0 + hh - 1 + ((tap >> 1) & 1);
            int kw = tap & 1;
            const unsigned short* src = inb + (((bb * 256 + ci) * 16 + tt) * 256 + sh * 16);
            bool rowok = (tt >= 0) && (sh >= 0);
#pragma unroll
            for (int w = 0; w < 16; ++w) {
                int sw = w - 1 + kw;
                unsigned short val = (rowok && sw >= 0) ? src[sw] : (unsigned short)0;
                sX[SWZ64(hh * 16 + w, kk)] = val;
            }
        }
        __syncthreads();
#pragma unroll
        for (int ks = 0; ks < 2; ++ks) {
            bf16x8 a[4], bv[2];
#pragma unroll
            for (int mi = 0; mi < 4; ++mi)
                a[mi] = *(const bf16x8*)&sA[SWZ64(mi * 16 + lr, ks * 32 + lg * 8)];
#pragma unroll
            for (int ni = 0; ni < 2; ++ni) {
                int n = wv * 32 + ni * 16 + lr;
                bv[ni] = *(const bf16x8*)&sX[SWZ64(n, ks * 32 + lg * 8)];
            }
#pragma unroll
            for (int mi = 0; mi < 4; ++mi)
#pragma unroll
                for (int ni = 0; ni < 2; ++ni)
                    acc[mi][ni] = __builtin_amdgcn_mfma_f32_16x16x32_bf16(
                        a[mi], bv[ni], acc[mi][ni], 0, 0, 0);
        }
        __syncthreads();
    }
#pragma unroll
    for (int mi = 0; mi < 4; ++mi) {
#pragma unroll
        for (int ni = 0; ni < 2; ++ni) {
            int pos = h0 * 16 + wv * 32 + ni * 16 + lr;
#pragma unroll
            for (int r = 0; r < 4; ++r) {
                int co = co0 + mi * 16 + lg * 4 + r;
                float v = acc[mi][ni][r] + bias[co];
                outb[((bb * 256 + co) * 16 + t) * 256 + pos] = f2b(elu_f(v));
            }
        }
    }
}

// ========== conv2 (MFMA) + gate: res += a*sigmoid(g); eluB = bf16(elu(res)) ==========
__global__ __launch_bounds__(256) void conv2_mfma(
    const unsigned short* __restrict__ inb,
    const unsigned short* __restrict__ wb,
    const float* __restrict__ bias,
    float* __restrict__ resf,
    unsigned short* __restrict__ elub)
{
    __shared__ unsigned short sA[64 * 64];
    __shared__ unsigned short sX[128 * 64];

    const int slab = blockIdx.x;
    const int bb = slab >> 5, t = (slab >> 1) & 15, h0 = (slab & 1) * 8;
    const int c0 = blockIdx.y * 32;
    const int tid = threadIdx.x;
    const int lane = tid & 63, wv = tid >> 6;
    const int lr = lane & 15, lg = lane >> 4;

    f32x4 acc[4][2];
#pragma unroll
    for (int mi = 0; mi < 4; ++mi)
#pragma unroll
        for (int ni = 0; ni < 2; ++ni) acc[mi][ni] = (f32x4){0.f, 0.f, 0.f, 0.f};

    const int rA = tid >> 2, kA = (tid & 3) * 16;
    const int rowIdx = (rA < 32) ? (c0 + rA) : (256 + c0 + rA - 32);
    const unsigned short* srcA = wb + (size_t)rowIdx * 2048 + kA;

    for (int kc = 0; kc < 32; ++kc) {
        const unsigned short* sa = srcA + kc * 64;
#pragma unroll
        for (int q = 0; q < 4; ++q) {
            ushort4 v4 = *(const ushort4*)(sa + q * 4);
            *(ushort4*)&sA[SWZ64(rA, kA + q * 4)] = v4;
        }
#pragma unroll
        for (int uu = 0; uu < 2; ++uu) {
            int uid = tid + 256 * uu;
            int kk = uid & 63, hh = uid >> 6;
            int ci = (kc << 3) + (kk >> 3);
            int tap = kk & 7;
            int tt = t - 1 + (tap >> 2);
            int sh = h0 + hh - 1 + ((tap >> 1) & 1);
            int kw = tap & 1;
            const unsigned short* src = inb + (((bb * 256 + ci) * 16 + tt) * 256 + sh * 16);
            bool rowok = (tt >= 0) && (sh >= 0);
#pragma unroll
            for (int w = 0; w < 16; ++w) {
                int sw = w - 1 + kw;
                unsigned short val = (rowok && sw >= 0) ? src[sw] : (unsigned short)0;
                sX[SWZ64(hh * 16 + w, kk)] = val;
            }
        }
        __syncthreads();
#pragma unroll
        for (int ks = 0; ks < 2; ++ks) {
            bf16x8 a[4], bv[2];
#pragma unroll
            for (int mi = 0; mi < 4; ++mi)
                a[mi] = *(const bf16x8*)&sA[SWZ64(mi * 16 + lr, ks * 32 + lg * 8)];
#pragma unroll
            for (int ni = 0; ni < 2; ++ni) {
                int n = wv * 32 + ni * 16 + lr;
                bv[ni] = *(const bf16x8*)&sX[SWZ64(n, ks * 32 + lg * 8)];
            }
#pragma unroll
            for (int mi = 0; mi < 4; ++mi)
#pragma unroll
                for (int ni = 0; ni < 2; ++ni)
                    acc[mi][ni] = __builtin_amdgcn_mfma_f32_16x16x32_bf16(
                        a[mi], bv[ni], acc[mi][ni], 0, 0, 0);
        }
        __syncthreads();
    }
#pragma unroll
    for (int mi = 0; mi < 2; ++mi) {
#pragma unroll
        for (int ni = 0; ni < 2; ++ni) {
            int pos = h0 * 16 + wv * 32 + ni * 16 + lr;
#pragma unroll
            for (int r = 0; r < 4; ++r) {
                int co = c0 + mi * 16 + lg * 4 + r;
                float av = acc[mi][ni][r] + bias[co];
                float gv = acc[mi + 2][ni][r] + bias[co + 256];
                float add = av / (1.0f + expf(-gv));
                size_t idx = (size_t)((bb * 256 + co) * 16 + t) * 256 + pos;
                float rn = resf[idx] + add;
                resf[idx] = rn;
                elub[idx] = f2b(elu_f(rn));
            }
        }
    }
}

// ===== pack: xq[b][s][320] = bf16(res | orig | pos | 0); elut[b][s][256] = bf16(elu(res)) =====
// grid (64 = b*32 s-tiles of 128, 10 c-groups of 32), 256 threads
__global__ __launch_bounds__(256) void pack_kernel(
    const float* __restrict__ res, const float* __restrict__ orig,
    unsigned short* __restrict__ xq, unsigned short* __restrict__ elut)
{
    const int b = blockIdx.x >> 5;
    const int s0 = (blockIdx.x & 31) << 7;
    const int cg = blockIdx.y;
    const int tid = threadIdx.x;
    const int s = s0 + (tid & 127);
    const int c0 = cg * 32 + (tid >> 7) * 16;

    unsigned short xv[16], ev[16];
    if (cg < 8) {
#pragma unroll
        for (int cc = 0; cc < 16; ++cc) {
            int c = c0 + cc;
            float v = res[(size_t)((b * 256 + c) << 12) + s];
            xv[cc] = f2b(v);
            ev[cc] = f2b(elu_f(v));
        }
        *(ushort4*)&elut[((size_t)(b << 12) + s) * 256 + c0]      = *(ushort4*)&ev[0];
        *(ushort4*)&elut[((size_t)(b << 12) + s) * 256 + c0 + 4]  = *(ushort4*)&ev[4];
        *(ushort4*)&elut[((size_t)(b << 12) + s) * 256 + c0 + 8]  = *(ushort4*)&ev[8];
        *(ushort4*)&elut[((size_t)(b << 12) + s) * 256 + c0 + 12] = *(ushort4*)&ev[12];
    } else if (cg == 8) {
#pragma unroll
        for (int cc = 0; cc < 16; ++cc) {
            int c = c0 + cc;
            float v;
            if (c < 259)      v = orig[(size_t)((b * 3 + (c - 256)) << 12) + s];
            else if (c == 259) v = -0.5f + (float)(s >> 8) * 0.0625f;
            else if (c == 260) v = -0.5f + (float)((s >> 4) & 15) * 0.0625f;
            else if (c == 261) v = -0.5f + (float)(s & 15) * 0.0625f;
            else               v = 0.0f;
            xv[cc] = f2b(v);
        }
    } else {
#pragma unroll
        for (int cc = 0; cc < 16; ++cc) xv[cc] = 0;
    }
    unsigned short* xp = &xq[((size_t)(b << 12) + s) * 320 + c0];
    *(ushort4*)(xp)      = *(ushort4*)&xv[0];
    *(ushort4*)(xp + 4)  = *(ushort4*)&xv[4];
    *(ushort4*)(xp + 8)  = *(ushort4*)&xv[8];
    *(ushort4*)(xp + 12) = *(ushort4*)&xv[12];
}

// ===== wcvt2: pack qkv weights [192][320] (zero-pad) + attn/resc/out weights -> bf16 =====
__global__ __launch_bounds__(256) void wcvt2_kernel(
    const float* __restrict__ qw, const float* __restrict__ kw,
    const float* __restrict__ vw, const float* __restrict__ aw,
    const float* __restrict__ rw, const float* __restrict__ ow,
    unsigned short* __restrict__ wqkv, unsigned short* __restrict__ awb,
    unsigned short* __restrict__ rwb, unsigned short* __restrict__ owb)
{
    int idx = blockIdx.x * 256 + threadIdx.x;
    if (idx < 61440) {
        int r = idx / 320, c = idx - r * 320;
        float v = 0.0f;
        if (c < 262) {
            if (r < 16)       v = qw[r * 262 + c];
            else if (r < 32)  v = kw[(r - 16) * 262 + c];
            else if (r < 160) v = vw[(r - 32) * 262 + c];
        }
        wqkv[idx] = f2b(v);
    } else if (idx < 61440 + 32768) {
        int j = idx - 61440; awb[j] = f2b(aw[j]);
    } else if (idx < 61440 + 32768 + 65536) {
        int j = idx - 61440 - 32768; rwb[j] = f2b(rw[j]);
    } else if (idx < 61440 + 32768 + 131072) {
        int j = idx - 61440 - 98304; owb[j] = f2b(ow[j]);
    }
}

// ===== qkv GEMM (no LDS, direct global fragments): [192][320] @ [s][320]^T =====
// grid (64 = b*32 s-tiles of 128, 3 co-tiles of 64), 256 threads
__global__ __launch_bounds__(256) void qkv_gemm(
    const unsigned short* __restrict__ Wb, const unsigned short* __restrict__ Xt,
    const float* __restrict__ qb, const float* __restrict__ kb,
    const float* __restrict__ vb,
    float* __restrict__ q, float* __restrict__ k, unsigned short* __restrict__ vbt)
{
    const int b = blockIdx.x >> 5;
    const int s0 = (blockIdx.x & 31) << 7;
    const int co0 = blockIdx.y << 6;
    const int lane = threadIdx.x & 63, wv = threadIdx.x >> 6;
    const int lr = lane & 15, lg = lane >> 4;

    f32x4 acc[4][2];
#pragma unroll
    for (int mi = 0; mi < 4; ++mi)
#pragma unroll
        for (int ni = 0; ni < 2; ++ni) acc[mi][ni] = (f32x4){0.f, 0.f, 0.f, 0.f};

    const unsigned short* wp = Wb + (size_t)co0 * 320 + lg * 8;
    const unsigned short* xp = Xt + ((size_t)(b << 12) + s0 + wv * 32) * 320 + lg * 8;

#pragma unroll
    for (int kc = 0; kc < 10; ++kc) {
        int ko = kc * 32;
        bf16x8 a[4], x[2];
#pragma unroll
        for (int mi = 0; mi < 4; ++mi)
            a[mi] = *(const bf16x8*)(wp + (size_t)(mi * 16 + lr) * 320 + ko);
#pragma unroll
        for (int ni = 0; ni < 2; ++ni)
            x[ni] = *(const bf16x8*)(xp + (size_t)(ni * 16 + lr) * 320 + ko);
#pragma unroll
        for (int mi = 0; mi < 4; ++mi)
#pragma unroll
            for (int ni = 0; ni < 2; ++ni)
                acc[mi][ni] = __builtin_amdgcn_mfma_f32_16x16x32_bf16(
                    a[mi], x[ni], acc[mi][ni], 0, 0, 0);
    }
#pragma unroll
    for (int mi = 0; mi < 4; ++mi)
#pragma unroll
    for (int ni = 0; ni < 2; ++ni)
#pragma unroll
    for (int r = 0; r < 4; ++r) {
        int co = co0 + mi * 16 + lg * 4 + r;
        if (co >= 160) continue;
        int s = s0 + wv * 32 + ni * 16 + lr;
        float bias = (co < 16) ? qb[co] : ((co < 32) ? kb[co - 16] : vb[co - 32]);
        float v = acc[mi][ni][r] + bias;
        if (co < 16)      q[((size_t)(b << 12) + s) * 16 + co] = v;
        else if (co < 32) k[((size_t)(b << 12) + s) * 16 + co - 16] = v;
        else              vbt[((size_t)(b * 128 + co - 32) << 12) + s] = f2b(v);
    }
}

// ===== flash attention v2: register scores, shfl softmax, LDS only for P =====
// grid 256 (b * 128 q-tiles of 32), 256 threads
#define SWZP(row, kk) ((row) * 128 + ((kk) ^ (((row) & 15) << 3)))
__global__ __launch_bounds__(256) void attn_flash2(
    const float* __restrict__ qbuf, const float* __restrict__ kbuf,
    const unsigned short* __restrict__ vbt, unsigned short* __restrict__ attEb)
{
    __shared__ unsigned short sP[32 * 128];
    __shared__ float sF[32];
    __shared__ float sL[32];

    const int b = blockIdx.x >> 7;
    const int q0 = (blockIdx.x & 127) * 32;
    const int tid = threadIdx.x;
    const int lane = tid & 63, wv = tid >> 6;
    const int lr = lane & 15, lg = lane >> 4;
    const int qq = wv * 8 + (lane >> 3), dq = lane & 7;
    const float scale = 1.0f / sqrtf(259.0f);

    float qr[16];
    {
        const float* qp = qbuf + ((size_t)(b << 12) + q0 + qq) * 16;
#pragma unroll
        for (int c = 0; c < 16; ++c) qr[c] = qp[c];
    }

    f32x4 acc[2][2];
#pragma unroll
    for (int mi = 0; mi < 2; ++mi)
#pragma unroll
        for (int ni = 0; ni < 2; ++ni) acc[mi][ni] = (f32x4){0.f, 0.f, 0.f, 0.f};
    float m = -1e30f, l = 0.0f;

    const int nch = (q0 >> 7) + 1;
    for (int kc = 0; kc < nch; ++kc) {
        const int kv0 = kc << 7;
        float sv[16];
        const float* kp = kbuf + ((size_t)(b << 12) + kv0 + dq * 16) * 16;
#pragma unroll
        for (int i = 0; i < 16; ++i) {
            float t0 = 0.f, t1 = 0.f, t2 = 0.f, t3 = 0.f;
            const float* kr = kp + i * 16;
#pragma unroll
            for (int c = 0; c < 4; ++c) {
                t0 = fmaf(qr[c],      kr[c],      t0);
                t1 = fmaf(qr[4 + c],  kr[4 + c],  t1);
                t2 = fmaf(qr[8 + c],  kr[8 + c],  t2);
                t3 = fmaf(qr[12 + c], kr[12 + c], t3);
            }
            bool valid = (kv0 + dq * 16 + i) < (q0 + qq);
            sv[i] = valid ? ((t0 + t1) + (t2 + t3)) * scale : -1e30f;
        }
        // row max over 16 local + 8-lane group
        float mc = sv[0];
#pragma unroll
        for (int i = 1; i < 16; ++i) mc = fmaxf(mc, sv[i]);
        mc = fmaxf(mc, __shfl_xor(mc, 1, 64));
        mc = fmaxf(mc, __shfl_xor(mc, 2, 64));
        mc = fmaxf(mc, __shfl_xor(mc, 4, 64));
        float mn = fmaxf(m, mc);
        float fac = expf(m - mn);
        float ls = 0.f;
        unsigned int packs[8];
#pragma unroll
        for (int i2 = 0; i2 < 8; ++i2) {
            float p0 = (sv[2 * i2]     <= -1e29f) ? 0.f : expf(sv[2 * i2]     - mn);
            float p1 = (sv[2 * i2 + 1] <= -1e29f) ? 0.f : expf(sv[2 * i2 + 1] - mn);
            ls += p0 + p1;
            packs[i2] = (unsigned int)f2b(p0) | ((unsigned int)f2b(p1) << 16);
        }
        ls += __shfl_xor(ls, 1, 64);
        ls += __shfl_xor(ls, 2, 64);
        ls += __shfl_xor(ls, 4, 64);
        l = l * fac + ls;
        m = mn;
        if (dq == 0) sF[qq] = fac;
#pragma unroll
        for (int i2 = 0; i2 < 8; ++i2) {
            int kk = (dq * 16 + i2 * 2) ^ ((qq & 15) << 3);
            ((unsigned int*)sP)[(qq * 128 + kk) >> 1] = packs[i2];
        }
        __syncthreads();
        // rescale + PV
#pragma unroll
        for (int mi = 0; mi < 2; ++mi)
#pragma unroll
            for (int r = 0; r < 4; ++r) {
                float f = sF[mi * 16 + lg * 4 + r];
                acc[mi][0][r] *= f;
                acc[mi][1][r] *= f;
            }
#pragma unroll
        for (int ks = 0; ks < 4; ++ks) {
            bf16x8 pa[2], vv[2];
#pragma unroll
            for (int mi = 0; mi < 2; ++mi)
                pa[mi] = *(const bf16x8*)&sP[SWZP(mi * 16 + lr, ks * 32 + lg * 8)];
#pragma unroll
            for (int ni = 0; ni < 2; ++ni)
                vv[ni] = *(const bf16x8*)(vbt +
                    ((size_t)(b * 128 + wv * 32 + ni * 16 + lr) << 12) +
                    kv0 + ks * 32 + lg * 8);
#pragma unroll
            for (int mi = 0; mi < 2; ++mi)
#pragma unroll
                for (int ni = 0; ni < 2; ++ni)
                    acc[mi][ni] = __builtin_amdgcn_mfma_f32_16x16x32_bf16(
                        pa[mi], vv[ni], acc[mi][ni], 0, 0, 0);
        }
        __syncthreads();
    }
    if (dq == 0) sL[qq] = l;
    __syncthreads();
#pragma unroll
    for (int mi = 0; mi < 2; ++mi)
#pragma unroll
    for (int ni = 0; ni < 2; ++ni)
#pragma unroll
    for (int r = 0; r < 4; ++r) {
        int qrow = mi * 16 + lg * 4 + r;
        int vc = wv * 32 + ni * 16 + lr;
        float lv = sL[qrow];
        float o = (lv > 0.f) ? acc[mi][ni][r] / lv : 0.f;
        attEb[((size_t)(b << 12) + q0 + qrow) * 128 + vc] = f2b(elu_f(o));
    }
}

// ===== final_ab GEMM: sum2b = bf16(elu( elu(W1@attEb+b1) + elu(W2@elut+b2) )) =====
// grid (64, 4 co-tiles of 64), 256 threads
__global__ __launch_bounds__(256) void final_ab_gemm(
    const unsigned short* __restrict__ W1b, const unsigned short* __restrict__ W2b,
    const unsigned short* __restrict__ X1, const unsigned short* __restrict__ X2,
    const float* __restrict__ b1, const float* __restrict__ b2,
    unsigned short* __restrict__ sum2b)
{
    const int b = blockIdx.x >> 5;
    const int s0 = (blockIdx.x & 31) << 7;
    const int co0 = blockIdx.y << 6;
    const int lane = threadIdx.x & 63, wv = threadIdx.x >> 6;
    const int lr = lane & 15, lg = lane >> 4;

    f32x4 acc1[4][2], acc2[4][2];
#pragma unroll
    for (int mi = 0; mi < 4; ++mi)
#pragma unroll
        for (int ni = 0; ni < 2; ++ni) {
            acc1[mi][ni] = (f32x4){0.f, 0.f, 0.f, 0.f};
            acc2[mi][ni] = (f32x4){0.f, 0.f, 0.f, 0.f};
        }

    {
        const unsigned short* wp = W1b + (size_t)co0 * 128 + lg * 8;
        const unsigned short* xp = X1 + ((size_t)(b << 12) + s0 + wv * 32) * 128 + lg * 8;
#pragma unroll
        for (int kc = 0; kc < 4; ++kc) {
            int ko = kc * 32;
            bf16x8 a[4], x[2];
#pragma unroll
            for (int mi = 0; mi < 4; ++mi)
                a[mi] = *(const bf16x8*)(wp + (size_t)(mi * 16 + lr) * 128 + ko);
#pragma unroll
            for (int ni = 0; ni < 2; ++ni)
                x[ni] = *(const bf16x8*)(xp + (size_t)(ni * 16 + lr) * 128 + ko);
#pragma unroll
            for (int mi = 0; mi < 4; ++mi)
#pragma unroll
                for (int ni = 0; ni < 2; ++ni)
                    acc1[mi][ni] = __builtin_amdgcn_mfma_f32_16x16x32_bf16(
                        a[mi], x[ni], acc1[mi][ni], 0, 0, 0);
        }
    }
    {
        const unsigned short* wp = W2b + (size_t)co0 * 256 + lg * 8;
        const unsigned short* xp = X2 + ((size_t)(b << 12) + s0 + wv * 32) * 256 + lg * 8;
#pragma unroll
        for (int kc = 0; kc < 8; ++kc) {
            int ko = kc * 32;
            bf16x8 a[4], x[2];
#pragma unroll
            for (int mi = 0; mi < 4; ++mi)
                a[mi] = *(const bf16x8*)(wp + (size_t)(mi * 16 + lr) * 256 + ko);
#pragma unroll
            for (int ni = 0; ni < 2; ++ni)
                x[ni] = *(const bf16x8*)(xp + (size_t)(ni * 16 + lr) * 256 + ko);
#pragma unroll
            for (int mi = 0; mi < 4; ++mi)
#pragma unroll
                for (int ni = 0; ni < 2; ++ni)
                    acc2[mi][ni] = __builtin_amdgcn_mfma_f32_16x16x32_bf16(
                        a[mi], x[ni], acc2[mi][ni], 0, 0, 0);
        }
    }
#pragma unroll
    for (int mi = 0; mi < 4; ++mi)
#pragma unroll
    for (int ni = 0; ni < 2; ++ni)
#pragma unroll
    for (int r = 0; r < 4; ++r) {
        int co = co0 + mi * 16 + lg * 4 + r;
        int s = s0 + wv * 32 + ni * 16 + lr;
        float v1 = elu_f(acc1[mi][ni][r] + b1[co]);
        float v2 = elu_f(acc2[mi][ni][r] + b2[co]);
        sum2b[((size_t)(b << 12) + s) * 256 + co] = f2b(elu_f(v1 + v2));
    }
}

// ===== final_c GEMM: out = elu(outW@sum2b + out_b), fp32 [b][256][4096] =====
__global__ __launch_bounds__(256) void final_c_gemm(
    const unsigned short* __restrict__ Wb, const unsigned short* __restrict__ Xt,
    const float* __restrict__ bias, float* __restrict__ out)
{
    const int b = blockIdx.x >> 5;
    const int s0 = (blockIdx.x & 31) << 7;
    const int co0 = blockIdx.y << 6;
    const int lane = threadIdx.x & 63, wv = threadIdx.x >> 6;
    const int lr = lane & 15, lg = lane >> 4;

    f32x4 acc[4][2];
#pragma unroll
    for (int mi = 0; mi < 4; ++mi)
#pragma unroll
        for (int ni = 0; ni < 2; ++ni) acc[mi][ni] = (f32x4){0.f, 0.f, 0.f, 0.f};

    const unsigned short* wp = Wb + (size_t)co0 * 256 + lg * 8;
    const unsigned short* xp = Xt + ((size_t)(b << 12) + s0 + wv * 32) * 256 + lg * 8;
#pragma unroll
    for (int kc = 0; kc < 8; ++kc) {
        int ko = kc * 32;
        bf16x8 a[4], x[2];
#pragma unroll
        for (int mi = 0; mi < 4; ++mi)
            a[mi] = *(const bf16x8*)(wp + (size_t)(mi * 16 + lr) * 256 + ko);
#pragma unroll
        for (int ni = 0; ni < 2; ++ni)
            x[ni] = *(const bf16x8*)(xp + (size_t)(ni * 16 + lr) * 256 + ko);
#pragma unroll
        for (int mi = 0; mi < 4; ++mi)
#pragma unroll
            for (int ni = 0; ni < 2; ++ni)
                acc[mi][ni] = __builtin_amdgcn_mfma_f32_16x16x32_bf16(
                    a[mi], x[ni], acc[mi][ni], 0, 0, 0);
    }
#pragma unroll
    for (int mi = 0; mi < 4; ++mi)
#pragma unroll
    for (int ni = 0; ni < 2; ++ni)
#pragma unroll
    for (int r = 0; r < 4; ++r) {
        int co = co0 + mi * 16 + lg * 4 + r;
        int s = s0 + wv * 32 + ni * 16 + lr;
        out[((size_t)(b * 256 + co) << 12) + s] = elu_f(acc[mi][ni][r] + bias[co]);
    }
}

extern "C" void kernel_launch(void* const* d_in, const int* in_sizes, int n_in,
                              void* d_out, int out_size, void* d_ws, size_t ws_size,
                              hipStream_t stream) {
    const float* x      = (const float*)d_in[0];
    const float* orig   = (const float*)d_in[1];
    const float* rb_w1  = (const float*)d_in[2];
    const float* rb_b1  = (const float*)d_in[3];
    const float* rb_w2  = (const float*)d_in[4];
    const float* rb_b2  = (const float*)d_in[5];
    const float* q_w    = (const float*)d_in[6];
    const float* q_b    = (const float*)d_in[7];
    const float* k_w    = (const float*)d_in[8];
    const float* k_b    = (const float*)d_in[9];
    const float* v_w    = (const float*)d_in[10];
    const float* v_b    = (const float*)d_in[11];
    const float* attn_w = (const float*)d_in[12];
    const float* attn_b = (const float*)d_in[13];
    const float* resc_w = (const float*)d_in[14];
    const float* resc_b = (const float*)d_in[15];
    const float* out_w  = (const float*)d_in[16];
    const float* out_b  = (const float*)d_in[17];
    float* out = (float*)d_out;

    char* base = (char*)d_ws;
    float*          res   = (float*)(base);                       // 8 MB
    unsigned short* eluB  = (unsigned short*)(base + (8u << 20)); // 4 MB
    unsigned short* o1b   = (unsigned short*)(base + (12u << 20)); // 4 MB
    unsigned short* w1b   = (unsigned short*)(base + (16u << 20)); // 4 MB
    unsigned short* w2b   = (unsigned short*)(base + (20u << 20)); // 8 MB
    // aliases (live after conv loop)
    unsigned short* elut  = eluB;                                  // [b][s][256]
    unsigned short* vbt   = o1b;                                   // 2 MB
    unsigned short* attEb = (unsigned short*)(base + (12u << 20) + 2097152); // 2 MB
    unsigned short* sum2b = w1b;                                   // 4 MB
    unsigned short* xqkvB = w2b;                                   // 5 MB
    float*          qbuf  = (float*)(base + (20u << 20) + 5242880);   // 512 KB
    float*          kbuf  = (float*)(base + (20u << 20) + 5767168);   // 512 KB
    unsigned short* wqkvB = (unsigned short*)(base + (20u << 20) + 6291456); // 120 KB
    unsigned short* attnWb= (unsigned short*)(base + (20u << 20) + 6414336); // 64 KB
    unsigned short* rescWb= (unsigned short*)(base + (20u << 20) + 6479872); // 128 KB
    unsigned short* outWb = (unsigned short*)(base + (20u << 20) + 6610944); // 128 KB

    prep_kernel<<<8192, 256, 0, stream>>>(x, res, eluB, 2097152);
    wcvt_kernel<<<16384, 256, 0, stream>>>(rb_w1, rb_w2, w1b, w2b,
                                           2097152, 4194304);

    for (int i = 0; i < 4; ++i) {
        conv1_mfma<<<dim3(64, 4), 256, 0, stream>>>(
            eluB, w1b + (size_t)i * 524288, rb_b1 + i * 256, o1b);
        conv2_mfma<<<dim3(64, 8), 256, 0, stream>>>(
            o1b, w2b + (size_t)i * 1048576, rb_b2 + i * 512, res, eluB);
    }

    pack_kernel<<<dim3(64, 10), 256, 0, stream>>>(res, orig, xqkvB, elut);
    wcvt2_kernel<<<880, 256, 0, stream>>>(q_w, k_w, v_w, attn_w, resc_w, out_w,
                                          wqkvB, attnWb, rescWb, outWb);

    qkv_gemm<<<dim3(64, 3), 256, 0, stream>>>(wqkvB, xqkvB, q_b, k_b, v_b,
                                              qbuf, kbuf, vbt);

    attn_flash2<<<256, 256, 0, stream>>>(qbuf, kbuf, vbt, attEb);

    final_ab_gemm<<<dim3(64, 4), 256, 0, stream>>>(
        attnWb, rescWb, attEb, elut, attn_b, resc_b, sum2b);

    final_c_gemm<<<dim3(64, 4), 256, 0, stream>>>(outWb, sum2b, out_b, out);
}

// Round 5
// 1318.859 us; speedup vs baseline: 3.6138x; 1.0308x over previous
//
#include <hip/hip_runtime.h>
#include <math.h>

#define SEQ 4096
#define CIN 256

typedef __attribute__((ext_vector_type(8))) short bf16x8;
typedef __attribute__((ext_vector_type(4))) float f32x4;

__device__ __forceinline__ float elu_f(float x) {
    return x > 0.0f ? x : (expf(x) - 1.0f);
}
__device__ __forceinline__ unsigned short f2b(float f) {
    unsigned int u = __float_as_uint(f);
    return (unsigned short)((u + 0x7FFFu + ((u >> 16) & 1u)) >> 16);
}

// element-index swizzle for conv LDS tiles (64-element rows)
#define SWZ64(row, k)  ((row) * 64  + ((k) ^ (((row) & 7) << 3)))

// ===================== prep: res = x ; eluB = bf16(elu(x)) =====================
__global__ __launch_bounds__(256) void prep_kernel(
    const float* __restrict__ x, float* __restrict__ res,
    unsigned short* __restrict__ elub, int n)
{
    int i = blockIdx.x * 256 + threadIdx.x;
    if (i < n) { float v = x[i]; res[i] = v; elub[i] = f2b(elu_f(v)); }
}

// ===================== weight convert fp32 -> bf16 (conv weights) =====================
__global__ __launch_bounds__(256) void wcvt_kernel(
    const float* __restrict__ w1, const float* __restrict__ w2,
    unsigned short* __restrict__ w1b, unsigned short* __restrict__ w2b,
    int n1, int n2)
{
    int i = blockIdx.x * 256 + threadIdx.x;
    if (i < n1) w1b[i] = f2b(w1[i]);
    if (i < n2) w2b[i] = f2b(w2[i]);
}

// ========== conv1 (MFMA implicit GEMM): o1 = elu(conv2x2x2(eluRes) + b1) ==========
__global__ __launch_bounds__(256) void conv1_mfma(
    const unsigned short* __restrict__ inb,
    const unsigned short* __restrict__ wb,
    const float* __restrict__ bias,
    unsigned short* __restrict__ outb)
{
    __shared__ unsigned short sA[64 * 64];
    __shared__ unsigned short sX[128 * 64];

    const int slab = blockIdx.x;
    const int bb = slab >> 5, t = (slab >> 1) & 15, h0 = (slab & 1) * 8;
    const int co0 = blockIdx.y * 64;
    const int tid = threadIdx.x;
    const int lane = tid & 63, wv = tid >> 6;
    const int lr = lane & 15, lg = lane >> 4;

    f32x4 acc[4][2];
#pragma unroll
    for (int mi = 0; mi < 4; ++mi)
#pragma unroll
        for (int ni = 0; ni < 2; ++ni) acc[mi][ni] = (f32x4){0.f, 0.f, 0.f, 0.f};

    const int rA = tid >> 2, kA = (tid & 3) * 16;
    const unsigned short* srcA = wb + (size_t)(co0 + rA) * 2048 + kA;

    for (int kc = 0; kc < 32; ++kc) {
        const unsigned short* sa = srcA + kc * 64;
#pragma unroll
        for (int q = 0; q < 4; ++q) {
            ushort4 v4 = *(const ushort4*)(sa + q * 4);
            *(ushort4*)&sA[SWZ64(rA, kA + q * 4)] = v4;
        }
#pragma unroll
        for (int uu = 0; uu < 2; ++uu) {
            int uid = tid + 256 * uu;
            int kk = uid & 63, hh = uid >> 6;
            int ci = (kc << 3) + (kk >> 3);
            int tap = kk & 7;
            int tt = t - 1 + (tap >> 2);
            int sh = h0 + hh - 1 + ((tap >> 1) & 1);
            int kw = tap & 1;
            const unsigned short* src = inb + (((bb * 256 + ci) * 16 + tt) * 256 + sh * 16);
            bool rowok = (tt >= 0) && (sh >= 0);
#pragma unroll
            for (int w = 0; w < 16; ++w) {
                int sw = w - 1 + kw;
                unsigned short val = (rowok && sw >= 0) ? src[sw] : (unsigned short)0;
                sX[SWZ64(hh * 16 + w, kk)] = val;
            }
        }
        __syncthreads();
#pragma unroll
        for (int ks = 0; ks < 2; ++ks) {
            bf16x8 a[4], bv[2];
#pragma unroll
            for (int mi = 0; mi < 4; ++mi)
                a[mi] = *(const bf16x8*)&sA[SWZ64(mi * 16 + lr, ks * 32 + lg * 8)];
#pragma unroll
            for (int ni = 0; ni < 2; ++ni) {
                int n = wv * 32 + ni * 16 + lr;
                bv[ni] = *(const bf16x8*)&sX[SWZ64(n, ks * 32 + lg * 8)];
            }
#pragma unroll
            for (int mi = 0; mi < 4; ++mi)
#pragma unroll
                for (int ni = 0; ni < 2; ++ni)
                    acc[mi][ni] = __builtin_amdgcn_mfma_f32_16x16x32_bf16(
                        a[mi], bv[ni], acc[mi][ni], 0, 0, 0);
        }
        __syncthreads();
    }
#pragma unroll
    for (int mi = 0; mi < 4; ++mi) {
#pragma unroll
        for (int ni = 0; ni < 2; ++ni) {
            int pos = h0 * 16 + wv * 32 + ni * 16 + lr;
#pragma unroll
            for (int r = 0; r < 4; ++r) {
                int co = co0 + mi * 16 + lg * 4 + r;
                float v = acc[mi][ni][r] + bias[co];
                outb[((bb * 256 + co) * 16 + t) * 256 + pos] = f2b(elu_f(v));
            }
        }
    }
}

// ========== conv2 (MFMA) + gate: res += a*sigmoid(g); eluB = bf16(elu(res)) ==========
__global__ __launch_bounds__(256) void conv2_mfma(
    const unsigned short* __restrict__ inb,
    const unsigned short* __restrict__ wb,
    const float* __restrict__ bias,
    float* __restrict__ resf,
    unsigned short* __restrict__ elub)
{
    __shared__ unsigned short sA[64 * 64];
    __shared__ unsigned short sX[128 * 64];

    const int slab = blockIdx.x;
    const int bb = slab >> 5, t = (slab >> 1) & 15, h0 = (slab & 1) * 8;
    const int c0 = blockIdx.y * 32;
    const int tid = threadIdx.x;
    const int lane = tid & 63, wv = tid >> 6;
    const int lr = lane & 15, lg = lane >> 4;

    f32x4 acc[4][2];
#pragma unroll
    for (int mi = 0; mi < 4; ++mi)
#pragma unroll
        for (int ni = 0; ni < 2; ++ni) acc[mi][ni] = (f32x4){0.f, 0.f, 0.f, 0.f};

    const int rA = tid >> 2, kA = (tid & 3) * 16;
    const int rowIdx = (rA < 32) ? (c0 + rA) : (256 + c0 + rA - 32);
    const unsigned short* srcA = wb + (size_t)rowIdx * 2048 + kA;

    for (int kc = 0; kc < 32; ++kc) {
        const unsigned short* sa = srcA + kc * 64;
#pragma unroll
        for (int q = 0; q < 4; ++q) {
            ushort4 v4 = *(const ushort4*)(sa + q * 4);
            *(ushort4*)&sA[SWZ64(rA, kA + q * 4)] = v4;
        }
#pragma unroll
        for (int uu = 0; uu < 2; ++uu) {
            int uid = tid + 256 * uu;
            int kk = uid & 63, hh = uid >> 6;
            int ci = (kc << 3) + (kk >> 3);
            int tap = kk & 7;
            int tt = t - 1 + (tap >> 2);
            int sh = h0 + hh - 1 + ((tap >> 1) & 1);
            int kw = tap & 1;
            const unsigned short* src = inb + (((bb * 256 + ci) * 16 + tt) * 256 + sh * 16);
            bool rowok = (tt >= 0) && (sh >= 0);
#pragma unroll
            for (int w = 0; w < 16; ++w) {
                int sw = w - 1 + kw;
                unsigned short val = (rowok && sw >= 0) ? src[sw] : (unsigned short)0;
                sX[SWZ64(hh * 16 + w, kk)] = val;
            }
        }
        __syncthreads();
#pragma unroll
        for (int ks = 0; ks < 2; ++ks) {
            bf16x8 a[4], bv[2];
#pragma unroll
            for (int mi = 0; mi < 4; ++mi)
                a[mi] = *(const bf16x8*)&sA[SWZ64(mi * 16 + lr, ks * 32 + lg * 8)];
#pragma unroll
            for (int ni = 0; ni < 2; ++ni) {
                int n = wv * 32 + ni * 16 + lr;
                bv[ni] = *(const bf16x8*)&sX[SWZ64(n, ks * 32 + lg * 8)];
            }
#pragma unroll
            for (int mi = 0; mi < 4; ++mi)
#pragma unroll
                for (int ni = 0; ni < 2; ++ni)
                    acc[mi][ni] = __builtin_amdgcn_mfma_f32_16x16x32_bf16(
                        a[mi], bv[ni], acc[mi][ni], 0, 0, 0);
        }
        __syncthreads();
    }
#pragma unroll
    for (int mi = 0; mi < 2; ++mi) {
#pragma unroll
        for (int ni = 0; ni < 2; ++ni) {
            int pos = h0 * 16 + wv * 32 + ni * 16 + lr;
#pragma unroll
            for (int r = 0; r < 4; ++r) {
                int co = c0 + mi * 16 + lg * 4 + r;
                float av = acc[mi][ni][r] + bias[co];
                float gv = acc[mi + 2][ni][r] + bias[co + 256];
                float add = av / (1.0f + expf(-gv));
                size_t idx = (size_t)((bb * 256 + co) * 16 + t) * 256 + pos;
                float rn = resf[idx] + add;
                resf[idx] = rn;
                elub[idx] = f2b(elu_f(rn));
            }
        }
    }
}

// ===== pack: xq[b][s][320] = bf16(res | orig | pos | 0); elut[b][s][256] = bf16(elu(res)) =====
__global__ __launch_bounds__(256) void pack_kernel(
    const float* __restrict__ res, const float* __restrict__ orig,
    unsigned short* __restrict__ xq, unsigned short* __restrict__ elut)
{
    const int b = blockIdx.x >> 5;
    const int s0 = (blockIdx.x & 31) << 7;
    const int cg = blockIdx.y;
    const int tid = threadIdx.x;
    const int s = s0 + (tid & 127);
    const int c0 = cg * 32 + (tid >> 7) * 16;

    unsigned short xv[16], ev[16];
    if (cg < 8) {
#pragma unroll
        for (int cc = 0; cc < 16; ++cc) {
            int c = c0 + cc;
            float v = res[(size_t)((b * 256 + c) << 12) + s];
            xv[cc] = f2b(v);
            ev[cc] = f2b(elu_f(v));
        }
        *(ushort4*)&elut[((size_t)(b << 12) + s) * 256 + c0]      = *(ushort4*)&ev[0];
        *(ushort4*)&elut[((size_t)(b << 12) + s) * 256 + c0 + 4]  = *(ushort4*)&ev[4];
        *(ushort4*)&elut[((size_t)(b << 12) + s) * 256 + c0 + 8]  = *(ushort4*)&ev[8];
        *(ushort4*)&elut[((size_t)(b << 12) + s) * 256 + c0 + 12] = *(ushort4*)&ev[12];
    } else if (cg == 8) {
#pragma unroll
        for (int cc = 0; cc < 16; ++cc) {
            int c = c0 + cc;
            float v;
            if (c < 259)      v = orig[(size_t)((b * 3 + (c - 256)) << 12) + s];
            else if (c == 259) v = -0.5f + (float)(s >> 8) * 0.0625f;
            else if (c == 260) v = -0.5f + (float)((s >> 4) & 15) * 0.0625f;
            else if (c == 261) v = -0.5f + (float)(s & 15) * 0.0625f;
            else               v = 0.0f;
            xv[cc] = f2b(v);
        }
    } else {
#pragma unroll
        for (int cc = 0; cc < 16; ++cc) xv[cc] = 0;
    }
    unsigned short* xp = &xq[((size_t)(b << 12) + s) * 320 + c0];
    *(ushort4*)(xp)      = *(ushort4*)&xv[0];
    *(ushort4*)(xp + 4)  = *(ushort4*)&xv[4];
    *(ushort4*)(xp + 8)  = *(ushort4*)&xv[8];
    *(ushort4*)(xp + 12) = *(ushort4*)&xv[12];
}

// ===== wcvt2: pack qkv weights [192][320] (zero-pad) + attn/resc/out weights -> bf16 =====
__global__ __launch_bounds__(256) void wcvt2_kernel(
    const float* __restrict__ qw, const float* __restrict__ kw,
    const float* __restrict__ vw, const float* __restrict__ aw,
    const float* __restrict__ rw, const float* __restrict__ ow,
    unsigned short* __restrict__ wqkv, unsigned short* __restrict__ awb,
    unsigned short* __restrict__ rwb, unsigned short* __restrict__ owb)
{
    int idx = blockIdx.x * 256 + threadIdx.x;
    if (idx < 61440) {
        int r = idx / 320, c = idx - r * 320;
        float v = 0.0f;
        if (c < 262) {
            if (r < 16)       v = qw[r * 262 + c];
            else if (r < 32)  v = kw[(r - 16) * 262 + c];
            else if (r < 160) v = vw[(r - 32) * 262 + c];
        }
        wqkv[idx] = f2b(v);
    } else if (idx < 61440 + 32768) {
        int j = idx - 61440; awb[j] = f2b(aw[j]);
    } else if (idx < 61440 + 32768 + 65536) {
        int j = idx - 61440 - 32768; rwb[j] = f2b(rw[j]);
    } else if (idx < 61440 + 32768 + 131072) {
        int j = idx - 61440 - 98304; owb[j] = f2b(ow[j]);
    }
}

// ===== qkv GEMM (no LDS, direct global fragments): [192][320] @ [s][320]^T =====
__global__ __launch_bounds__(256) void qkv_gemm(
    const unsigned short* __restrict__ Wb, const unsigned short* __restrict__ Xt,
    const float* __restrict__ qb, const float* __restrict__ kb,
    const float* __restrict__ vb,
    float* __restrict__ q, float* __restrict__ k, unsigned short* __restrict__ vbt)
{
    const int b = blockIdx.x >> 5;
    const int s0 = (blockIdx.x & 31) << 7;
    const int co0 = blockIdx.y << 6;
    const int lane = threadIdx.x & 63, wv = threadIdx.x >> 6;
    const int lr = lane & 15, lg = lane >> 4;

    f32x4 acc[4][2];
#pragma unroll
    for (int mi = 0; mi < 4; ++mi)
#pragma unroll
        for (int ni = 0; ni < 2; ++ni) acc[mi][ni] = (f32x4){0.f, 0.f, 0.f, 0.f};

    const unsigned short* wp = Wb + (size_t)co0 * 320 + lg * 8;
    const unsigned short* xp = Xt + ((size_t)(b << 12) + s0 + wv * 32) * 320 + lg * 8;

#pragma unroll
    for (int kc = 0; kc < 10; ++kc) {
        int ko = kc * 32;
        bf16x8 a[4], x[2];
#pragma unroll
        for (int mi = 0; mi < 4; ++mi)
            a[mi] = *(const bf16x8*)(wp + (size_t)(mi * 16 + lr) * 320 + ko);
#pragma unroll
        for (int ni = 0; ni < 2; ++ni)
            x[ni] = *(const bf16x8*)(xp + (size_t)(ni * 16 + lr) * 320 + ko);
#pragma unroll
        for (int mi = 0; mi < 4; ++mi)
#pragma unroll
            for (int ni = 0; ni < 2; ++ni)
                acc[mi][ni] = __builtin_amdgcn_mfma_f32_16x16x32_bf16(
                    a[mi], x[ni], acc[mi][ni], 0, 0, 0);
    }
#pragma unroll
    for (int mi = 0; mi < 4; ++mi)
#pragma unroll
    for (int ni = 0; ni < 2; ++ni)
#pragma unroll
    for (int r = 0; r < 4; ++r) {
        int co = co0 + mi * 16 + lg * 4 + r;
        if (co >= 160) continue;
        int s = s0 + wv * 32 + ni * 16 + lr;
        float bias = (co < 16) ? qb[co] : ((co < 32) ? kb[co - 16] : vb[co - 32]);
        float v = acc[mi][ni][r] + bias;
        if (co < 16)      q[((size_t)(b << 12) + s) * 16 + co] = v;
        else if (co < 32) k[((size_t)(b << 12) + s) * 16 + co - 16] = v;
        else              vbt[((size_t)(b * 128 + co - 32) << 12) + s] = f2b(v);
    }
}

// dense slot packing for KV-split partials: nseg(qt) = ((qt>>2)>>3)+1 in {1..4}
__device__ __forceinline__ int qt_offset(int qt) {
    if (qt < 32) return qt;
    if (qt < 64) return 32 + (qt - 32) * 2;
    if (qt < 96) return 96 + (qt - 64) * 3;
    return 192 + (qt - 96) * 4;
}

// ===== attention partial: flash over KV segment of <=8 chunks (1024 kv) =====
// grid 1024: bx = ((b*128+qt)*4+seg); stores unnormalized (acc, m, l)
#define SWZP(row, kk) ((row) * 128 + ((kk) ^ (((row) & 15) << 3)))
__global__ __launch_bounds__(256) void attn_part(
    const float* __restrict__ qbuf, const float* __restrict__ kbuf,
    const unsigned short* __restrict__ vbt,
    float* __restrict__ pacc, float* __restrict__ pml)
{
    const int bx = blockIdx.x;
    const int b = bx >> 9;
    const int qt = (bx >> 2) & 127;
    const int seg = bx & 3;
    const int q0 = qt << 5;
    const int nch = (q0 >> 7) + 1;
    const int c_lo = seg << 3;
    if (c_lo >= nch) return;
    const int c_hi = min(c_lo + 8, nch);

    __shared__ unsigned short sP[32 * 128];
    __shared__ float sF[32];
    __shared__ float sL[32];

    const int tid = threadIdx.x;
    const int lane = tid & 63, wv = tid >> 6;
    const int lr = lane & 15, lg = lane >> 4;
    const int qq = wv * 8 + (lane >> 3), dq = lane & 7;
    const float scale = 1.0f / sqrtf(259.0f);

    float qr[16];
    {
        const float* qp = qbuf + ((size_t)(b << 12) + q0 + qq) * 16;
#pragma unroll
        for (int c = 0; c < 16; ++c) qr[c] = qp[c];
    }

    f32x4 acc[2][2];
#pragma unroll
    for (int mi = 0; mi < 2; ++mi)
#pragma unroll
        for (int ni = 0; ni < 2; ++ni) acc[mi][ni] = (f32x4){0.f, 0.f, 0.f, 0.f};
    float m = -1e30f, l = 0.0f;

    for (int kc = c_lo; kc < c_hi; ++kc) {
        const int kv0 = kc << 7;
        float sv[16];
        const float* kp = kbuf + ((size_t)(b << 12) + kv0 + dq * 16) * 16;
#pragma unroll
        for (int i = 0; i < 16; ++i) {
            float t0 = 0.f, t1 = 0.f, t2 = 0.f, t3 = 0.f;
            const float* kr = kp + i * 16;
#pragma unroll
            for (int c = 0; c < 4; ++c) {
                t0 = fmaf(qr[c],      kr[c],      t0);
                t1 = fmaf(qr[4 + c],  kr[4 + c],  t1);
                t2 = fmaf(qr[8 + c],  kr[8 + c],  t2);
                t3 = fmaf(qr[12 + c], kr[12 + c], t3);
            }
            bool valid = (kv0 + dq * 16 + i) < (q0 + qq);
            sv[i] = valid ? ((t0 + t1) + (t2 + t3)) * scale : -1e30f;
        }
        float mc = sv[0];
#pragma unroll
        for (int i = 1; i < 16; ++i) mc = fmaxf(mc, sv[i]);
        mc = fmaxf(mc, __shfl_xor(mc, 1, 64));
        mc = fmaxf(mc, __shfl_xor(mc, 2, 64));
        mc = fmaxf(mc, __shfl_xor(mc, 4, 64));
        float mn = fmaxf(m, mc);
        float fac = expf(m - mn);
        float ls = 0.f;
        unsigned int packs[8];
#pragma unroll
        for (int i2 = 0; i2 < 8; ++i2) {
            float p0 = (sv[2 * i2]     <= -1e29f) ? 0.f : expf(sv[2 * i2]     - mn);
            float p1 = (sv[2 * i2 + 1] <= -1e29f) ? 0.f : expf(sv[2 * i2 + 1] - mn);
            ls += p0 + p1;
            packs[i2] = (unsigned int)f2b(p0) | ((unsigned int)f2b(p1) << 16);
        }
        ls += __shfl_xor(ls, 1, 64);
        ls += __shfl_xor(ls, 2, 64);
        ls += __shfl_xor(ls, 4, 64);
        l = l * fac + ls;
        m = mn;
        if (dq == 0) sF[qq] = fac;
#pragma unroll
        for (int i2 = 0; i2 < 8; ++i2) {
            int kk = (dq * 16 + i2 * 2) ^ ((qq & 15) << 3);
            ((unsigned int*)sP)[(qq * 128 + kk) >> 1] = packs[i2];
        }
        __syncthreads();
#pragma unroll
        for (int mi = 0; mi < 2; ++mi)
#pragma unroll
            for (int r = 0; r < 4; ++r) {
                float f = sF[mi * 16 + lg * 4 + r];
                acc[mi][0][r] *= f;
                acc[mi][1][r] *= f;
            }
#pragma unroll
        for (int ks = 0; ks < 4; ++ks) {
            bf16x8 pa[2], vv[2];
#pragma unroll
            for (int mi = 0; mi < 2; ++mi)
                pa[mi] = *(const bf16x8*)&sP[SWZP(mi * 16 + lr, ks * 32 + lg * 8)];
#pragma unroll
            for (int ni = 0; ni < 2; ++ni)
                vv[ni] = *(const bf16x8*)(vbt +
                    ((size_t)(b * 128 + wv * 32 + ni * 16 + lr) << 12) +
                    kv0 + ks * 32 + lg * 8);
#pragma unroll
            for (int mi = 0; mi < 2; ++mi)
#pragma unroll
                for (int ni = 0; ni < 2; ++ni)
                    acc[mi][ni] = __builtin_amdgcn_mfma_f32_16x16x32_bf16(
                        pa[mi], vv[ni], acc[mi][ni], 0, 0, 0);
        }
        __syncthreads();
    }

    const int slot = b * 320 + qt_offset(qt) + seg;
    float* ap = pacc + (size_t)slot * 4096;
#pragma unroll
    for (int mi = 0; mi < 2; ++mi)
#pragma unroll
    for (int ni = 0; ni < 2; ++ni)
#pragma unroll
    for (int r = 0; r < 4; ++r) {
        int row = mi * 16 + lg * 4 + r;
        int vc = wv * 32 + ni * 16 + lr;
        ap[row * 128 + vc] = acc[mi][ni][r];
    }
    if (dq == 0) {
        pml[slot * 64 + qq * 2]     = m;
        pml[slot * 64 + qq * 2 + 1] = l;
    }
}

// ===== attention combine: merge <=4 partials, normalize, elu, write attEb =====
// grid 256 (b*128+qt), 256 threads: thread = (qq = tid>>3, vg = tid&7 -> 16 vc)
__global__ __launch_bounds__(256) void attn_combine(
    const float* __restrict__ pacc, const float* __restrict__ pml,
    unsigned short* __restrict__ attEb)
{
    const int b = blockIdx.x >> 7;
    const int qt = blockIdx.x & 127;
    const int nseg = ((qt >> 2) >> 3) + 1;
    const int base = b * 320 + qt_offset(qt);
    const int tid = threadIdx.x;
    const int qq = tid >> 3, vg = tid & 7;

    float mi_[4], li_[4];
    float m = -1e30f;
    for (int i = 0; i < nseg; ++i) {
        mi_[i] = pml[(base + i) * 64 + qq * 2];
        li_[i] = pml[(base + i) * 64 + qq * 2 + 1];
        m = fmaxf(m, mi_[i]);
    }
    float w[4];
    float l = 0.f;
    for (int i = 0; i < nseg; ++i) {
        float wi = (mi_[i] <= -1e29f) ? 0.f : expf(mi_[i] - m);
        w[i] = wi;
        l += wi * li_[i];
    }
    float inv = (l > 0.f) ? 1.f / l : 0.f;
    int q = (qt << 5) + qq;
#pragma unroll
    for (int v4 = 0; v4 < 4; ++v4) {
        int vc = vg * 16 + v4 * 4;
        float o0 = 0.f, o1 = 0.f, o2 = 0.f, o3 = 0.f;
        for (int i = 0; i < nseg; ++i) {
            f32x4 a = *(const f32x4*)(pacc + (size_t)(base + i) * 4096 + qq * 128 + vc);
            o0 = fmaf(w[i], a[0], o0);
            o1 = fmaf(w[i], a[1], o1);
            o2 = fmaf(w[i], a[2], o2);
            o3 = fmaf(w[i], a[3], o3);
        }
        unsigned short r0 = f2b(elu_f(o0 * inv));
        unsigned short r1 = f2b(elu_f(o1 * inv));
        unsigned short r2 = f2b(elu_f(o2 * inv));
        unsigned short r3 = f2b(elu_f(o3 * inv));
        ushort4 pk = {r0, r1, r2, r3};
        *(ushort4*)&attEb[((size_t)(b << 12) + q) * 128 + vc] = pk;
    }
}

// ===== final_ab GEMM: sum2b = bf16(elu( elu(W1@attEb+b1) + elu(W2@elut+b2) )) =====
__global__ __launch_bounds__(256) void final_ab_gemm(
    const unsigned short* __restrict__ W1b, const unsigned short* __restrict__ W2b,
    const unsigned short* __restrict__ X1, const unsigned short* __restrict__ X2,
    const float* __restrict__ b1, const float* __restrict__ b2,
    unsigned short* __restrict__ sum2b)
{
    const int b = blockIdx.x >> 5;
    const int s0 = (blockIdx.x & 31) << 7;
    const int co0 = blockIdx.y << 6;
    const int lane = threadIdx.x & 63, wv = threadIdx.x >> 6;
    const int lr = lane & 15, lg = lane >> 4;

    f32x4 acc1[4][2], acc2[4][2];
#pragma unroll
    for (int mi = 0; mi < 4; ++mi)
#pragma unroll
        for (int ni = 0; ni < 2; ++ni) {
            acc1[mi][ni] = (f32x4){0.f, 0.f, 0.f, 0.f};
            acc2[mi][ni] = (f32x4){0.f, 0.f, 0.f, 0.f};
        }

    {
        const unsigned short* wp = W1b + (size_t)co0 * 128 + lg * 8;
        const unsigned short* xp = X1 + ((size_t)(b << 12) + s0 + wv * 32) * 128 + lg * 8;
#pragma unroll
        for (int kc = 0; kc < 4; ++kc) {
            int ko = kc * 32;
            bf16x8 a[4], x[2];
#pragma unroll
            for (int mi = 0; mi < 4; ++mi)
                a[mi] = *(const bf16x8*)(wp + (size_t)(mi * 16 + lr) * 128 + ko);
#pragma unroll
            for (int ni = 0; ni < 2; ++ni)
                x[ni] = *(const bf16x8*)(xp + (size_t)(ni * 16 + lr) * 128 + ko);
#pragma unroll
            for (int mi = 0; mi < 4; ++mi)
#pragma unroll
                for (int ni = 0; ni < 2; ++ni)
                    acc1[mi][ni] = __builtin_amdgcn_mfma_f32_16x16x32_bf16(
                        a[mi], x[ni], acc1[mi][ni], 0, 0, 0);
        }
    }
    {
        const unsigned short* wp = W2b + (size_t)co0 * 256 + lg * 8;
        const unsigned short* xp = X2 + ((size_t)(b << 12) + s0 + wv * 32) * 256 + lg * 8;
#pragma unroll
        for (int kc = 0; kc < 8; ++kc) {
            int ko = kc * 32;
            bf16x8 a[4], x[2];
#pragma unroll
            for (int mi = 0; mi < 4; ++mi)
                a[mi] = *(const bf16x8*)(wp + (size_t)(mi * 16 + lr) * 256 + ko);
#pragma unroll
            for (int ni = 0; ni < 2; ++ni)
                x[ni] = *(const bf16x8*)(xp + (size_t)(ni * 16 + lr) * 256 + ko);
#pragma unroll
            for (int mi = 0; mi < 4; ++mi)
#pragma unroll
                for (int ni = 0; ni < 2; ++ni)
                    acc2[mi][ni] = __builtin_amdgcn_mfma_f32_16x16x32_bf16(
                        a[mi], x[ni], acc2[mi][ni], 0, 0, 0);
        }
    }
#pragma unroll
    for (int mi = 0; mi < 4; ++mi)
#pragma unroll
    for (int ni = 0; ni < 2; ++ni)
#pragma unroll
    for (int r = 0; r < 4; ++r) {
        int co = co0 + mi * 16 + lg * 4 + r;
        int s = s0 + wv * 32 + ni * 16 + lr;
        float v1 = elu_f(acc1[mi][ni][r] + b1[co]);
        float v2 = elu_f(acc2[mi][ni][r] + b2[co]);
        sum2b[((size_t)(b << 12) + s) * 256 + co] = f2b(elu_f(v1 + v2));
    }
}

// ===== final_c GEMM: out = elu(outW@sum2b + out_b), fp32 [b][256][4096] =====
__global__ __launch_bounds__(256) void final_c_gemm(
    const unsigned short* __restrict__ Wb, const unsigned short* __restrict__ Xt,
    const float* __restrict__ bias, float* __restrict__ out)
{
    const int b = blockIdx.x >> 5;
    const int s0 = (blockIdx.x & 31) << 7;
    const int co0 = blockIdx.y << 6;
    const int lane = threadIdx.x & 63, wv = threadIdx.x >> 6;
    const int lr = lane & 15, lg = lane >> 4;

    f32x4 acc[4][2];
#pragma unroll
    for (int mi = 0; mi < 4; ++mi)
#pragma unroll
        for (int ni = 0; ni < 2; ++ni) acc[mi][ni] = (f32x4){0.f, 0.f, 0.f, 0.f};

    const unsigned short* wp = Wb + (size_t)co0 * 256 + lg * 8;
    const unsigned short* xp = Xt + ((size_t)(b << 12) + s0 + wv * 32) * 256 + lg * 8;
#pragma unroll
    for (int kc = 0; kc < 8; ++kc) {
        int ko = kc * 32;
        bf16x8 a[4], x[2];
#pragma unroll
        for (int mi = 0; mi < 4; ++mi)
            a[mi] = *(const bf16x8*)(wp + (size_t)(mi * 16 + lr) * 256 + ko);
#pragma unroll
        for (int ni = 0; ni < 2; ++ni)
            x[ni] = *(const bf16x8*)(xp + (size_t)(ni * 16 + lr) * 256 + ko);
#pragma unroll
        for (int mi = 0; mi < 4; ++mi)
#pragma unroll
            for (int ni = 0; ni < 2; ++ni)
                acc[mi][ni] = __builtin_amdgcn_mfma_f32_16x16x32_bf16(
                    a[mi], x[ni], acc[mi][ni], 0, 0, 0);
    }
#pragma unroll
    for (int mi = 0; mi < 4; ++mi)
#pragma unroll
    for (int ni = 0; ni < 2; ++ni)
#pragma unroll
    for (int r = 0; r < 4; ++r) {
        int co = co0 + mi * 16 + lg * 4 + r;
        int s = s0 + wv * 32 + ni * 16 + lr;
        out[((size_t)(b * 256 + co) << 12) + s] = elu_f(acc[mi][ni][r] + bias[co]);
    }
}

extern "C" void kernel_launch(void* const* d_in, const int* in_sizes, int n_in,
                              void* d_out, int out_size, void* d_ws, size_t ws_size,
                              hipStream_t stream) {
    const float* x      = (const float*)d_in[0];
    const float* orig   = (const float*)d_in[1];
    const float* rb_w1  = (const float*)d_in[2];
    const float* rb_b1  = (const float*)d_in[3];
    const float* rb_w2  = (const float*)d_in[4];
    const float* rb_b2  = (const float*)d_in[5];
    const float* q_w    = (const float*)d_in[6];
    const float* q_b    = (const float*)d_in[7];
    const float* k_w    = (const float*)d_in[8];
    const float* k_b    = (const float*)d_in[9];
    const float* v_w    = (const float*)d_in[10];
    const float* v_b    = (const float*)d_in[11];
    const float* attn_w = (const float*)d_in[12];
    const float* attn_b = (const float*)d_in[13];
    const float* resc_w = (const float*)d_in[14];
    const float* resc_b = (const float*)d_in[15];
    const float* out_w  = (const float*)d_in[16];
    const float* out_b  = (const float*)d_in[17];
    float* out = (float*)d_out;

    char* base = (char*)d_ws;
    float*          res   = (float*)(base);                        // 8 MB
    unsigned short* eluB  = (unsigned short*)(base + (8u << 20));  // 4 MB
    unsigned short* o1b   = (unsigned short*)(base + (12u << 20)); // 4 MB
    unsigned short* w1b   = (unsigned short*)(base + (16u << 20)); // 4 MB
    unsigned short* w2b   = (unsigned short*)(base + (20u << 20)); // 8 MB
    // aliases (live after conv loop)
    unsigned short* elut  = eluB;
    unsigned short* vbt   = o1b;                                   // 2 MB
    unsigned short* attEb = (unsigned short*)(base + (12u << 20) + 2097152); // 2 MB
    unsigned short* sum2b = w1b;
    unsigned short* xqkvB = w2b;                                   // 5 MB
    float*          qbuf  = (float*)(base + (20u << 20) + 5242880);   // 512 KB
    float*          kbuf  = (float*)(base + (20u << 20) + 5767168);   // 512 KB
    unsigned short* wqkvB = (unsigned short*)(base + (20u << 20) + 6291456); // 120 KB
    unsigned short* attnWb= (unsigned short*)(base + (20u << 20) + 6414336); // 64 KB
    unsigned short* rescWb= (unsigned short*)(base + (20u << 20) + 6479872); // 128 KB
    unsigned short* outWb = (unsigned short*)(base + (20u << 20) + 6610944); // 128 KB
    // attention partials (28 MB ..): 640 slots
    float*          pacc  = (float*)(base + (28u << 20));          // 10.49 MB
    float*          pml   = (float*)(base + (28u << 20) + 10485760); // 164 KB

    prep_kernel<<<8192, 256, 0, stream>>>(x, res, eluB, 2097152);
    wcvt_kernel<<<16384, 256, 0, stream>>>(rb_w1, rb_w2, w1b, w2b,
                                           2097152, 4194304);

    for (int i = 0; i < 4; ++i) {
        conv1_mfma<<<dim3(64, 4), 256, 0, stream>>>(
            eluB, w1b + (size_t)i * 524288, rb_b1 + i * 256, o1b);
        conv2_mfma<<<dim3(64, 8), 256, 0, stream>>>(
            o1b, w2b + (size_t)i * 1048576, rb_b2 + i * 512, res, eluB);
    }

    pack_kernel<<<dim3(64, 10), 256, 0, stream>>>(res, orig, xqkvB, elut);
    wcvt2_kernel<<<880, 256, 0, stream>>>(q_w, k_w, v_w, attn_w, resc_w, out_w,
                                          wqkvB, attnWb, rescWb, outWb);

    qkv_gemm<<<dim3(64, 3), 256, 0, stream>>>(wqkvB, xqkvB, q_b, k_b, v_b,
                                              qbuf, kbuf, vbt);

    attn_part<<<1024, 256, 0, stream>>>(qbuf, kbuf, vbt, pacc, pml);
    attn_combine<<<256, 256, 0, stream>>>(pacc, pml, attEb);

    final_ab_gemm<<<dim3(64, 4), 256, 0, stream>>>(
        attnWb, rescWb, attEb, elut, attn_b, resc_b, sum2b);

    final_c_gemm<<<dim3(64, 4), 256, 0, stream>>>(outWb, sum2b, out_b, out);
}

// Round 6
// 1124.165 us; speedup vs baseline: 4.2397x; 1.1732x over previous
//
#include <hip/hip_runtime.h>
#include <math.h>

#define SEQ 4096
#define CIN 256

typedef __attribute__((ext_vector_type(8))) short bf16x8;
typedef __attribute__((ext_vector_type(4))) float f32x4;

__device__ __forceinline__ float elu_f(float x) {
    return x > 0.0f ? x : (expf(x) - 1.0f);
}
__device__ __forceinline__ unsigned short f2b(float f) {
    unsigned int u = __float_as_uint(f);
    return (unsigned short)((u + 0x7FFFu + ((u >> 16) & 1u)) >> 16);
}

// element-index swizzle for conv LDS tiles (64-element rows)
#define SWZ64(row, k)  ((row) * 64  + ((k) ^ (((row) & 7) << 3)))

// ===================== prep: res = x ; eluB = bf16(elu(x)) =====================
__global__ __launch_bounds__(256) void prep_kernel(
    const float* __restrict__ x, float* __restrict__ res,
    unsigned short* __restrict__ elub, int n)
{
    int i = blockIdx.x * 256 + threadIdx.x;
    if (i < n) { float v = x[i]; res[i] = v; elub[i] = f2b(elu_f(v)); }
}

// ===================== weight convert fp32 -> bf16 (conv weights) =====================
__global__ __launch_bounds__(256) void wcvt_kernel(
    const float* __restrict__ w1, const float* __restrict__ w2,
    unsigned short* __restrict__ w1b, unsigned short* __restrict__ w2b,
    int n1, int n2)
{
    int i = blockIdx.x * 256 + threadIdx.x;
    if (i < n1) w1b[i] = f2b(w1[i]);
    if (i < n2) w2b[i] = f2b(w2[i]);
}

// ========== conv1 (MFMA implicit GEMM): o1 = elu(conv2x2x2(eluRes) + b1) ==========
__global__ __launch_bounds__(256) void conv1_mfma(
    const unsigned short* __restrict__ inb,
    const unsigned short* __restrict__ wb,
    const float* __restrict__ bias,
    unsigned short* __restrict__ outb)
{
    __shared__ unsigned short sA[64 * 64];
    __shared__ unsigned short sX[128 * 64];

    const int slab = blockIdx.x;
    const int bb = slab >> 5, t = (slab >> 1) & 15, h0 = (slab & 1) * 8;
    const int co0 = blockIdx.y * 64;
    const int tid = threadIdx.x;
    const int lane = tid & 63, wv = tid >> 6;
    const int lr = lane & 15, lg = lane >> 4;

    f32x4 acc[4][2];
#pragma unroll
    for (int mi = 0; mi < 4; ++mi)
#pragma unroll
        for (int ni = 0; ni < 2; ++ni) acc[mi][ni] = (f32x4){0.f, 0.f, 0.f, 0.f};

    const int rA = tid >> 2, kA = (tid & 3) * 16;
    const unsigned short* srcA = wb + (size_t)(co0 + rA) * 2048 + kA;

    for (int kc = 0; kc < 32; ++kc) {
        const unsigned short* sa = srcA + kc * 64;
#pragma unroll
        for (int q = 0; q < 4; ++q) {
            ushort4 v4 = *(const ushort4*)(sa + q * 4);
            *(ushort4*)&sA[SWZ64(rA, kA + q * 4)] = v4;
        }
#pragma unroll
        for (int uu = 0; uu < 2; ++uu) {
            int uid = tid + 256 * uu;
            int kk = uid & 63, hh = uid >> 6;
            int ci = (kc << 3) + (kk >> 3);
            int tap = kk & 7;
            int tt = t - 1 + (tap >> 2);
            int sh = h0 + hh - 1 + ((tap >> 1) & 1);
            int kw = tap & 1;
            const unsigned short* src = inb + (((bb * 256 + ci) * 16 + tt) * 256 + sh * 16);
            bool rowok = (tt >= 0) && (sh >= 0);
#pragma unroll
            for (int w = 0; w < 16; ++w) {
                int sw = w - 1 + kw;
                unsigned short val = (rowok && sw >= 0) ? src[sw] : (unsigned short)0;
                sX[SWZ64(hh * 16 + w, kk)] = val;
            }
        }
        __syncthreads();
#pragma unroll
        for (int ks = 0; ks < 2; ++ks) {
            bf16x8 a[4], bv[2];
#pragma unroll
            for (int mi = 0; mi < 4; ++mi)
                a[mi] = *(const bf16x8*)&sA[SWZ64(mi * 16 + lr, ks * 32 + lg * 8)];
#pragma unroll
            for (int ni = 0; ni < 2; ++ni) {
                int n = wv * 32 + ni * 16 + lr;
                bv[ni] = *(const bf16x8*)&sX[SWZ64(n, ks * 32 + lg * 8)];
            }
#pragma unroll
            for (int mi = 0; mi < 4; ++mi)
#pragma unroll
                for (int ni = 0; ni < 2; ++ni)
                    acc[mi][ni] = __builtin_amdgcn_mfma_f32_16x16x32_bf16(
                        a[mi], bv[ni], acc[mi][ni], 0, 0, 0);
        }
        __syncthreads();
    }
#pragma unroll
    for (int mi = 0; mi < 4; ++mi) {
#pragma unroll
        for (int ni = 0; ni < 2; ++ni) {
            int pos = h0 * 16 + wv * 32 + ni * 16 + lr;
#pragma unroll
            for (int r = 0; r < 4; ++r) {
                int co = co0 + mi * 16 + lg * 4 + r;
                float v = acc[mi][ni][r] + bias[co];
                outb[((bb * 256 + co) * 16 + t) * 256 + pos] = f2b(elu_f(v));
            }
        }
    }
}

// ========== conv2 (MFMA) + gate: res += a*sigmoid(g); eluB = bf16(elu(res)) ==========
__global__ __launch_bounds__(256) void conv2_mfma(
    const unsigned short* __restrict__ inb,
    const unsigned short* __restrict__ wb,
    const float* __restrict__ bias,
    float* __restrict__ resf,
    unsigned short* __restrict__ elub)
{
    __shared__ unsigned short sA[64 * 64];
    __shared__ unsigned short sX[128 * 64];

    const int slab = blockIdx.x;
    const int bb = slab >> 5, t = (slab >> 1) & 15, h0 = (slab & 1) * 8;
    const int c0 = blockIdx.y * 32;
    const int tid = threadIdx.x;
    const int lane = tid & 63, wv = tid >> 6;
    const int lr = lane & 15, lg = lane >> 4;

    f32x4 acc[4][2];
#pragma unroll
    for (int mi = 0; mi < 4; ++mi)
#pragma unroll
        for (int ni = 0; ni < 2; ++ni) acc[mi][ni] = (f32x4){0.f, 0.f, 0.f, 0.f};

    const int rA = tid >> 2, kA = (tid & 3) * 16;
    const int rowIdx = (rA < 32) ? (c0 + rA) : (256 + c0 + rA - 32);
    const unsigned short* srcA = wb + (size_t)rowIdx * 2048 + kA;

    for (int kc = 0; kc < 32; ++kc) {
        const unsigned short* sa = srcA + kc * 64;
#pragma unroll
        for (int q = 0; q < 4; ++q) {
            ushort4 v4 = *(const ushort4*)(sa + q * 4);
            *(ushort4*)&sA[SWZ64(rA, kA + q * 4)] = v4;
        }
#pragma unroll
        for (int uu = 0; uu < 2; ++uu) {
            int uid = tid + 256 * uu;
            int kk = uid & 63, hh = uid >> 6;
            int ci = (kc << 3) + (kk >> 3);
            int tap = kk & 7;
            int tt = t - 1 + (tap >> 2);
            int sh = h0 + hh - 1 + ((tap >> 1) & 1);
            int kw = tap & 1;
            const unsigned short* src = inb + (((bb * 256 + ci) * 16 + tt) * 256 + sh * 16);
            bool rowok = (tt >= 0) && (sh >= 0);
#pragma unroll
            for (int w = 0; w < 16; ++w) {
                int sw = w - 1 + kw;
                unsigned short val = (rowok && sw >= 0) ? src[sw] : (unsigned short)0;
                sX[SWZ64(hh * 16 + w, kk)] = val;
            }
        }
        __syncthreads();
#pragma unroll
        for (int ks = 0; ks < 2; ++ks) {
            bf16x8 a[4], bv[2];
#pragma unroll
            for (int mi = 0; mi < 4; ++mi)
                a[mi] = *(const bf16x8*)&sA[SWZ64(mi * 16 + lr, ks * 32 + lg * 8)];
#pragma unroll
            for (int ni = 0; ni < 2; ++ni) {
                int n = wv * 32 + ni * 16 + lr;
                bv[ni] = *(const bf16x8*)&sX[SWZ64(n, ks * 32 + lg * 8)];
            }
#pragma unroll
            for (int mi = 0; mi < 4; ++mi)
#pragma unroll
                for (int ni = 0; ni < 2; ++ni)
                    acc[mi][ni] = __builtin_amdgcn_mfma_f32_16x16x32_bf16(
                        a[mi], bv[ni], acc[mi][ni], 0, 0, 0);
        }
        __syncthreads();
    }
#pragma unroll
    for (int mi = 0; mi < 2; ++mi) {
#pragma unroll
        for (int ni = 0; ni < 2; ++ni) {
            int pos = h0 * 16 + wv * 32 + ni * 16 + lr;
#pragma unroll
            for (int r = 0; r < 4; ++r) {
                int co = c0 + mi * 16 + lg * 4 + r;
                float av = acc[mi][ni][r] + bias[co];
                float gv = acc[mi + 2][ni][r] + bias[co + 256];
                float add = av / (1.0f + expf(-gv));
                size_t idx = (size_t)((bb * 256 + co) * 16 + t) * 256 + pos;
                float rn = resf[idx] + add;
                resf[idx] = rn;
                elub[idx] = f2b(elu_f(rn));
            }
        }
    }
}

// ===== pack: xq[b][s][320] = bf16(res | orig | pos | 0); elut[b][s][256] = bf16(elu(res)) =====
__global__ __launch_bounds__(256) void pack_kernel(
    const float* __restrict__ res, const float* __restrict__ orig,
    unsigned short* __restrict__ xq, unsigned short* __restrict__ elut)
{
    const int b = blockIdx.x >> 5;
    const int s0 = (blockIdx.x & 31) << 7;
    const int cg = blockIdx.y;
    const int tid = threadIdx.x;
    const int s = s0 + (tid & 127);
    const int c0 = cg * 32 + (tid >> 7) * 16;

    unsigned short xv[16], ev[16];
    if (cg < 8) {
#pragma unroll
        for (int cc = 0; cc < 16; ++cc) {
            int c = c0 + cc;
            float v = res[(size_t)((b * 256 + c) << 12) + s];
            xv[cc] = f2b(v);
            ev[cc] = f2b(elu_f(v));
        }
        *(ushort4*)&elut[((size_t)(b << 12) + s) * 256 + c0]      = *(ushort4*)&ev[0];
        *(ushort4*)&elut[((size_t)(b << 12) + s) * 256 + c0 + 4]  = *(ushort4*)&ev[4];
        *(ushort4*)&elut[((size_t)(b << 12) + s) * 256 + c0 + 8]  = *(ushort4*)&ev[8];
        *(ushort4*)&elut[((size_t)(b << 12) + s) * 256 + c0 + 12] = *(ushort4*)&ev[12];
    } else if (cg == 8) {
#pragma unroll
        for (int cc = 0; cc < 16; ++cc) {
            int c = c0 + cc;
            float v;
            if (c < 259)      v = orig[(size_t)((b * 3 + (c - 256)) << 12) + s];
            else if (c == 259) v = -0.5f + (float)(s >> 8) * 0.0625f;
            else if (c == 260) v = -0.5f + (float)((s >> 4) & 15) * 0.0625f;
            else if (c == 261) v = -0.5f + (float)(s & 15) * 0.0625f;
            else               v = 0.0f;
            xv[cc] = f2b(v);
        }
    } else {
#pragma unroll
        for (int cc = 0; cc < 16; ++cc) xv[cc] = 0;
    }
    unsigned short* xp = &xq[((size_t)(b << 12) + s) * 320 + c0];
    *(ushort4*)(xp)      = *(ushort4*)&xv[0];
    *(ushort4*)(xp + 4)  = *(ushort4*)&xv[4];
    *(ushort4*)(xp + 8)  = *(ushort4*)&xv[8];
    *(ushort4*)(xp + 12) = *(ushort4*)&xv[12];
}

// ===== wcvt2: pack qkv weights [192][320] (zero-pad) + attn/resc/out weights -> bf16 =====
__global__ __launch_bounds__(256) void wcvt2_kernel(
    const float* __restrict__ qw, const float* __restrict__ kw,
    const float* __restrict__ vw, const float* __restrict__ aw,
    const float* __restrict__ rw, const float* __restrict__ ow,
    unsigned short* __restrict__ wqkv, unsigned short* __restrict__ awb,
    unsigned short* __restrict__ rwb, unsigned short* __restrict__ owb)
{
    int idx = blockIdx.x * 256 + threadIdx.x;
    if (idx < 61440) {
        int r = idx / 320, c = idx - r * 320;
        float v = 0.0f;
        if (c < 262) {
            if (r < 16)       v = qw[r * 262 + c];
            else if (r < 32)  v = kw[(r - 16) * 262 + c];
            else if (r < 160) v = vw[(r - 32) * 262 + c];
        }
        wqkv[idx] = f2b(v);
    } else if (idx < 61440 + 32768) {
        int j = idx - 61440; awb[j] = f2b(aw[j]);
    } else if (idx < 61440 + 32768 + 65536) {
        int j = idx - 61440 - 32768; rwb[j] = f2b(rw[j]);
    } else if (idx < 61440 + 32768 + 131072) {
        int j = idx - 61440 - 98304; owb[j] = f2b(ow[j]);
    }
}

// ===== qkv GEMM: [192][320] @ [s][320]^T ; q,k -> bf16 [s][16]; v -> bf16 [vc][s] =====
__global__ __launch_bounds__(256) void qkv_gemm(
    const unsigned short* __restrict__ Wb, const unsigned short* __restrict__ Xt,
    const float* __restrict__ qb, const float* __restrict__ kb,
    const float* __restrict__ vb,
    unsigned short* __restrict__ qbt, unsigned short* __restrict__ kbt,
    unsigned short* __restrict__ vbt)
{
    const int b = blockIdx.x >> 5;
    const int s0 = (blockIdx.x & 31) << 7;
    const int co0 = blockIdx.y << 6;
    const int lane = threadIdx.x & 63, wv = threadIdx.x >> 6;
    const int lr = lane & 15, lg = lane >> 4;

    f32x4 acc[4][2];
#pragma unroll
    for (int mi = 0; mi < 4; ++mi)
#pragma unroll
        for (int ni = 0; ni < 2; ++ni) acc[mi][ni] = (f32x4){0.f, 0.f, 0.f, 0.f};

    const unsigned short* wp = Wb + (size_t)co0 * 320 + lg * 8;
    const unsigned short* xp = Xt + ((size_t)(b << 12) + s0 + wv * 32) * 320 + lg * 8;

#pragma unroll
    for (int kc = 0; kc < 10; ++kc) {
        int ko = kc * 32;
        bf16x8 a[4], x[2];
#pragma unroll
        for (int mi = 0; mi < 4; ++mi)
            a[mi] = *(const bf16x8*)(wp + (size_t)(mi * 16 + lr) * 320 + ko);
#pragma unroll
        for (int ni = 0; ni < 2; ++ni)
            x[ni] = *(const bf16x8*)(xp + (size_t)(ni * 16 + lr) * 320 + ko);
#pragma unroll
        for (int mi = 0; mi < 4; ++mi)
#pragma unroll
            for (int ni = 0; ni < 2; ++ni)
                acc[mi][ni] = __builtin_amdgcn_mfma_f32_16x16x32_bf16(
                    a[mi], x[ni], acc[mi][ni], 0, 0, 0);
    }
#pragma unroll
    for (int mi = 0; mi < 4; ++mi)
#pragma unroll
    for (int ni = 0; ni < 2; ++ni)
#pragma unroll
    for (int r = 0; r < 4; ++r) {
        int co = co0 + mi * 16 + lg * 4 + r;
        if (co >= 160) continue;
        int s = s0 + wv * 32 + ni * 16 + lr;
        float bias = (co < 16) ? qb[co] : ((co < 32) ? kb[co - 16] : vb[co - 32]);
        float v = acc[mi][ni][r] + bias;
        if (co < 16)      qbt[((size_t)(b << 12) + s) * 16 + co] = f2b(v);
        else if (co < 32) kbt[((size_t)(b << 12) + s) * 16 + (co - 16)] = f2b(v);
        else              vbt[((size_t)((b << 7) + (co - 32)) << 12) + s] = f2b(v);
    }
}

// ===== attention partial v2: MFMA QK^T + in-register softmax (swapped operands) =====
// grid 512: bx = ((b*64+qt)*4+seg); q-tile 64 (4 waves x 16 q), seg = 8 chunks of 128 kv
__global__ __launch_bounds__(256) void attn_part2(
    const unsigned short* __restrict__ qbt, const unsigned short* __restrict__ kbt,
    const unsigned short* __restrict__ vbt,
    float* __restrict__ pacc, float* __restrict__ pml)
{
    const int bx = blockIdx.x;
    const int b = bx >> 8;
    const int qt = (bx >> 2) & 63;
    const int seg = bx & 3;
    const int q0 = qt << 6;
    const int nch = (qt >> 1) + 1;
    const int c_lo = seg << 3;
    if (c_lo >= nch) return;
    const int c_hi = min(c_lo + 8, nch);

    __shared__ unsigned short sK[128 * 16];      // 4 KB: K chunk [kv][ch]
    __shared__ unsigned short sP[4][16 * 136];   // per-wave P [q16][kv128], pad-136

    const int tid = threadIdx.x;
    const int lane = tid & 63, wv = tid >> 6;
    const int lr = lane & 15, lg = lane >> 4;
    const int qa = q0 + wv * 16 + lr;            // this lane's q column
    const float scale = 1.0f / sqrtf(259.0f);

    // Q B-fragment (col q = lr, k-rows ch = lg*8+j; ch>=16 -> zero)
    bf16x8 qf = (bf16x8){0, 0, 0, 0, 0, 0, 0, 0};
    if (lg < 2)
        qf = *(const bf16x8*)(qbt + ((size_t)(b << 12) + qa) * 16 + lg * 8);

    f32x4 oacc[8];
#pragma unroll
    for (int vct = 0; vct < 8; ++vct) oacc[vct] = (f32x4){0.f, 0.f, 0.f, 0.f};
    float m = -1e30f, l = 0.0f;

    unsigned short* myP = &sP[wv][0];

    for (int kc = c_lo; kc < c_hi; ++kc) {
        const int kv0 = kc << 7;
        __syncthreads();   // prev chunk's sK reads complete
        // stage K chunk: 1 x 16B per thread, coalesced
        *(bf16x8*)&sK[(tid >> 1) * 16 + (tid & 1) * 8] =
            *(const bf16x8*)(kbt + ((size_t)(b << 12) + kv0 + (tid >> 1)) * 16 + (tid & 1) * 8);
        __syncthreads();

        // scores: S^T tiles (kv x q), one mfma per 16-kv tile (K=32, upper 16 ch zero)
        f32x4 sc[8];
#pragma unroll
        for (int kvt = 0; kvt < 8; ++kvt) {
            bf16x8 af = (bf16x8){0, 0, 0, 0, 0, 0, 0, 0};
            if (lg < 2)
                af = *(const bf16x8*)&sK[(kvt * 16 + lr) * 16 + lg * 8];
            sc[kvt] = __builtin_amdgcn_mfma_f32_16x16x32_bf16(
                af, qf, (f32x4){0.f, 0.f, 0.f, 0.f}, 0, 0, 0);
        }
        // mask + scale; per-lane kv = kv0 + kvt*16 + lg*4 + r, all for q = qa
        float mc = -1e30f;
#pragma unroll
        for (int kvt = 0; kvt < 8; ++kvt) {
#pragma unroll
            for (int r = 0; r < 4; ++r) {
                int kv = kv0 + kvt * 16 + lg * 4 + r;
                float s = (kv < qa) ? sc[kvt][r] * scale : -1e30f;
                sc[kvt][r] = s;
                mc = fmaxf(mc, s);
            }
        }
        mc = fmaxf(mc, __shfl_xor(mc, 16, 64));
        mc = fmaxf(mc, __shfl_xor(mc, 32, 64));
        float mn = fmaxf(m, mc);
        float fac = __expf(m - mn);
        float ls = 0.0f;
#pragma unroll
        for (int kvt = 0; kvt < 8; ++kvt) {
#pragma unroll
            for (int e = 0; e < 2; ++e) {
                float s0v = sc[kvt][2 * e];
                float s1v = sc[kvt][2 * e + 1];
                float p0 = (s0v <= -1e29f) ? 0.f : __expf(s0v - mn);
                float p1 = (s1v <= -1e29f) ? 0.f : __expf(s1v - mn);
                ls += p0 + p1;
                unsigned int pk = (unsigned int)f2b(p0) | ((unsigned int)f2b(p1) << 16);
                int kv = kvt * 16 + lg * 4 + 2 * e;
                *(unsigned int*)&myP[lr * 136 + kv] = pk;
            }
        }
        ls += __shfl_xor(ls, 16, 64);
        ls += __shfl_xor(ls, 32, 64);
        l = l * fac + ls;
        m = mn;
        // rescale O (per-lane scalar: all regs belong to q = qa)
#pragma unroll
        for (int vct = 0; vct < 8; ++vct) {
            oacc[vct][0] *= fac; oacc[vct][1] *= fac;
            oacc[vct][2] *= fac; oacc[vct][3] *= fac;
        }
        // PV: O^T(vc x q) += V^T(vc x kv) @ P^T(kv x q)
#pragma unroll
        for (int ks = 0; ks < 4; ++ks) {
            bf16x8 pf = *(const bf16x8*)&myP[lr * 136 + ks * 32 + lg * 8];
#pragma unroll
            for (int vct = 0; vct < 8; ++vct) {
                bf16x8 vf = *(const bf16x8*)(vbt +
                    ((size_t)((b << 7) + vct * 16 + lr) << 12) + kv0 + ks * 32 + lg * 8);
                oacc[vct] = __builtin_amdgcn_mfma_f32_16x16x32_bf16(
                    vf, pf, oacc[vct], 0, 0, 0);
            }
        }
    }

    // store partial (dense slot packing: nseg(qt) = (qt>>4)+1)
    const int a_ = qt >> 4;
    const int slot = b * 160 + 8 * a_ * (a_ + 1) + (qt & 15) * (a_ + 1) + seg;
    float* ap = pacc + (size_t)slot * 8192;
#pragma unroll
    for (int vct = 0; vct < 8; ++vct)
        *(f32x4*)&ap[(wv * 16 + lr) * 128 + vct * 16 + lg * 4] = oacc[vct];
    if (lg == 0) {
        pml[slot * 128 + (wv * 16 + lr) * 2]     = m;
        pml[slot * 128 + (wv * 16 + lr) * 2 + 1] = l;
    }
}

// ===== attention combine v2: merge <=4 partials over 64q x 128vc, elu, write attEb =====
// grid 256: bx = (b*64+qt)*2 + half(32 q rows each)
__global__ __launch_bounds__(256) void attn_combine2(
    const float* __restrict__ pacc, const float* __restrict__ pml,
    unsigned short* __restrict__ attEb)
{
    const int bx = blockIdx.x;
    const int b = bx >> 7;
    const int qt = (bx >> 1) & 63;
    const int half = bx & 1;
    const int a_ = qt >> 4;
    const int nseg_alloc = a_ + 1;
    const int nch = (qt >> 1) + 1;
    const int nseg = (nch + 7) >> 3;          // actual segments with work
    const int base = b * 160 + 8 * a_ * (a_ + 1) + (qt & 15) * nseg_alloc;
    const int tid = threadIdx.x;
    const int qq = (tid >> 3) + half * 32;    // 0..63
    const int vg = tid & 7;

    float mi_[4], li_[4];
    float m = -1e30f;
    for (int i = 0; i < nseg; ++i) {
        mi_[i] = pml[(base + i) * 128 + qq * 2];
        li_[i] = pml[(base + i) * 128 + qq * 2 + 1];
        m = fmaxf(m, mi_[i]);
    }
    float w[4];
    float l = 0.f;
    for (int i = 0; i < nseg; ++i) {
        float wi = (mi_[i] <= -1e29f) ? 0.f : __expf(mi_[i] - m);
        w[i] = wi;
        l += wi * li_[i];
    }
    float inv = (l > 0.f) ? 1.f / l : 0.f;
    int q = (qt << 6) + qq;
#pragma unroll
    for (int v4 = 0; v4 < 4; ++v4) {
        int vc = vg * 16 + v4 * 4;
        float o0 = 0.f, o1 = 0.f, o2 = 0.f, o3 = 0.f;
        for (int i = 0; i < nseg; ++i) {
            f32x4 a = *(const f32x4*)(pacc + (size_t)(base + i) * 8192 + qq * 128 + vc);
            o0 = fmaf(w[i], a[0], o0);
            o1 = fmaf(w[i], a[1], o1);
            o2 = fmaf(w[i], a[2], o2);
            o3 = fmaf(w[i], a[3], o3);
        }
        unsigned short r0 = f2b(elu_f(o0 * inv));
        unsigned short r1 = f2b(elu_f(o1 * inv));
        unsigned short r2 = f2b(elu_f(o2 * inv));
        unsigned short r3 = f2b(elu_f(o3 * inv));
        ushort4 pk = {r0, r1, r2, r3};
        *(ushort4*)&attEb[((size_t)(b << 12) + q) * 128 + vc] = pk;
    }
}

// ===== final_ab GEMM: sum2b = bf16(elu( elu(W1@attEb+b1) + elu(W2@elut+b2) )) =====
__global__ __launch_bounds__(256) void final_ab_gemm(
    const unsigned short* __restrict__ W1b, const unsigned short* __restrict__ W2b,
    const unsigned short* __restrict__ X1, const unsigned short* __restrict__ X2,
    const float* __restrict__ b1, const float* __restrict__ b2,
    unsigned short* __restrict__ sum2b)
{
    const int b = blockIdx.x >> 5;
    const int s0 = (blockIdx.x & 31) << 7;
    const int co0 = blockIdx.y << 6;
    const int lane = threadIdx.x & 63, wv = threadIdx.x >> 6;
    const int lr = lane & 15, lg = lane >> 4;

    f32x4 acc1[4][2], acc2[4][2];
#pragma unroll
    for (int mi = 0; mi < 4; ++mi)
#pragma unroll
        for (int ni = 0; ni < 2; ++ni) {
            acc1[mi][ni] = (f32x4){0.f, 0.f, 0.f, 0.f};
            acc2[mi][ni] = (f32x4){0.f, 0.f, 0.f, 0.f};
        }

    {
        const unsigned short* wp = W1b + (size_t)co0 * 128 + lg * 8;
        const unsigned short* xp = X1 + ((size_t)(b << 12) + s0 + wv * 32) * 128 + lg * 8;
#pragma unroll
        for (int kc = 0; kc < 4; ++kc) {
            int ko = kc * 32;
            bf16x8 a[4], x[2];
#pragma unroll
            for (int mi = 0; mi < 4; ++mi)
                a[mi] = *(const bf16x8*)(wp + (size_t)(mi * 16 + lr) * 128 + ko);
#pragma unroll
            for (int ni = 0; ni < 2; ++ni)
                x[ni] = *(const bf16x8*)(xp + (size_t)(ni * 16 + lr) * 128 + ko);
#pragma unroll
            for (int mi = 0; mi < 4; ++mi)
#pragma unroll
                for (int ni = 0; ni < 2; ++ni)
                    acc1[mi][ni] = __builtin_amdgcn_mfma_f32_16x16x32_bf16(
                        a[mi], x[ni], acc1[mi][ni], 0, 0, 0);
        }
    }
    {
        const unsigned short* wp = W2b + (size_t)co0 * 256 + lg * 8;
        const unsigned short* xp = X2 + ((size_t)(b << 12) + s0 + wv * 32) * 256 + lg * 8;
#pragma unroll
        for (int kc = 0; kc < 8; ++kc) {
            int ko = kc * 32;
            bf16x8 a[4], x[2];
#pragma unroll
            for (int mi = 0; mi < 4; ++mi)
                a[mi] = *(const bf16x8*)(wp + (size_t)(mi * 16 + lr) * 256 + ko);
#pragma unroll
            for (int ni = 0; ni < 2; ++ni)
                x[ni] = *(const bf16x8*)(xp + (size_t)(ni * 16 + lr) * 256 + ko);
#pragma unroll
            for (int mi = 0; mi < 4; ++mi)
#pragma unroll
                for (int ni = 0; ni < 2; ++ni)
                    acc2[mi][ni] = __builtin_amdgcn_mfma_f32_16x16x32_bf16(
                        a[mi], x[ni], acc2[mi][ni], 0, 0, 0);
        }
    }
#pragma unroll
    for (int mi = 0; mi < 4; ++mi)
#pragma unroll
    for (int ni = 0; ni < 2; ++ni)
#pragma unroll
    for (int r = 0; r < 4; ++r) {
        int co = co0 + mi * 16 + lg * 4 + r;
        int s = s0 + wv * 32 + ni * 16 + lr;
        float v1 = elu_f(acc1[mi][ni][r] + b1[co]);
        float v2 = elu_f(acc2[mi][ni][r] + b2[co]);
        sum2b[((size_t)(b << 12) + s) * 256 + co] = f2b(elu_f(v1 + v2));
    }
}

// ===== final_c GEMM: out = elu(outW@sum2b + out_b), fp32 [b][256][4096] =====
__global__ __launch_bounds__(256) void final_c_gemm(
    const unsigned short* __restrict__ Wb, const unsigned short* __restrict__ Xt,
    const float* __restrict__ bias, float* __restrict__ out)
{
    const int b = blockIdx.x >> 5;
    const int s0 = (blockIdx.x & 31) << 7;
    const int co0 = blockIdx.y << 6;
    const int lane = threadIdx.x & 63, wv = threadIdx.x >> 6;
    const int lr = lane & 15, lg = lane >> 4;

    f32x4 acc[4][2];
#pragma unroll
    for (int mi = 0; mi < 4; ++mi)
#pragma unroll
        for (int ni = 0; ni < 2; ++ni) acc[mi][ni] = (f32x4){0.f, 0.f, 0.f, 0.f};

    const unsigned short* wp = Wb + (size_t)co0 * 256 + lg * 8;
    const unsigned short* xp = Xt + ((size_t)(b << 12) + s0 + wv * 32) * 256 + lg * 8;
#pragma unroll
    for (int kc = 0; kc < 8; ++kc) {
        int ko = kc * 32;
        bf16x8 a[4], x[2];
#pragma unroll
        for (int mi = 0; mi < 4; ++mi)
            a[mi] = *(const bf16x8*)(wp + (size_t)(mi * 16 + lr) * 256 + ko);
#pragma unroll
        for (int ni = 0; ni < 2; ++ni)
            x[ni] = *(const bf16x8*)(xp + (size_t)(ni * 16 + lr) * 256 + ko);
#pragma unroll
        for (int mi = 0; mi < 4; ++mi)
#pragma unroll
            for (int ni = 0; ni < 2; ++ni)
                acc[mi][ni] = __builtin_amdgcn_mfma_f32_16x16x32_bf16(
                    a[mi], x[ni], acc[mi][ni], 0, 0, 0);
    }
#pragma unroll
    for (int mi = 0; mi < 4; ++mi)
#pragma unroll
    for (int ni = 0; ni < 2; ++ni)
#pragma unroll
    for (int r = 0; r < 4; ++r) {
        int co = co0 + mi * 16 + lg * 4 + r;
        int s = s0 + wv * 32 + ni * 16 + lr;
        out[((size_t)(b * 256 + co) << 12) + s] = elu_f(acc[mi][ni][r] + bias[co]);
    }
}

extern "C" void kernel_launch(void* const* d_in, const int* in_sizes, int n_in,
                              void* d_out, int out_size, void* d_ws, size_t ws_size,
                              hipStream_t stream) {
    const float* x      = (const float*)d_in[0];
    const float* orig   = (const float*)d_in[1];
    const float* rb_w1  = (const float*)d_in[2];
    const float* rb_b1  = (const float*)d_in[3];
    const float* rb_w2  = (const float*)d_in[4];
    const float* rb_b2  = (const float*)d_in[5];
    const float* q_w    = (const float*)d_in[6];
    const float* q_b    = (const float*)d_in[7];
    const float* k_w    = (const float*)d_in[8];
    const float* k_b    = (const float*)d_in[9];
    const float* v_w    = (const float*)d_in[10];
    const float* v_b    = (const float*)d_in[11];
    const float* attn_w = (const float*)d_in[12];
    const float* attn_b = (const float*)d_in[13];
    const float* resc_w = (const float*)d_in[14];
    const float* resc_b = (const float*)d_in[15];
    const float* out_w  = (const float*)d_in[16];
    const float* out_b  = (const float*)d_in[17];
    float* out = (float*)d_out;

    char* base = (char*)d_ws;
    float*          res   = (float*)(base);                        // 8 MB
    unsigned short* eluB  = (unsigned short*)(base + (8u << 20));  // 4 MB
    unsigned short* o1b   = (unsigned short*)(base + (12u << 20)); // 4 MB
    unsigned short* w1b   = (unsigned short*)(base + (16u << 20)); // 4 MB
    unsigned short* w2b   = (unsigned short*)(base + (20u << 20)); // 8 MB
    // aliases (live after conv loop)
    unsigned short* elut  = eluB;
    unsigned short* vbt   = o1b;                                   // 2 MB
    unsigned short* attEb = (unsigned short*)(base + (12u << 20) + 2097152); // 2 MB
    unsigned short* sum2b = w1b;
    unsigned short* xqkvB = w2b;                                   // 5 MB
    unsigned short* qbt   = (unsigned short*)(base + (20u << 20) + 5242880); // 256 KB
    unsigned short* kbt   = (unsigned short*)(base + (20u << 20) + 5505024); // 256 KB
    unsigned short* wqkvB = (unsigned short*)(base + (20u << 20) + 5767168); // 120 KB
    unsigned short* attnWb= (unsigned short*)(base + (20u << 20) + 5890048); // 64 KB
    unsigned short* rescWb= (unsigned short*)(base + (20u << 20) + 5955584); // 128 KB
    unsigned short* outWb = (unsigned short*)(base + (20u << 20) + 6086656); // 128 KB
    // attention partials: 320 dense slots
    float*          pacc  = (float*)(base + (28u << 20));            // 10 MB
    float*          pml   = (float*)(base + (28u << 20) + 10485760); // 160 KB

    prep_kernel<<<8192, 256, 0, stream>>>(x, res, eluB, 2097152);
    wcvt_kernel<<<16384, 256, 0, stream>>>(rb_w1, rb_w2, w1b, w2b,
                                           2097152, 4194304);

    for (int i = 0; i < 4; ++i) {
        conv1_mfma<<<dim3(64, 4), 256, 0, stream>>>(
            eluB, w1b + (size_t)i * 524288, rb_b1 + i * 256, o1b);
        conv2_mfma<<<dim3(64, 8), 256, 0, stream>>>(
            o1b, w2b + (size_t)i * 1048576, rb_b2 + i * 512, res, eluB);
    }

    pack_kernel<<<dim3(64, 10), 256, 0, stream>>>(res, orig, xqkvB, elut);
    wcvt2_kernel<<<880, 256, 0, stream>>>(q_w, k_w, v_w, attn_w, resc_w, out_w,
                                          wqkvB, attnWb, rescWb, outWb);

    qkv_gemm<<<dim3(64, 3), 256, 0, stream>>>(wqkvB, xqkvB, q_b, k_b, v_b,
                                              qbt, kbt, vbt);

    attn_part2<<<512, 256, 0, stream>>>(qbt, kbt, vbt, pacc, pml);
    attn_combine2<<<256, 256, 0, stream>>>(pacc, pml, attEb);

    final_ab_gemm<<<dim3(64, 4), 256, 0, stream>>>(
        attnWb, rescWb, attEb, elut, attn_b, resc_b, sum2b);

    final_c_gemm<<<dim3(64, 4), 256, 0, stream>>>(outWb, sum2b, out_b, out);
}

// Round 7
// 809.148 us; speedup vs baseline: 5.8903x; 1.3893x over previous
//
#include <hip/hip_runtime.h>
#include <math.h>

#define SEQ 4096
#define CIN 256

typedef __attribute__((ext_vector_type(8))) short bf16x8;
typedef __attribute__((ext_vector_type(4))) float f32x4;

__device__ __forceinline__ float elu_f(float x) {
    return x > 0.0f ? x : (expf(x) - 1.0f);
}
__device__ __forceinline__ unsigned short f2b(float f) {
    unsigned int u = __float_as_uint(f);
    return (unsigned short)((u + 0x7FFFu + ((u >> 16) & 1u)) >> 16);
}

// ===== prep_t: elubT[b][s][256] = bf16(elu(x)) (channel-last transpose) =====
// grid (64, 8), 256 threads
__global__ __launch_bounds__(256) void prep_t(
    const float* __restrict__ x, unsigned short* __restrict__ elub)
{
    const int b = blockIdx.x >> 5;
    const int s0 = (blockIdx.x & 31) << 7;
    const int cg = blockIdx.y;
    const int tid = threadIdx.x;
    const int s = s0 + (tid & 127);
    const int c0 = cg * 32 + (tid >> 7) * 16;
    unsigned short ev[16];
#pragma unroll
    for (int cc = 0; cc < 16; ++cc) {
        float v = x[(((size_t)(b * 256 + c0 + cc)) << 12) + s];
        ev[cc] = f2b(elu_f(v));
    }
    unsigned short* ep = &elub[(((size_t)(b << 12) + s) << 8) + c0];
    *(ushort4*)(ep)      = *(ushort4*)&ev[0];
    *(ushort4*)(ep + 4)  = *(ushort4*)&ev[4];
    *(ushort4*)(ep + 8)  = *(ushort4*)&ev[8];
    *(ushort4*)(ep + 12) = *(ushort4*)&ev[12];
}

// ===== wcvt: conv weights -> bf16, transposed to [layer][tap][row][ci] =====
// w1t rows = co (256); w2t rows permuted: grp=co-block of 16 pairs, a rows 0-15, g rows 16-31
__global__ __launch_bounds__(256) void wcvt_kernel(
    const float* __restrict__ w1, const float* __restrict__ w2,
    unsigned short* __restrict__ w1t, unsigned short* __restrict__ w2t)
{
    int idx = blockIdx.x * 256 + threadIdx.x;
    if (idx < 2097152) {
        int i   = idx >> 19;
        int tap = (idx >> 16) & 7;
        int co  = (idx >> 8) & 255;
        int ci  = idx & 255;
        w1t[idx] = f2b(w1[(((size_t)(i * 256 + co)) * 256 + ci) * 8 + tap]);
    }
    if (idx < 4194304) {
        int i   = idx >> 20;
        int tap = (idx >> 17) & 7;
        int row = (idx >> 8) & 511;
        int ci  = idx & 255;
        int grp = row >> 5, sub = row & 31;
        int co = (sub < 16) ? (grp * 16 + sub) : (256 + grp * 16 + (sub - 16));
        w2t[idx] = f2b(w2[(((size_t)(i * 512 + co)) * 256 + ci) * 8 + tap]);
    }
}

// ===== conv1 (tap-GEMM, no LDS): o1T = elu(conv(eluT) + b1), channel-last =====
// grid (64, 8): (b x 32 pos-tiles of 128, 8 co-tiles of 32), 256 threads
__global__ __launch_bounds__(256) void conv1_mfma(
    const unsigned short* __restrict__ inT,   // [b][4096][256]
    const unsigned short* __restrict__ wT,    // [8][256][256]
    const float* __restrict__ bias,
    unsigned short* __restrict__ outT)        // [b][4096][256]
{
    const int bx = blockIdx.x;
    const int b = bx >> 5, ptile = bx & 31;
    const int t = ptile >> 1, h0 = (ptile & 1) * 8;
    const int co0 = blockIdx.y << 5;
    const int lane = threadIdx.x & 63, wv = threadIdx.x >> 6;
    const int lr = lane & 15, lg = lane >> 4;
    const bf16x8 kZ = (bf16x8){0, 0, 0, 0, 0, 0, 0, 0};

    const unsigned short* inTb = inT + (((size_t)b << 12) << 8);

    int xo[8][2]; bool ok[8][2];
#pragma unroll
    for (int tap = 0; tap < 8; ++tap) {
        const int kd = tap >> 2, kh = (tap >> 1) & 1, kw = tap & 1;
        const int tt = t - 1 + kd;
        const int ww = lr - 1 + kw;
#pragma unroll
        for (int ni = 0; ni < 2; ++ni) {
            const int hh = h0 + wv * 2 + ni - 1 + kh;
            ok[tap][ni] = (tt >= 0) && (hh >= 0) && (ww >= 0);
            xo[tap][ni] = (((tt << 8) + (hh << 4) + ww) << 8) + lg * 8;
        }
    }

    f32x4 acc[2][2];
#pragma unroll
    for (int mi = 0; mi < 2; ++mi)
#pragma unroll
        for (int ni = 0; ni < 2; ++ni) acc[mi][ni] = (f32x4){0.f, 0.f, 0.f, 0.f};

#pragma unroll
    for (int tap = 0; tap < 8; ++tap) {
        const unsigned short* wp = wT + (((size_t)(tap * 256 + co0 + lr)) << 8) + lg * 8;
#pragma unroll
        for (int kc = 0; kc < 8; ++kc) {
            const int ko = kc * 32;
            bf16x8 a0 = *(const bf16x8*)(wp + ko);
            bf16x8 a1 = *(const bf16x8*)(wp + (16 << 8) + ko);
            bf16x8 x0 = ok[tap][0] ? *(const bf16x8*)(inTb + xo[tap][0] + ko) : kZ;
            bf16x8 x1 = ok[tap][1] ? *(const bf16x8*)(inTb + xo[tap][1] + ko) : kZ;
            acc[0][0] = __builtin_amdgcn_mfma_f32_16x16x32_bf16(a0, x0, acc[0][0], 0, 0, 0);
            acc[0][1] = __builtin_amdgcn_mfma_f32_16x16x32_bf16(a0, x1, acc[0][1], 0, 0, 0);
            acc[1][0] = __builtin_amdgcn_mfma_f32_16x16x32_bf16(a1, x0, acc[1][0], 0, 0, 0);
            acc[1][1] = __builtin_amdgcn_mfma_f32_16x16x32_bf16(a1, x1, acc[1][1], 0, 0, 0);
        }
    }
#pragma unroll
    for (int mi = 0; mi < 2; ++mi)
#pragma unroll
    for (int ni = 0; ni < 2; ++ni) {
        const int pos = (t << 8) + ((h0 + wv * 2 + ni) << 4) + lr;
        const int cob = co0 + mi * 16 + lg * 4;
        unsigned short v4[4];
#pragma unroll
        for (int r = 0; r < 4; ++r)
            v4[r] = f2b(elu_f(acc[mi][ni][r] + bias[cob + r]));
        *(ushort4*)&outT[((((size_t)b << 12) + pos) << 8) + cob] = *(ushort4*)v4;
    }
}

// ===== conv2 (tap-GEMM, no LDS) + gate: res += a*sigmoid(g); elubT = bf16(elu(res)) =====
// grid (64, 16): 16 tiles of 16 channel-pairs (32 W-rows: a 0-15, g 16-31)
__global__ __launch_bounds__(256) void conv2_mfma(
    const unsigned short* __restrict__ inT,   // o1T [b][4096][256]
    const unsigned short* __restrict__ wT,    // [8][512][256] permuted
    const float* __restrict__ bias,           // [512]
    float* __restrict__ resf,                 // [b][256][4096]
    unsigned short* __restrict__ elub)        // [b][4096][256]
{
    const int bx = blockIdx.x;
    const int b = bx >> 5, ptile = bx & 31;
    const int t = ptile >> 1, h0 = (ptile & 1) * 8;
    const int c0 = blockIdx.y << 4;           // pair base
    const int wrow0 = blockIdx.y << 5;        // W row base
    const int lane = threadIdx.x & 63, wv = threadIdx.x >> 6;
    const int lr = lane & 15, lg = lane >> 4;
    const bf16x8 kZ = (bf16x8){0, 0, 0, 0, 0, 0, 0, 0};

    const unsigned short* inTb = inT + (((size_t)b << 12) << 8);

    int xo[8][2]; bool ok[8][2];
#pragma unroll
    for (int tap = 0; tap < 8; ++tap) {
        const int kd = tap >> 2, kh = (tap >> 1) & 1, kw = tap & 1;
        const int tt = t - 1 + kd;
        const int ww = lr - 1 + kw;
#pragma unroll
        for (int ni = 0; ni < 2; ++ni) {
            const int hh = h0 + wv * 2 + ni - 1 + kh;
            ok[tap][ni] = (tt >= 0) && (hh >= 0) && (ww >= 0);
            xo[tap][ni] = (((tt << 8) + (hh << 4) + ww) << 8) + lg * 8;
        }
    }

    f32x4 acc[2][2];
#pragma unroll
    for (int mi = 0; mi < 2; ++mi)
#pragma unroll
        for (int ni = 0; ni < 2; ++ni) acc[mi][ni] = (f32x4){0.f, 0.f, 0.f, 0.f};

#pragma unroll
    for (int tap = 0; tap < 8; ++tap) {
        const unsigned short* wp = wT + (((size_t)(tap * 512 + wrow0 + lr)) << 8) + lg * 8;
#pragma unroll
        for (int kc = 0; kc < 8; ++kc) {
            const int ko = kc * 32;
            bf16x8 a0 = *(const bf16x8*)(wp + ko);
            bf16x8 a1 = *(const bf16x8*)(wp + (16 << 8) + ko);
            bf16x8 x0 = ok[tap][0] ? *(const bf16x8*)(inTb + xo[tap][0] + ko) : kZ;
            bf16x8 x1 = ok[tap][1] ? *(const bf16x8*)(inTb + xo[tap][1] + ko) : kZ;
            acc[0][0] = __builtin_amdgcn_mfma_f32_16x16x32_bf16(a0, x0, acc[0][0], 0, 0, 0);
            acc[0][1] = __builtin_amdgcn_mfma_f32_16x16x32_bf16(a0, x1, acc[0][1], 0, 0, 0);
            acc[1][0] = __builtin_amdgcn_mfma_f32_16x16x32_bf16(a1, x0, acc[1][0], 0, 0, 0);
            acc[1][1] = __builtin_amdgcn_mfma_f32_16x16x32_bf16(a1, x1, acc[1][1], 0, 0, 0);
        }
    }
    // epilogue: a = acc[0], g = acc[1]
#pragma unroll
    for (int ni = 0; ni < 2; ++ni) {
        const int pos = (t << 8) + ((h0 + wv * 2 + ni) << 4) + lr;
        unsigned short e4[4];
#pragma unroll
        for (int r = 0; r < 4; ++r) {
            const int co = c0 + lg * 4 + r;
            float av = acc[0][ni][r] + bias[co];
            float gv = acc[1][ni][r] + bias[co + 256];
            float add = av / (1.0f + expf(-gv));
            size_t ridx = (((size_t)(b * 256 + co)) << 12) + pos;
            float rn = resf[ridx] + add;
            resf[ridx] = rn;
            e4[r] = f2b(elu_f(rn));
        }
        *(ushort4*)&elub[((((size_t)b << 12) + pos) << 8) + c0 + lg * 4] = *(ushort4*)e4;
    }
}

// ===== pack: xq[b][s][320] = bf16(res | orig | pos | 0) =====
__global__ __launch_bounds__(256) void pack_kernel(
    const float* __restrict__ res, const float* __restrict__ orig,
    unsigned short* __restrict__ xq)
{
    const int b = blockIdx.x >> 5;
    const int s0 = (blockIdx.x & 31) << 7;
    const int cg = blockIdx.y;
    const int tid = threadIdx.x;
    const int s = s0 + (tid & 127);
    const int c0 = cg * 32 + (tid >> 7) * 16;

    unsigned short xv[16];
    if (cg < 8) {
#pragma unroll
        for (int cc = 0; cc < 16; ++cc) {
            int c = c0 + cc;
            float v = res[(size_t)((b * 256 + c) << 12) + s];
            xv[cc] = f2b(v);
        }
    } else if (cg == 8) {
#pragma unroll
        for (int cc = 0; cc < 16; ++cc) {
            int c = c0 + cc;
            float v;
            if (c < 259)      v = orig[(size_t)((b * 3 + (c - 256)) << 12) + s];
            else if (c == 259) v = -0.5f + (float)(s >> 8) * 0.0625f;
            else if (c == 260) v = -0.5f + (float)((s >> 4) & 15) * 0.0625f;
            else if (c == 261) v = -0.5f + (float)(s & 15) * 0.0625f;
            else               v = 0.0f;
            xv[cc] = f2b(v);
        }
    } else {
#pragma unroll
        for (int cc = 0; cc < 16; ++cc) xv[cc] = 0;
    }
    unsigned short* xp = &xq[((size_t)(b << 12) + s) * 320 + c0];
    *(ushort4*)(xp)      = *(ushort4*)&xv[0];
    *(ushort4*)(xp + 4)  = *(ushort4*)&xv[4];
    *(ushort4*)(xp + 8)  = *(ushort4*)&xv[8];
    *(ushort4*)(xp + 12) = *(ushort4*)&xv[12];
}

// ===== wcvt2: pack qkv weights [192][320] (zero-pad) + attn/resc/out weights -> bf16 =====
__global__ __launch_bounds__(256) void wcvt2_kernel(
    const float* __restrict__ qw, const float* __restrict__ kw,
    const float* __restrict__ vw, const float* __restrict__ aw,
    const float* __restrict__ rw, const float* __restrict__ ow,
    unsigned short* __restrict__ wqkv, unsigned short* __restrict__ awb,
    unsigned short* __restrict__ rwb, unsigned short* __restrict__ owb)
{
    int idx = blockIdx.x * 256 + threadIdx.x;
    if (idx < 61440) {
        int r = idx / 320, c = idx - r * 320;
        float v = 0.0f;
        if (c < 262) {
            if (r < 16)       v = qw[r * 262 + c];
            else if (r < 32)  v = kw[(r - 16) * 262 + c];
            else if (r < 160) v = vw[(r - 32) * 262 + c];
        }
        wqkv[idx] = f2b(v);
    } else if (idx < 61440 + 32768) {
        int j = idx - 61440; awb[j] = f2b(aw[j]);
    } else if (idx < 61440 + 32768 + 65536) {
        int j = idx - 61440 - 32768; rwb[j] = f2b(rw[j]);
    } else if (idx < 61440 + 32768 + 131072) {
        int j = idx - 61440 - 98304; owb[j] = f2b(ow[j]);
    }
}

// ===== qkv GEMM: [192][320] @ [s][320]^T ; q,k -> bf16 [s][16]; v -> bf16 [vc][s] =====
__global__ __launch_bounds__(256) void qkv_gemm(
    const unsigned short* __restrict__ Wb, const unsigned short* __restrict__ Xt,
    const float* __restrict__ qb, const float* __restrict__ kb,
    const float* __restrict__ vb,
    unsigned short* __restrict__ qbt, unsigned short* __restrict__ kbt,
    unsigned short* __restrict__ vbt)
{
    const int b = blockIdx.x >> 5;
    const int s0 = (blockIdx.x & 31) << 7;
    const int co0 = blockIdx.y << 6;
    const int lane = threadIdx.x & 63, wv = threadIdx.x >> 6;
    const int lr = lane & 15, lg = lane >> 4;

    f32x4 acc[4][2];
#pragma unroll
    for (int mi = 0; mi < 4; ++mi)
#pragma unroll
        for (int ni = 0; ni < 2; ++ni) acc[mi][ni] = (f32x4){0.f, 0.f, 0.f, 0.f};

    const unsigned short* wp = Wb + (size_t)co0 * 320 + lg * 8;
    const unsigned short* xp = Xt + ((size_t)(b << 12) + s0 + wv * 32) * 320 + lg * 8;

#pragma unroll
    for (int kc = 0; kc < 10; ++kc) {
        int ko = kc * 32;
        bf16x8 a[4], x[2];
#pragma unroll
        for (int mi = 0; mi < 4; ++mi)
            a[mi] = *(const bf16x8*)(wp + (size_t)(mi * 16 + lr) * 320 + ko);
#pragma unroll
        for (int ni = 0; ni < 2; ++ni)
            x[ni] = *(const bf16x8*)(xp + (size_t)(ni * 16 + lr) * 320 + ko);
#pragma unroll
        for (int mi = 0; mi < 4; ++mi)
#pragma unroll
            for (int ni = 0; ni < 2; ++ni)
                acc[mi][ni] = __builtin_amdgcn_mfma_f32_16x16x32_bf16(
                    a[mi], x[ni], acc[mi][ni], 0, 0, 0);
    }
#pragma unroll
    for (int mi = 0; mi < 4; ++mi)
#pragma unroll
    for (int ni = 0; ni < 2; ++ni)
#pragma unroll
    for (int r = 0; r < 4; ++r) {
        int co = co0 + mi * 16 + lg * 4 + r;
        if (co >= 160) continue;
        int s = s0 + wv * 32 + ni * 16 + lr;
        float bias = (co < 16) ? qb[co] : ((co < 32) ? kb[co - 16] : vb[co - 32]);
        float v = acc[mi][ni][r] + bias;
        if (co < 16)      qbt[((size_t)(b << 12) + s) * 16 + co] = f2b(v);
        else if (co < 32) kbt[((size_t)(b << 12) + s) * 16 + (co - 16)] = f2b(v);
        else              vbt[((size_t)((b << 7) + (co - 32)) << 12) + s] = f2b(v);
    }
}

// ===== attention partial: MFMA QK^T + in-register softmax (swapped operands) =====
__global__ __launch_bounds__(256) void attn_part2(
    const unsigned short* __restrict__ qbt, const unsigned short* __restrict__ kbt,
    const unsigned short* __restrict__ vbt,
    float* __restrict__ pacc, float* __restrict__ pml)
{
    const int bx = blockIdx.x;
    const int b = bx >> 8;
    const int qt = (bx >> 2) & 63;
    const int seg = bx & 3;
    const int q0 = qt << 6;
    const int nch = (qt >> 1) + 1;
    const int c_lo = seg << 3;
    if (c_lo >= nch) return;
    const int c_hi = min(c_lo + 8, nch);

    __shared__ unsigned short sK[128 * 16];
    __shared__ unsigned short sP[4][16 * 136];

    const int tid = threadIdx.x;
    const int lane = tid & 63, wv = tid >> 6;
    const int lr = lane & 15, lg = lane >> 4;
    const int qa = q0 + wv * 16 + lr;
    const float scale = 1.0f / sqrtf(259.0f);

    bf16x8 qf = (bf16x8){0, 0, 0, 0, 0, 0, 0, 0};
    if (lg < 2)
        qf = *(const bf16x8*)(qbt + ((size_t)(b << 12) + qa) * 16 + lg * 8);

    f32x4 oacc[8];
#pragma unroll
    for (int vct = 0; vct < 8; ++vct) oacc[vct] = (f32x4){0.f, 0.f, 0.f, 0.f};
    float m = -1e30f, l = 0.0f;

    unsigned short* myP = &sP[wv][0];

    for (int kc = c_lo; kc < c_hi; ++kc) {
        const int kv0 = kc << 7;
        __syncthreads();
        *(bf16x8*)&sK[(tid >> 1) * 16 + (tid & 1) * 8] =
            *(const bf16x8*)(kbt + ((size_t)(b << 12) + kv0 + (tid >> 1)) * 16 + (tid & 1) * 8);
        __syncthreads();

        f32x4 sc[8];
#pragma unroll
        for (int kvt = 0; kvt < 8; ++kvt) {
            bf16x8 af = (bf16x8){0, 0, 0, 0, 0, 0, 0, 0};
            if (lg < 2)
                af = *(const bf16x8*)&sK[(kvt * 16 + lr) * 16 + lg * 8];
            sc[kvt] = __builtin_amdgcn_mfma_f32_16x16x32_bf16(
                af, qf, (f32x4){0.f, 0.f, 0.f, 0.f}, 0, 0, 0);
        }
        float mc = -1e30f;
#pragma unroll
        for (int kvt = 0; kvt < 8; ++kvt) {
#pragma unroll
            for (int r = 0; r < 4; ++r) {
                int kv = kv0 + kvt * 16 + lg * 4 + r;
                float s = (kv < qa) ? sc[kvt][r] * scale : -1e30f;
                sc[kvt][r] = s;
                mc = fmaxf(mc, s);
            }
        }
        mc = fmaxf(mc, __shfl_xor(mc, 16, 64));
        mc = fmaxf(mc, __shfl_xor(mc, 32, 64));
        float mn = fmaxf(m, mc);
        float fac = __expf(m - mn);
        float ls = 0.0f;
#pragma unroll
        for (int kvt = 0; kvt < 8; ++kvt) {
#pragma unroll
            for (int e = 0; e < 2; ++e) {
                float s0v = sc[kvt][2 * e];
                float s1v = sc[kvt][2 * e + 1];
                float p0 = (s0v <= -1e29f) ? 0.f : __expf(s0v - mn);
                float p1 = (s1v <= -1e29f) ? 0.f : __expf(s1v - mn);
                ls += p0 + p1;
                unsigned int pk = (unsigned int)f2b(p0) | ((unsigned int)f2b(p1) << 16);
                int kv = kvt * 16 + lg * 4 + 2 * e;
                *(unsigned int*)&myP[lr * 136 + kv] = pk;
            }
        }
        ls += __shfl_xor(ls, 16, 64);
        ls += __shfl_xor(ls, 32, 64);
        l = l * fac + ls;
        m = mn;
#pragma unroll
        for (int vct = 0; vct < 8; ++vct) {
            oacc[vct][0] *= fac; oacc[vct][1] *= fac;
            oacc[vct][2] *= fac; oacc[vct][3] *= fac;
        }
#pragma unroll
        for (int ks = 0; ks < 4; ++ks) {
            bf16x8 pf = *(const bf16x8*)&myP[lr * 136 + ks * 32 + lg * 8];
#pragma unroll
            for (int vct = 0; vct < 8; ++vct) {
                bf16x8 vf = *(const bf16x8*)(vbt +
                    ((size_t)((b << 7) + vct * 16 + lr) << 12) + kv0 + ks * 32 + lg * 8);
                oacc[vct] = __builtin_amdgcn_mfma_f32_16x16x32_bf16(
                    vf, pf, oacc[vct], 0, 0, 0);
            }
        }
    }

    const int a_ = qt >> 4;
    const int slot = b * 160 + 8 * a_ * (a_ + 1) + (qt & 15) * (a_ + 1) + seg;
    float* ap = pacc + (size_t)slot * 8192;
#pragma unroll
    for (int vct = 0; vct < 8; ++vct)
        *(f32x4*)&ap[(wv * 16 + lr) * 128 + vct * 16 + lg * 4] = oacc[vct];
    if (lg == 0) {
        pml[slot * 128 + (wv * 16 + lr) * 2]     = m;
        pml[slot * 128 + (wv * 16 + lr) * 2 + 1] = l;
    }
}

// ===== attention combine =====
__global__ __launch_bounds__(256) void attn_combine2(
    const float* __restrict__ pacc, const float* __restrict__ pml,
    unsigned short* __restrict__ attEb)
{
    const int bx = blockIdx.x;
    const int b = bx >> 7;
    const int qt = (bx >> 1) & 63;
    const int half = bx & 1;
    const int a_ = qt >> 4;
    const int nseg_alloc = a_ + 1;
    const int nch = (qt >> 1) + 1;
    const int nseg = (nch + 7) >> 3;
    const int base = b * 160 + 8 * a_ * (a_ + 1) + (qt & 15) * nseg_alloc;
    const int tid = threadIdx.x;
    const int qq = (tid >> 3) + half * 32;
    const int vg = tid & 7;

    float mi_[4], li_[4];
    float m = -1e30f;
    for (int i = 0; i < nseg; ++i) {
        mi_[i] = pml[(base + i) * 128 + qq * 2];
        li_[i] = pml[(base + i) * 128 + qq * 2 + 1];
        m = fmaxf(m, mi_[i]);
    }
    float w[4];
    float l = 0.f;
    for (int i = 0; i < nseg; ++i) {
        float wi = (mi_[i] <= -1e29f) ? 0.f : __expf(mi_[i] - m);
        w[i] = wi;
        l += wi * li_[i];
    }
    float inv = (l > 0.f) ? 1.f / l : 0.f;
    int q = (qt << 6) + qq;
#pragma unroll
    for (int v4 = 0; v4 < 4; ++v4) {
        int vc = vg * 16 + v4 * 4;
        float o0 = 0.f, o1 = 0.f, o2 = 0.f, o3 = 0.f;
        for (int i = 0; i < nseg; ++i) {
            f32x4 a = *(const f32x4*)(pacc + (size_t)(base + i) * 8192 + qq * 128 + vc);
            o0 = fmaf(w[i], a[0], o0);
            o1 = fmaf(w[i], a[1], o1);
            o2 = fmaf(w[i], a[2], o2);
            o3 = fmaf(w[i], a[3], o3);
        }
        unsigned short r0 = f2b(elu_f(o0 * inv));
        unsigned short r1 = f2b(elu_f(o1 * inv));
        unsigned short r2 = f2b(elu_f(o2 * inv));
        unsigned short r3 = f2b(elu_f(o3 * inv));
        ushort4 pk = {r0, r1, r2, r3};
        *(ushort4*)&attEb[((size_t)(b << 12) + q) * 128 + vc] = pk;
    }
}

// ===== final_ab GEMM: sum2b = bf16(elu( elu(W1@attEb+b1) + elu(W2@elut+b2) )) =====
__global__ __launch_bounds__(256) void final_ab_gemm(
    const unsigned short* __restrict__ W1b, const unsigned short* __restrict__ W2b,
    const unsigned short* __restrict__ X1, const unsigned short* __restrict__ X2,
    const float* __restrict__ b1, const float* __restrict__ b2,
    unsigned short* __restrict__ sum2b)
{
    const int b = blockIdx.x >> 5;
    const int s0 = (blockIdx.x & 31) << 7;
    const int co0 = blockIdx.y << 6;
    const int lane = threadIdx.x & 63, wv = threadIdx.x >> 6;
    const int lr = lane & 15, lg = lane >> 4;

    f32x4 acc1[4][2], acc2[4][2];
#pragma unroll
    for (int mi = 0; mi < 4; ++mi)
#pragma unroll
        for (int ni = 0; ni < 2; ++ni) {
            acc1[mi][ni] = (f32x4){0.f, 0.f, 0.f, 0.f};
            acc2[mi][ni] = (f32x4){0.f, 0.f, 0.f, 0.f};
        }

    {
        const unsigned short* wp = W1b + (size_t)co0 * 128 + lg * 8;
        const unsigned short* xp = X1 + ((size_t)(b << 12) + s0 + wv * 32) * 128 + lg * 8;
#pragma unroll
        for (int kc = 0; kc < 4; ++kc) {
            int ko = kc * 32;
            bf16x8 a[4], x[2];
#pragma unroll
            for (int mi = 0; mi < 4; ++mi)
                a[mi] = *(const bf16x8*)(wp + (size_t)(mi * 16 + lr) * 128 + ko);
#pragma unroll
            for (int ni = 0; ni < 2; ++ni)
                x[ni] = *(const bf16x8*)(xp + (size_t)(ni * 16 + lr) * 128 + ko);
#pragma unroll
            for (int mi = 0; mi < 4; ++mi)
#pragma unroll
                for (int ni = 0; ni < 2; ++ni)
                    acc1[mi][ni] = __builtin_amdgcn_mfma_f32_16x16x32_bf16(
                        a[mi], x[ni], acc1[mi][ni], 0, 0, 0);
        }
    }
    {
        const unsigned short* wp = W2b + (size_t)co0 * 256 + lg * 8;
        const unsigned short* xp = X2 + ((size_t)(b << 12) + s0 + wv * 32) * 256 + lg * 8;
#pragma unroll
        for (int kc = 0; kc < 8; ++kc) {
            int ko = kc * 32;
            bf16x8 a[4], x[2];
#pragma unroll
            for (int mi = 0; mi < 4; ++mi)
                a[mi] = *(const bf16x8*)(wp + (size_t)(mi * 16 + lr) * 256 + ko);
#pragma unroll
            for (int ni = 0; ni < 2; ++ni)
                x[ni] = *(const bf16x8*)(xp + (size_t)(ni * 16 + lr) * 256 + ko);
#pragma unroll
            for (int mi = 0; mi < 4; ++mi)
#pragma unroll
                for (int ni = 0; ni < 2; ++ni)
                    acc2[mi][ni] = __builtin_amdgcn_mfma_f32_16x16x32_bf16(
                        a[mi], x[ni], acc2[mi][ni], 0, 0, 0);
        }
    }
#pragma unroll
    for (int mi = 0; mi < 4; ++mi)
#pragma unroll
    for (int ni = 0; ni < 2; ++ni)
#pragma unroll
    for (int r = 0; r < 4; ++r) {
        int co = co0 + mi * 16 + lg * 4 + r;
        int s = s0 + wv * 32 + ni * 16 + lr;
        float v1 = elu_f(acc1[mi][ni][r] + b1[co]);
        float v2 = elu_f(acc2[mi][ni][r] + b2[co]);
        sum2b[((size_t)(b << 12) + s) * 256 + co] = f2b(elu_f(v1 + v2));
    }
}

// ===== final_c GEMM: out = elu(outW@sum2b + out_b), fp32 [b][256][4096] =====
__global__ __launch_bounds__(256) void final_c_gemm(
    const unsigned short* __restrict__ Wb, const unsigned short* __restrict__ Xt,
    const float* __restrict__ bias, float* __restrict__ out)
{
    const int b = blockIdx.x >> 5;
    const int s0 = (blockIdx.x & 31) << 7;
    const int co0 = blockIdx.y << 6;
    const int lane = threadIdx.x & 63, wv = threadIdx.x >> 6;
    const int lr = lane & 15, lg = lane >> 4;

    f32x4 acc[4][2];
#pragma unroll
    for (int mi = 0; mi < 4; ++mi)
#pragma unroll
        for (int ni = 0; ni < 2; ++ni) acc[mi][ni] = (f32x4){0.f, 0.f, 0.f, 0.f};

    const unsigned short* wp = Wb + (size_t)co0 * 256 + lg * 8;
    const unsigned short* xp = Xt + ((size_t)(b << 12) + s0 + wv * 32) * 256 + lg * 8;
#pragma unroll
    for (int kc = 0; kc < 8; ++kc) {
        int ko = kc * 32;
        bf16x8 a[4], x[2];
#pragma unroll
        for (int mi = 0; mi < 4; ++mi)
            a[mi] = *(const bf16x8*)(wp + (size_t)(mi * 16 + lr) * 256 + ko);
#pragma unroll
        for (int ni = 0; ni < 2; ++ni)
            x[ni] = *(const bf16x8*)(xp + (size_t)(ni * 16 + lr) * 256 + ko);
#pragma unroll
        for (int mi = 0; mi < 4; ++mi)
#pragma unroll
            for (int ni = 0; ni < 2; ++ni)
                acc[mi][ni] = __builtin_amdgcn_mfma_f32_16x16x32_bf16(
                    a[mi], x[ni], acc[mi][ni], 0, 0, 0);
    }
#pragma unroll
    for (int mi = 0; mi < 4; ++mi)
#pragma unroll
    for (int ni = 0; ni < 2; ++ni)
#pragma unroll
    for (int r = 0; r < 4; ++r) {
        int co = co0 + mi * 16 + lg * 4 + r;
        int s = s0 + wv * 32 + ni * 16 + lr;
        out[((size_t)(b * 256 + co) << 12) + s] = elu_f(acc[mi][ni][r] + bias[co]);
    }
}

extern "C" void kernel_launch(void* const* d_in, const int* in_sizes, int n_in,
                              void* d_out, int out_size, void* d_ws, size_t ws_size,
                              hipStream_t stream) {
    const float* x      = (const float*)d_in[0];
    const float* orig   = (const float*)d_in[1];
    const float* rb_w1  = (const float*)d_in[2];
    const float* rb_b1  = (const float*)d_in[3];
    const float* rb_w2  = (const float*)d_in[4];
    const float* rb_b2  = (const float*)d_in[5];
    const float* q_w    = (const float*)d_in[6];
    const float* q_b    = (const float*)d_in[7];
    const float* k_w    = (const float*)d_in[8];
    const float* k_b    = (const float*)d_in[9];
    const float* v_w    = (const float*)d_in[10];
    const float* v_b    = (const float*)d_in[11];
    const float* attn_w = (const float*)d_in[12];
    const float* attn_b = (const float*)d_in[13];
    const float* resc_w = (const float*)d_in[14];
    const float* resc_b = (const float*)d_in[15];
    const float* out_w  = (const float*)d_in[16];
    const float* out_b  = (const float*)d_in[17];
    float* out = (float*)d_out;

    char* base = (char*)d_ws;
    float*          res   = (float*)(base);                        // 8 MB [b][c][s]
    unsigned short* elubT = (unsigned short*)(base + (8u << 20));  // 4 MB [b][s][256]
    unsigned short* o1t   = (unsigned short*)(base + (12u << 20)); // 4 MB [b][s][256]
    unsigned short* w1t   = (unsigned short*)(base + (16u << 20)); // 4 MB [l][tap][co][ci]
    unsigned short* w2t   = (unsigned short*)(base + (20u << 20)); // 8 MB [l][tap][row][ci]
    // aliases (live after conv loop)
    unsigned short* vbt   = o1t;                                   // 2 MB
    unsigned short* attEb = (unsigned short*)(base + (12u << 20) + 2097152); // 2 MB
    unsigned short* sum2b = w1t;
    unsigned short* xqkvB = w2t;                                   // 5 MB
    unsigned short* qbt   = (unsigned short*)(base + (20u << 20) + 5242880); // 256 KB
    unsigned short* kbt   = (unsigned short*)(base + (20u << 20) + 5505024); // 256 KB
    unsigned short* wqkvB = (unsigned short*)(base + (20u << 20) + 5767168); // 120 KB
    unsigned short* attnWb= (unsigned short*)(base + (20u << 20) + 5890048); // 64 KB
    unsigned short* rescWb= (unsigned short*)(base + (20u << 20) + 5955584); // 128 KB
    unsigned short* outWb = (unsigned short*)(base + (20u << 20) + 6086656); // 128 KB
    float*          pacc  = (float*)(base + (28u << 20));            // 10 MB
    float*          pml   = (float*)(base + (28u << 20) + 10485760); // 160 KB

    hipMemcpyAsync(res, x, (size_t)2097152 * sizeof(float),
                   hipMemcpyDeviceToDevice, stream);
    prep_t<<<dim3(64, 8), 256, 0, stream>>>(x, elubT);
    wcvt_kernel<<<16384, 256, 0, stream>>>(rb_w1, rb_w2, w1t, w2t);

    for (int i = 0; i < 4; ++i) {
        conv1_mfma<<<dim3(64, 8), 256, 0, stream>>>(
            elubT, w1t + (size_t)i * 524288, rb_b1 + i * 256, o1t);
        conv2_mfma<<<dim3(64, 16), 256, 0, stream>>>(
            o1t, w2t + (size_t)i * 1048576, rb_b2 + i * 512, res, elubT);
    }

    pack_kernel<<<dim3(64, 10), 256, 0, stream>>>(res, orig, xqkvB);
    wcvt2_kernel<<<880, 256, 0, stream>>>(q_w, k_w, v_w, attn_w, resc_w, out_w,
                                          wqkvB, attnWb, rescWb, outWb);

    qkv_gemm<<<dim3(64, 3), 256, 0, stream>>>(wqkvB, xqkvB, q_b, k_b, v_b,
                                              qbt, kbt, vbt);

    attn_part2<<<512, 256, 0, stream>>>(qbt, kbt, vbt, pacc, pml);
    attn_combine2<<<256, 256, 0, stream>>>(pacc, pml, attEb);

    final_ab_gemm<<<dim3(64, 4), 256, 0, stream>>>(
        attnWb, rescWb, attEb, elubT, attn_b, resc_b, sum2b);

    final_c_gemm<<<dim3(64, 4), 256, 0, stream>>>(outWb, sum2b, out_b, out);
}

// Round 8
// 721.053 us; speedup vs baseline: 6.6099x; 1.1222x over previous
//
#include <hip/hip_runtime.h>
#include <math.h>

#define SEQ 4096
#define CIN 256
#define PROWS 4913   // 17*17*17 padded spatial rows
#define PT 289       // 17*17

typedef __attribute__((ext_vector_type(8))) short bf16x8;
typedef __attribute__((ext_vector_type(4))) float f32x4;

__device__ __forceinline__ float elu_f(float x) {
    return x > 0.0f ? x : (expf(x) - 1.0f);
}
__device__ __forceinline__ unsigned short f2b(float f) {
    unsigned int u = __float_as_uint(f);
    return (unsigned short)((u + 0x7FFFu + ((u >> 16) & 1u)) >> 16);
}

// ===== zero2: clear both padded activation buffers (halo must be 0) =====
__global__ __launch_bounds__(256) void zero2_kernel(
    uint4* __restrict__ p1, uint4* __restrict__ p2, int n)
{
    int i = blockIdx.x * 256 + threadIdx.x;
    if (i < n) {
        p1[i] = (uint4){0, 0, 0, 0};
        p2[i] = (uint4){0, 0, 0, 0};
    }
}

// ===== prep_t: elubP[b][padded pos][256] = bf16(elu(x)) =====
__global__ __launch_bounds__(256) void prep_t(
    const float* __restrict__ x, unsigned short* __restrict__ elub)
{
    const int b = blockIdx.x >> 5;
    const int s0 = (blockIdx.x & 31) << 7;
    const int cg = blockIdx.y;
    const int tid = threadIdx.x;
    const int s = s0 + (tid & 127);
    const int c0 = cg * 32 + (tid >> 7) * 16;
    const int tt = s >> 8, hh = (s >> 4) & 15, ww = s & 15;
    const size_t prow = (size_t)b * PROWS + (tt + 1) * PT + (hh + 1) * 17 + (ww + 1);
    unsigned short ev[16];
#pragma unroll
    for (int cc = 0; cc < 16; ++cc) {
        float v = x[(((size_t)(b * 256 + c0 + cc)) << 12) + s];
        ev[cc] = f2b(elu_f(v));
    }
    unsigned short* ep = &elub[prow * 256 + c0];
    *(ushort4*)(ep)      = *(ushort4*)&ev[0];
    *(ushort4*)(ep + 4)  = *(ushort4*)&ev[4];
    *(ushort4*)(ep + 8)  = *(ushort4*)&ev[8];
    *(ushort4*)(ep + 12) = *(ushort4*)&ev[12];
}

// ===== wcvt: conv weights -> bf16, transposed to [layer][tap][row][ci] =====
__global__ __launch_bounds__(256) void wcvt_kernel(
    const float* __restrict__ w1, const float* __restrict__ w2,
    unsigned short* __restrict__ w1t, unsigned short* __restrict__ w2t)
{
    int idx = blockIdx.x * 256 + threadIdx.x;
    if (idx < 2097152) {
        int i   = idx >> 19;
        int tap = (idx >> 16) & 7;
        int co  = (idx >> 8) & 255;
        int ci  = idx & 255;
        w1t[idx] = f2b(w1[(((size_t)(i * 256 + co)) * 256 + ci) * 8 + tap]);
    }
    if (idx < 4194304) {
        int i   = idx >> 20;
        int tap = (idx >> 17) & 7;
        int row = (idx >> 8) & 511;
        int ci  = idx & 255;
        int grp = row >> 5, sub = row & 31;
        int co = (sub < 16) ? (grp * 16 + sub) : (256 + grp * 16 + (sub - 16));
        w2t[idx] = f2b(w2[(((size_t)(i * 512 + co)) * 256 + ci) * 8 + tap]);
    }
}

// ===== conv1: padded tap-GEMM, no predication. block = 32co x 128pos, 2 waves =====
__global__ __launch_bounds__(128, 4) void conv1_mfma(
    const unsigned short* __restrict__ inP,   // [b][4913][256] padded
    const unsigned short* __restrict__ wT,    // [8][256][256]
    const float* __restrict__ bias,
    unsigned short* __restrict__ outP)        // [b][4913][256] padded
{
    const int bx = blockIdx.x;
    const int b = bx >> 5, ptile = bx & 31;
    const int t = ptile >> 1, h0 = (ptile & 1) * 8;
    const int co0 = blockIdx.y << 5;
    const int lane = threadIdx.x & 63, wv = threadIdx.x >> 6;
    const int lr = lane & 15, lg = lane >> 4;

    const unsigned short* inB = inP + (size_t)b * PROWS * 256;

    const unsigned short* xptr[4];
#pragma unroll
    for (int ni = 0; ni < 4; ++ni) {
        int pbase = t * PT + (h0 + wv * 4 + ni) * 17 + lr;
        xptr[ni] = inB + (size_t)pbase * 256 + lg * 8;
    }
    const unsigned short* aptr[2];
#pragma unroll
    for (int mi = 0; mi < 2; ++mi)
        aptr[mi] = wT + (size_t)(co0 + mi * 16 + lr) * 256 + lg * 8;

    f32x4 acc[2][4];
#pragma unroll
    for (int mi = 0; mi < 2; ++mi)
#pragma unroll
        for (int ni = 0; ni < 4; ++ni) acc[mi][ni] = (f32x4){0.f, 0.f, 0.f, 0.f};

#pragma unroll
    for (int tap = 0; tap < 8; ++tap) {
        const int td = (((tap >> 2) * PT) + (((tap >> 1) & 1) * 17) + (tap & 1)) * 256;
        const int wd = tap * 65536;
#pragma unroll
        for (int kc = 0; kc < 8; ++kc) {
            const int ko = kc * 32;
            bf16x8 a0 = *(const bf16x8*)(aptr[0] + wd + ko);
            bf16x8 a1 = *(const bf16x8*)(aptr[1] + wd + ko);
            bf16x8 x0 = *(const bf16x8*)(xptr[0] + td + ko);
            bf16x8 x1 = *(const bf16x8*)(xptr[1] + td + ko);
            bf16x8 x2 = *(const bf16x8*)(xptr[2] + td + ko);
            bf16x8 x3 = *(const bf16x8*)(xptr[3] + td + ko);
            acc[0][0] = __builtin_amdgcn_mfma_f32_16x16x32_bf16(a0, x0, acc[0][0], 0, 0, 0);
            acc[0][1] = __builtin_amdgcn_mfma_f32_16x16x32_bf16(a0, x1, acc[0][1], 0, 0, 0);
            acc[0][2] = __builtin_amdgcn_mfma_f32_16x16x32_bf16(a0, x2, acc[0][2], 0, 0, 0);
            acc[0][3] = __builtin_amdgcn_mfma_f32_16x16x32_bf16(a0, x3, acc[0][3], 0, 0, 0);
            acc[1][0] = __builtin_amdgcn_mfma_f32_16x16x32_bf16(a1, x0, acc[1][0], 0, 0, 0);
            acc[1][1] = __builtin_amdgcn_mfma_f32_16x16x32_bf16(a1, x1, acc[1][1], 0, 0, 0);
            acc[1][2] = __builtin_amdgcn_mfma_f32_16x16x32_bf16(a1, x2, acc[1][2], 0, 0, 0);
            acc[1][3] = __builtin_amdgcn_mfma_f32_16x16x32_bf16(a1, x3, acc[1][3], 0, 0, 0);
        }
    }
#pragma unroll
    for (int ni = 0; ni < 4; ++ni) {
        const int hh = h0 + wv * 4 + ni;
        const size_t orow = (size_t)b * PROWS + (t + 1) * PT + (hh + 1) * 17 + (lr + 1);
#pragma unroll
        for (int mi = 0; mi < 2; ++mi) {
            const int cob = co0 + mi * 16 + lg * 4;
            unsigned short v4[4];
#pragma unroll
            for (int r = 0; r < 4; ++r)
                v4[r] = f2b(elu_f(acc[mi][ni][r] + bias[cob + r]));
            *(ushort4*)&outP[orow * 256 + cob] = *(ushort4*)v4;
        }
    }
}

// ===== conv2: padded tap-GEMM + gate. block = 16 pairs x 128pos, 2 waves =====
__global__ __launch_bounds__(128, 4) void conv2_mfma(
    const unsigned short* __restrict__ inP,   // o1P padded
    const unsigned short* __restrict__ wT,    // [8][512][256] permuted
    const float* __restrict__ bias,           // [512]
    float* __restrict__ resf,                 // [b][256][4096]
    unsigned short* __restrict__ elub)        // padded [b][4913][256]
{
    const int bx = blockIdx.x;
    const int b = bx >> 5, ptile = bx & 31;
    const int t = ptile >> 1, h0 = (ptile & 1) * 8;
    const int c0 = blockIdx.y << 4;
    const int wrow0 = blockIdx.y << 5;
    const int lane = threadIdx.x & 63, wv = threadIdx.x >> 6;
    const int lr = lane & 15, lg = lane >> 4;

    const unsigned short* inB = inP + (size_t)b * PROWS * 256;

    const unsigned short* xptr[4];
#pragma unroll
    for (int ni = 0; ni < 4; ++ni) {
        int pbase = t * PT + (h0 + wv * 4 + ni) * 17 + lr;
        xptr[ni] = inB + (size_t)pbase * 256 + lg * 8;
    }
    const unsigned short* aptr[2];
#pragma unroll
    for (int mi = 0; mi < 2; ++mi)
        aptr[mi] = wT + (size_t)(wrow0 + mi * 16 + lr) * 256 + lg * 8;

    f32x4 acc[2][4];
#pragma unroll
    for (int mi = 0; mi < 2; ++mi)
#pragma unroll
        for (int ni = 0; ni < 4; ++ni) acc[mi][ni] = (f32x4){0.f, 0.f, 0.f, 0.f};

#pragma unroll
    for (int tap = 0; tap < 8; ++tap) {
        const int td = (((tap >> 2) * PT) + (((tap >> 1) & 1) * 17) + (tap & 1)) * 256;
        const int wd = tap * 131072;
#pragma unroll
        for (int kc = 0; kc < 8; ++kc) {
            const int ko = kc * 32;
            bf16x8 a0 = *(const bf16x8*)(aptr[0] + wd + ko);
            bf16x8 a1 = *(const bf16x8*)(aptr[1] + wd + ko);
            bf16x8 x0 = *(const bf16x8*)(xptr[0] + td + ko);
            bf16x8 x1 = *(const bf16x8*)(xptr[1] + td + ko);
            bf16x8 x2 = *(const bf16x8*)(xptr[2] + td + ko);
            bf16x8 x3 = *(const bf16x8*)(xptr[3] + td + ko);
            acc[0][0] = __builtin_amdgcn_mfma_f32_16x16x32_bf16(a0, x0, acc[0][0], 0, 0, 0);
            acc[0][1] = __builtin_amdgcn_mfma_f32_16x16x32_bf16(a0, x1, acc[0][1], 0, 0, 0);
            acc[0][2] = __builtin_amdgcn_mfma_f32_16x16x32_bf16(a0, x2, acc[0][2], 0, 0, 0);
            acc[0][3] = __builtin_amdgcn_mfma_f32_16x16x32_bf16(a0, x3, acc[0][3], 0, 0, 0);
            acc[1][0] = __builtin_amdgcn_mfma_f32_16x16x32_bf16(a1, x0, acc[1][0], 0, 0, 0);
            acc[1][1] = __builtin_amdgcn_mfma_f32_16x16x32_bf16(a1, x1, acc[1][1], 0, 0, 0);
            acc[1][2] = __builtin_amdgcn_mfma_f32_16x16x32_bf16(a1, x2, acc[1][2], 0, 0, 0);
            acc[1][3] = __builtin_amdgcn_mfma_f32_16x16x32_bf16(a1, x3, acc[1][3], 0, 0, 0);
        }
    }
    // epilogue: a = acc[0], g = acc[1]
#pragma unroll
    for (int ni = 0; ni < 4; ++ni) {
        const int hh = h0 + wv * 4 + ni;
        const int s = (t << 8) + (hh << 4) + lr;
        const size_t prow = (size_t)b * PROWS + (t + 1) * PT + (hh + 1) * 17 + (lr + 1);
        unsigned short e4[4];
#pragma unroll
        for (int r = 0; r < 4; ++r) {
            const int co = c0 + lg * 4 + r;
            float av = acc[0][ni][r] + bias[co];
            float gv = acc[1][ni][r] + bias[co + 256];
            float add = av / (1.0f + expf(-gv));
            size_t ridx = (((size_t)(b * 256 + co)) << 12) + s;
            float rn = resf[ridx] + add;
            resf[ridx] = rn;
            e4[r] = f2b(elu_f(rn));
        }
        *(ushort4*)&elub[prow * 256 + c0 + lg * 4] = *(ushort4*)e4;
    }
}

// ===== pack: xq[b][s][320] = bf16(res | orig | pos | 0) =====
__global__ __launch_bounds__(256) void pack_kernel(
    const float* __restrict__ res, const float* __restrict__ orig,
    unsigned short* __restrict__ xq)
{
    const int b = blockIdx.x >> 5;
    const int s0 = (blockIdx.x & 31) << 7;
    const int cg = blockIdx.y;
    const int tid = threadIdx.x;
    const int s = s0 + (tid & 127);
    const int c0 = cg * 32 + (tid >> 7) * 16;

    unsigned short xv[16];
    if (cg < 8) {
#pragma unroll
        for (int cc = 0; cc < 16; ++cc) {
            int c = c0 + cc;
            float v = res[(size_t)((b * 256 + c) << 12) + s];
            xv[cc] = f2b(v);
        }
    } else if (cg == 8) {
#pragma unroll
        for (int cc = 0; cc < 16; ++cc) {
            int c = c0 + cc;
            float v;
            if (c < 259)      v = orig[(size_t)((b * 3 + (c - 256)) << 12) + s];
            else if (c == 259) v = -0.5f + (float)(s >> 8) * 0.0625f;
            else if (c == 260) v = -0.5f + (float)((s >> 4) & 15) * 0.0625f;
            else if (c == 261) v = -0.5f + (float)(s & 15) * 0.0625f;
            else               v = 0.0f;
            xv[cc] = f2b(v);
        }
    } else {
#pragma unroll
        for (int cc = 0; cc < 16; ++cc) xv[cc] = 0;
    }
    unsigned short* xp = &xq[((size_t)(b << 12) + s) * 320 + c0];
    *(ushort4*)(xp)      = *(ushort4*)&xv[0];
    *(ushort4*)(xp + 4)  = *(ushort4*)&xv[4];
    *(ushort4*)(xp + 8)  = *(ushort4*)&xv[8];
    *(ushort4*)(xp + 12) = *(ushort4*)&xv[12];
}

// ===== wcvt2: pack qkv weights [192][320] (zero-pad) + attn/resc/out weights -> bf16 =====
__global__ __launch_bounds__(256) void wcvt2_kernel(
    const float* __restrict__ qw, const float* __restrict__ kw,
    const float* __restrict__ vw, const float* __restrict__ aw,
    const float* __restrict__ rw, const float* __restrict__ ow,
    unsigned short* __restrict__ wqkv, unsigned short* __restrict__ awb,
    unsigned short* __restrict__ rwb, unsigned short* __restrict__ owb)
{
    int idx = blockIdx.x * 256 + threadIdx.x;
    if (idx < 61440) {
        int r = idx / 320, c = idx - r * 320;
        float v = 0.0f;
        if (c < 262) {
            if (r < 16)       v = qw[r * 262 + c];
            else if (r < 32)  v = kw[(r - 16) * 262 + c];
            else if (r < 160) v = vw[(r - 32) * 262 + c];
        }
        wqkv[idx] = f2b(v);
    } else if (idx < 61440 + 32768) {
        int j = idx - 61440; awb[j] = f2b(aw[j]);
    } else if (idx < 61440 + 32768 + 65536) {
        int j = idx - 61440 - 32768; rwb[j] = f2b(rw[j]);
    } else if (idx < 61440 + 32768 + 131072) {
        int j = idx - 61440 - 98304; owb[j] = f2b(ow[j]);
    }
}

// ===== qkv GEMM: [192][320] @ [s][320]^T ; q,k -> bf16 [s][16]; v -> bf16 [vc][s] =====
__global__ __launch_bounds__(256) void qkv_gemm(
    const unsigned short* __restrict__ Wb, const unsigned short* __restrict__ Xt,
    const float* __restrict__ qb, const float* __restrict__ kb,
    const float* __restrict__ vb,
    unsigned short* __restrict__ qbt, unsigned short* __restrict__ kbt,
    unsigned short* __restrict__ vbt)
{
    const int b = blockIdx.x >> 5;
    const int s0 = (blockIdx.x & 31) << 7;
    const int co0 = blockIdx.y << 6;
    const int lane = threadIdx.x & 63, wv = threadIdx.x >> 6;
    const int lr = lane & 15, lg = lane >> 4;

    f32x4 acc[4][2];
#pragma unroll
    for (int mi = 0; mi < 4; ++mi)
#pragma unroll
        for (int ni = 0; ni < 2; ++ni) acc[mi][ni] = (f32x4){0.f, 0.f, 0.f, 0.f};

    const unsigned short* wp = Wb + (size_t)co0 * 320 + lg * 8;
    const unsigned short* xp = Xt + ((size_t)(b << 12) + s0 + wv * 32) * 320 + lg * 8;

#pragma unroll
    for (int kc = 0; kc < 10; ++kc) {
        int ko = kc * 32;
        bf16x8 a[4], x[2];
#pragma unroll
        for (int mi = 0; mi < 4; ++mi)
            a[mi] = *(const bf16x8*)(wp + (size_t)(mi * 16 + lr) * 320 + ko);
#pragma unroll
        for (int ni = 0; ni < 2; ++ni)
            x[ni] = *(const bf16x8*)(xp + (size_t)(ni * 16 + lr) * 320 + ko);
#pragma unroll
        for (int mi = 0; mi < 4; ++mi)
#pragma unroll
            for (int ni = 0; ni < 2; ++ni)
                acc[mi][ni] = __builtin_amdgcn_mfma_f32_16x16x32_bf16(
                    a[mi], x[ni], acc[mi][ni], 0, 0, 0);
    }
#pragma unroll
    for (int mi = 0; mi < 4; ++mi)
#pragma unroll
    for (int ni = 0; ni < 2; ++ni)
#pragma unroll
    for (int r = 0; r < 4; ++r) {
        int co = co0 + mi * 16 + lg * 4 + r;
        if (co >= 160) continue;
        int s = s0 + wv * 32 + ni * 16 + lr;
        float bias = (co < 16) ? qb[co] : ((co < 32) ? kb[co - 16] : vb[co - 32]);
        float v = acc[mi][ni][r] + bias;
        if (co < 16)      qbt[((size_t)(b << 12) + s) * 16 + co] = f2b(v);
        else if (co < 32) kbt[((size_t)(b << 12) + s) * 16 + (co - 16)] = f2b(v);
        else              vbt[((size_t)((b << 7) + (co - 32)) << 12) + s] = f2b(v);
    }
}

// ===== attention partial: MFMA QK^T + in-register softmax (swapped operands) =====
__global__ __launch_bounds__(256) void attn_part2(
    const unsigned short* __restrict__ qbt, const unsigned short* __restrict__ kbt,
    const unsigned short* __restrict__ vbt,
    float* __restrict__ pacc, float* __restrict__ pml)
{
    const int bx = blockIdx.x;
    const int b = bx >> 8;
    const int qt = (bx >> 2) & 63;
    const int seg = bx & 3;
    const int q0 = qt << 6;
    const int nch = (qt >> 1) + 1;
    const int c_lo = seg << 3;
    if (c_lo >= nch) return;
    const int c_hi = min(c_lo + 8, nch);

    __shared__ unsigned short sK[128 * 16];
    __shared__ unsigned short sP[4][16 * 136];

    const int tid = threadIdx.x;
    const int lane = tid & 63, wv = tid >> 6;
    const int lr = lane & 15, lg = lane >> 4;
    const int qa = q0 + wv * 16 + lr;
    const float scale = 1.0f / sqrtf(259.0f);

    bf16x8 qf = (bf16x8){0, 0, 0, 0, 0, 0, 0, 0};
    if (lg < 2)
        qf = *(const bf16x8*)(qbt + ((size_t)(b << 12) + qa) * 16 + lg * 8);

    f32x4 oacc[8];
#pragma unroll
    for (int vct = 0; vct < 8; ++vct) oacc[vct] = (f32x4){0.f, 0.f, 0.f, 0.f};
    float m = -1e30f, l = 0.0f;

    unsigned short* myP = &sP[wv][0];

    for (int kc = c_lo; kc < c_hi; ++kc) {
        const int kv0 = kc << 7;
        __syncthreads();
        *(bf16x8*)&sK[(tid >> 1) * 16 + (tid & 1) * 8] =
            *(const bf16x8*)(kbt + ((size_t)(b << 12) + kv0 + (tid >> 1)) * 16 + (tid & 1) * 8);
        __syncthreads();

        f32x4 sc[8];
#pragma unroll
        for (int kvt = 0; kvt < 8; ++kvt) {
            bf16x8 af = (bf16x8){0, 0, 0, 0, 0, 0, 0, 0};
            if (lg < 2)
                af = *(const bf16x8*)&sK[(kvt * 16 + lr) * 16 + lg * 8];
            sc[kvt] = __builtin_amdgcn_mfma_f32_16x16x32_bf16(
                af, qf, (f32x4){0.f, 0.f, 0.f, 0.f}, 0, 0, 0);
        }
        float mc = -1e30f;
#pragma unroll
        for (int kvt = 0; kvt < 8; ++kvt) {
#pragma unroll
            for (int r = 0; r < 4; ++r) {
                int kv = kv0 + kvt * 16 + lg * 4 + r;
                float s = (kv < qa) ? sc[kvt][r] * scale : -1e30f;
                sc[kvt][r] = s;
                mc = fmaxf(mc, s);
            }
        }
        mc = fmaxf(mc, __shfl_xor(mc, 16, 64));
        mc = fmaxf(mc, __shfl_xor(mc, 32, 64));
        float mn = fmaxf(m, mc);
        float fac = __expf(m - mn);
        float ls = 0.0f;
#pragma unroll
        for (int kvt = 0; kvt < 8; ++kvt) {
#pragma unroll
            for (int e = 0; e < 2; ++e) {
                float s0v = sc[kvt][2 * e];
                float s1v = sc[kvt][2 * e + 1];
                float p0 = (s0v <= -1e29f) ? 0.f : __expf(s0v - mn);
                float p1 = (s1v <= -1e29f) ? 0.f : __expf(s1v - mn);
                ls += p0 + p1;
                unsigned int pk = (unsigned int)f2b(p0) | ((unsigned int)f2b(p1) << 16);
                int kv = kvt * 16 + lg * 4 + 2 * e;
                *(unsigned int*)&myP[lr * 136 + kv] = pk;
            }
        }
        ls += __shfl_xor(ls, 16, 64);
        ls += __shfl_xor(ls, 32, 64);
        l = l * fac + ls;
        m = mn;
#pragma unroll
        for (int vct = 0; vct < 8; ++vct) {
            oacc[vct][0] *= fac; oacc[vct][1] *= fac;
            oacc[vct][2] *= fac; oacc[vct][3] *= fac;
        }
#pragma unroll
        for (int ks = 0; ks < 4; ++ks) {
            bf16x8 pf = *(const bf16x8*)&myP[lr * 136 + ks * 32 + lg * 8];
#pragma unroll
            for (int vct = 0; vct < 8; ++vct) {
                bf16x8 vf = *(const bf16x8*)(vbt +
                    ((size_t)((b << 7) + vct * 16 + lr) << 12) + kv0 + ks * 32 + lg * 8);
                oacc[vct] = __builtin_amdgcn_mfma_f32_16x16x32_bf16(
                    vf, pf, oacc[vct], 0, 0, 0);
            }
        }
    }

    const int a_ = qt >> 4;
    const int slot = b * 160 + 8 * a_ * (a_ + 1) + (qt & 15) * (a_ + 1) + seg;
    float* ap = pacc + (size_t)slot * 8192;
#pragma unroll
    for (int vct = 0; vct < 8; ++vct)
        *(f32x4*)&ap[(wv * 16 + lr) * 128 + vct * 16 + lg * 4] = oacc[vct];
    if (lg == 0) {
        pml[slot * 128 + (wv * 16 + lr) * 2]     = m;
        pml[slot * 128 + (wv * 16 + lr) * 2 + 1] = l;
    }
}

// ===== attention combine =====
__global__ __launch_bounds__(256) void attn_combine2(
    const float* __restrict__ pacc, const float* __restrict__ pml,
    unsigned short* __restrict__ attEb)
{
    const int bx = blockIdx.x;
    const int b = bx >> 7;
    const int qt = (bx >> 1) & 63;
    const int half = bx & 1;
    const int a_ = qt >> 4;
    const int nseg_alloc = a_ + 1;
    const int nch = (qt >> 1) + 1;
    const int nseg = (nch + 7) >> 3;
    const int base = b * 160 + 8 * a_ * (a_ + 1) + (qt & 15) * nseg_alloc;
    const int tid = threadIdx.x;
    const int qq = (tid >> 3) + half * 32;
    const int vg = tid & 7;

    float mi_[4], li_[4];
    float m = -1e30f;
    for (int i = 0; i < nseg; ++i) {
        mi_[i] = pml[(base + i) * 128 + qq * 2];
        li_[i] = pml[(base + i) * 128 + qq * 2 + 1];
        m = fmaxf(m, mi_[i]);
    }
    float w[4];
    float l = 0.f;
    for (int i = 0; i < nseg; ++i) {
        float wi = (mi_[i] <= -1e29f) ? 0.f : __expf(mi_[i] - m);
        w[i] = wi;
        l += wi * li_[i];
    }
    float inv = (l > 0.f) ? 1.f / l : 0.f;
    int q = (qt << 6) + qq;
#pragma unroll
    for (int v4 = 0; v4 < 4; ++v4) {
        int vc = vg * 16 + v4 * 4;
        float o0 = 0.f, o1 = 0.f, o2 = 0.f, o3 = 0.f;
        for (int i = 0; i < nseg; ++i) {
            f32x4 a = *(const f32x4*)(pacc + (size_t)(base + i) * 8192 + qq * 128 + vc);
            o0 = fmaf(w[i], a[0], o0);
            o1 = fmaf(w[i], a[1], o1);
            o2 = fmaf(w[i], a[2], o2);
            o3 = fmaf(w[i], a[3], o3);
        }
        unsigned short r0 = f2b(elu_f(o0 * inv));
        unsigned short r1 = f2b(elu_f(o1 * inv));
        unsigned short r2 = f2b(elu_f(o2 * inv));
        unsigned short r3 = f2b(elu_f(o3 * inv));
        ushort4 pk = {r0, r1, r2, r3};
        *(ushort4*)&attEb[((size_t)(b << 12) + q) * 128 + vc] = pk;
    }
}

// ===== final_ab GEMM: sum2b = bf16(elu( elu(W1@attEb+b1) + elu(W2@eluP+b2) )) =====
// X2 = padded elu(res) buffer, remapped per-fragment
__global__ __launch_bounds__(256) void final_ab_gemm(
    const unsigned short* __restrict__ W1b, const unsigned short* __restrict__ W2b,
    const unsigned short* __restrict__ X1, const unsigned short* __restrict__ X2,
    const float* __restrict__ b1, const float* __restrict__ b2,
    unsigned short* __restrict__ sum2b)
{
    const int b = blockIdx.x >> 5;
    const int s0 = (blockIdx.x & 31) << 7;
    const int co0 = blockIdx.y << 6;
    const int lane = threadIdx.x & 63, wv = threadIdx.x >> 6;
    const int lr = lane & 15, lg = lane >> 4;

    f32x4 acc1[4][2], acc2[4][2];
#pragma unroll
    for (int mi = 0; mi < 4; ++mi)
#pragma unroll
        for (int ni = 0; ni < 2; ++ni) {
            acc1[mi][ni] = (f32x4){0.f, 0.f, 0.f, 0.f};
            acc2[mi][ni] = (f32x4){0.f, 0.f, 0.f, 0.f};
        }

    {
        const unsigned short* wp = W1b + (size_t)co0 * 128 + lg * 8;
        const unsigned short* xp = X1 + ((size_t)(b << 12) + s0 + wv * 32) * 128 + lg * 8;
#pragma unroll
        for (int kc = 0; kc < 4; ++kc) {
            int ko = kc * 32;
            bf16x8 a[4], x[2];
#pragma unroll
            for (int mi = 0; mi < 4; ++mi)
                a[mi] = *(const bf16x8*)(wp + (size_t)(mi * 16 + lr) * 128 + ko);
#pragma unroll
            for (int ni = 0; ni < 2; ++ni)
                x[ni] = *(const bf16x8*)(xp + (size_t)(ni * 16 + lr) * 128 + ko);
#pragma unroll
            for (int mi = 0; mi < 4; ++mi)
#pragma unroll
                for (int ni = 0; ni < 2; ++ni)
                    acc1[mi][ni] = __builtin_amdgcn_mfma_f32_16x16x32_bf16(
                        a[mi], x[ni], acc1[mi][ni], 0, 0, 0);
        }
    }
    {
        const unsigned short* wp = W2b + (size_t)co0 * 256 + lg * 8;
        const unsigned short* xp2[2];
#pragma unroll
        for (int ni = 0; ni < 2; ++ni) {
            int u = (s0 >> 4) + wv * 2 + ni;
            int tt = u >> 4, hh = u & 15;
            xp2[ni] = X2 + ((size_t)b * PROWS + (tt + 1) * PT + (hh + 1) * 17 + (lr + 1)) * 256 + lg * 8;
        }
#pragma unroll
        for (int kc = 0; kc < 8; ++kc) {
            int ko = kc * 32;
            bf16x8 a[4], x[2];
#pragma unroll
            for (int mi = 0; mi < 4; ++mi)
                a[mi] = *(const bf16x8*)(wp + (size_t)(mi * 16 + lr) * 256 + ko);
#pragma unroll
            for (int ni = 0; ni < 2; ++ni)
                x[ni] = *(const bf16x8*)(xp2[ni] + ko);
#pragma unroll
            for (int mi = 0; mi < 4; ++mi)
#pragma unroll
                for (int ni = 0; ni < 2; ++ni)
                    acc2[mi][ni] = __builtin_amdgcn_mfma_f32_16x16x32_bf16(
                        a[mi], x[ni], acc2[mi][ni], 0, 0, 0);
        }
    }
#pragma unroll
    for (int mi = 0; mi < 4; ++mi)
#pragma unroll
    for (int ni = 0; ni < 2; ++ni)
#pragma unroll
    for (int r = 0; r < 4; ++r) {
        int co = co0 + mi * 16 + lg * 4 + r;
        int s = s0 + wv * 32 + ni * 16 + lr;
        float v1 = elu_f(acc1[mi][ni][r] + b1[co]);
        float v2 = elu_f(acc2[mi][ni][r] + b2[co]);
        sum2b[((size_t)(b << 12) + s) * 256 + co] = f2b(elu_f(v1 + v2));
    }
}

// ===== final_c GEMM: out = elu(outW@sum2b + out_b), fp32 [b][256][4096] =====
__global__ __launch_bounds__(256) void final_c_gemm(
    const unsigned short* __restrict__ Wb, const unsigned short* __restrict__ Xt,
    const float* __restrict__ bias, float* __restrict__ out)
{
    const int b = blockIdx.x >> 5;
    const int s0 = (blockIdx.x & 31) << 7;
    const int co0 = blockIdx.y << 6;
    const int lane = threadIdx.x & 63, wv = threadIdx.x >> 6;
    const int lr = lane & 15, lg = lane >> 4;

    f32x4 acc[4][2];
#pragma unroll
    for (int mi = 0; mi < 4; ++mi)
#pragma unroll
        for (int ni = 0; ni < 2; ++ni) acc[mi][ni] = (f32x4){0.f, 0.f, 0.f, 0.f};

    const unsigned short* wp = Wb + (size_t)co0 * 256 + lg * 8;
    const unsigned short* xp = Xt + ((size_t)(b << 12) + s0 + wv * 32) * 256 + lg * 8;
#pragma unroll
    for (int kc = 0; kc < 8; ++kc) {
        int ko = kc * 32;
        bf16x8 a[4], x[2];
#pragma unroll
        for (int mi = 0; mi < 4; ++mi)
            a[mi] = *(const bf16x8*)(wp + (size_t)(mi * 16 + lr) * 256 + ko);
#pragma unroll
        for (int ni = 0; ni < 2; ++ni)
            x[ni] = *(const bf16x8*)(xp + (size_t)(ni * 16 + lr) * 256 + ko);
#pragma unroll
        for (int mi = 0; mi < 4; ++mi)
#pragma unroll
            for (int ni = 0; ni < 2; ++ni)
                acc[mi][ni] = __builtin_amdgcn_mfma_f32_16x16x32_bf16(
                    a[mi], x[ni], acc[mi][ni], 0, 0, 0);
    }
#pragma unroll
    for (int mi = 0; mi < 4; ++mi)
#pragma unroll
    for (int ni = 0; ni < 2; ++ni)
#pragma unroll
    for (int r = 0; r < 4; ++r) {
        int co = co0 + mi * 16 + lg * 4 + r;
        int s = s0 + wv * 32 + ni * 16 + lr;
        out[((size_t)(b * 256 + co) << 12) + s] = elu_f(acc[mi][ni][r] + bias[co]);
    }
}

extern "C" void kernel_launch(void* const* d_in, const int* in_sizes, int n_in,
                              void* d_out, int out_size, void* d_ws, size_t ws_size,
                              hipStream_t stream) {
    const float* x      = (const float*)d_in[0];
    const float* orig   = (const float*)d_in[1];
    const float* rb_w1  = (const float*)d_in[2];
    const float* rb_b1  = (const float*)d_in[3];
    const float* rb_w2  = (const float*)d_in[4];
    const float* rb_b2  = (const float*)d_in[5];
    const float* q_w    = (const float*)d_in[6];
    const float* q_b    = (const float*)d_in[7];
    const float* k_w    = (const float*)d_in[8];
    const float* k_b    = (const float*)d_in[9];
    const float* v_w    = (const float*)d_in[10];
    const float* v_b    = (const float*)d_in[11];
    const float* attn_w = (const float*)d_in[12];
    const float* attn_b = (const float*)d_in[13];
    const float* resc_w = (const float*)d_in[14];
    const float* resc_b = (const float*)d_in[15];
    const float* out_w  = (const float*)d_in[16];
    const float* out_b  = (const float*)d_in[17];
    float* out = (float*)d_out;

    char* base = (char*)d_ws;
    // layout (bytes):
    float*          res   = (float*)(base);                          // 0..8MB  [b][c][s] fp32
    unsigned short* elubP = (unsigned short*)(base + (8u << 20));    // 8..13MB  padded [b][4913][256]
    unsigned short* o1P   = (unsigned short*)(base + (13u << 20));   // 13..18MB padded
    unsigned short* w1t   = (unsigned short*)(base + (18u << 20));   // 18..22MB
    unsigned short* w2t   = (unsigned short*)(base + (22u << 20));   // 22..30MB
    // aliases after conv loop:
    unsigned short* vbt   = o1P;                                     // 2MB @13MB
    unsigned short* attEb = (unsigned short*)(base + (15u << 20));   // 2MB @15MB
    unsigned short* sum2b = w1t;                                     // 4MB @18MB
    unsigned short* xqkvB = w2t;                                     // 5MB @22MB (dead after qkv_gemm)
    float*          pacc  = (float*)(base + (22u << 20));            // 10MB @22MB (alias over xqkvB)
    unsigned short* qbt   = (unsigned short*)(base + (32u << 20));            // 256KB
    unsigned short* kbt   = (unsigned short*)(base + (32u << 20) + 262144);   // 256KB
    unsigned short* wqkvB = (unsigned short*)(base + (32u << 20) + 524288);   // 120KB
    unsigned short* attnWb= (unsigned short*)(base + (32u << 20) + 655360);   // 64KB
    unsigned short* rescWb= (unsigned short*)(base + (32u << 20) + 720896);   // 128KB
    unsigned short* outWb = (unsigned short*)(base + (32u << 20) + 851968);   // 128KB
    float*          pml   = (float*)(base + (32u << 20) + 983040);           // 160KB

    const int nz = (2 * PROWS * 256 * 2) / 16;   // uint4 count per padded buffer
    zero2_kernel<<<(nz + 255) / 256, 256, 0, stream>>>(
        (uint4*)elubP, (uint4*)o1P, nz);

    hipMemcpyAsync(res, x, (size_t)2097152 * sizeof(float),
                   hipMemcpyDeviceToDevice, stream);
    prep_t<<<dim3(64, 8), 256, 0, stream>>>(x, elubP);
    wcvt_kernel<<<16384, 256, 0, stream>>>(rb_w1, rb_w2, w1t, w2t);

    for (int i = 0; i < 4; ++i) {
        conv1_mfma<<<dim3(64, 8), 128, 0, stream>>>(
            elubP, w1t + (size_t)i * 524288, rb_b1 + i * 256, o1P);
        conv2_mfma<<<dim3(64, 16), 128, 0, stream>>>(
            o1P, w2t + (size_t)i * 1048576, rb_b2 + i * 512, res, elubP);
    }

    pack_kernel<<<dim3(64, 10), 256, 0, stream>>>(res, orig, xqkvB);
    wcvt2_kernel<<<880, 256, 0, stream>>>(q_w, k_w, v_w, attn_w, resc_w, out_w,
                                          wqkvB, attnWb, rescWb, outWb);

    qkv_gemm<<<dim3(64, 3), 256, 0, stream>>>(wqkvB, xqkvB, q_b, k_b, v_b,
                                              qbt, kbt, vbt);

    attn_part2<<<512, 256, 0, stream>>>(qbt, kbt, vbt, pacc, pml);
    attn_combine2<<<256, 256, 0, stream>>>(pacc, pml, attEb);

    final_ab_gemm<<<dim3(64, 4), 256, 0, stream>>>(
        attnWb, rescWb, attEb, elubP, attn_b, resc_b, sum2b);

    final_c_gemm<<<dim3(64, 4), 256, 0, stream>>>(outWb, sum2b, out_b, out);
}

// Round 9
// 702.330 us; speedup vs baseline: 6.7861x; 1.0267x over previous
//
#include <hip/hip_runtime.h>
#include <math.h>

#define SEQ 4096
#define CIN 256
#define PROWS 4913   // 17*17*17 padded spatial rows
#define PT 289       // 17*17

typedef __attribute__((ext_vector_type(8))) short bf16x8;
typedef __attribute__((ext_vector_type(4))) float f32x4;

__device__ __forceinline__ float elu_f(float x) {
    return x > 0.0f ? x : (expf(x) - 1.0f);
}
__device__ __forceinline__ unsigned short f2b(float f) {
    unsigned int u = __float_as_uint(f);
    return (unsigned short)((u + 0x7FFFu + ((u >> 16) & 1u)) >> 16);
}

struct Frag6 { bf16x8 a0, a1, x0, x1, x2, x3; };

// ===== zero2: clear both padded activation buffers (halo must be 0) =====
__global__ __launch_bounds__(256) void zero2_kernel(
    uint4* __restrict__ p1, uint4* __restrict__ p2, int n)
{
    int i = blockIdx.x * 256 + threadIdx.x;
    if (i < n) {
        p1[i] = (uint4){0, 0, 0, 0};
        p2[i] = (uint4){0, 0, 0, 0};
    }
}

// ===== prep_t: elubP[b][padded pos][256] = bf16(elu(x)) =====
__global__ __launch_bounds__(256) void prep_t(
    const float* __restrict__ x, unsigned short* __restrict__ elub)
{
    const int b = blockIdx.x >> 5;
    const int s0 = (blockIdx.x & 31) << 7;
    const int cg = blockIdx.y;
    const int tid = threadIdx.x;
    const int s = s0 + (tid & 127);
    const int c0 = cg * 32 + (tid >> 7) * 16;
    const int tt = s >> 8, hh = (s >> 4) & 15, ww = s & 15;
    const size_t prow = (size_t)b * PROWS + (tt + 1) * PT + (hh + 1) * 17 + (ww + 1);
    unsigned short ev[16];
#pragma unroll
    for (int cc = 0; cc < 16; ++cc) {
        float v = x[(((size_t)(b * 256 + c0 + cc)) << 12) + s];
        ev[cc] = f2b(elu_f(v));
    }
    unsigned short* ep = &elub[prow * 256 + c0];
    *(ushort4*)(ep)      = *(ushort4*)&ev[0];
    *(ushort4*)(ep + 4)  = *(ushort4*)&ev[4];
    *(ushort4*)(ep + 8)  = *(ushort4*)&ev[8];
    *(ushort4*)(ep + 12) = *(ushort4*)&ev[12];
}

// ===== wcvt: conv weights -> bf16, transposed to [layer][tap][row][ci] =====
__global__ __launch_bounds__(256) void wcvt_kernel(
    const float* __restrict__ w1, const float* __restrict__ w2,
    unsigned short* __restrict__ w1t, unsigned short* __restrict__ w2t)
{
    int idx = blockIdx.x * 256 + threadIdx.x;
    if (idx < 2097152) {
        int i   = idx >> 19;
        int tap = (idx >> 16) & 7;
        int co  = (idx >> 8) & 255;
        int ci  = idx & 255;
        w1t[idx] = f2b(w1[(((size_t)(i * 256 + co)) * 256 + ci) * 8 + tap]);
    }
    if (idx < 4194304) {
        int i   = idx >> 20;
        int tap = (idx >> 17) & 7;
        int row = (idx >> 8) & 511;
        int ci  = idx & 255;
        int grp = row >> 5, sub = row & 31;
        int co = (sub < 16) ? (grp * 16 + sub) : (256 + grp * 16 + (sub - 16));
        w2t[idx] = f2b(w2[(((size_t)(i * 512 + co)) * 256 + ci) * 8 + tap]);
    }
}

// ===== conv1: padded tap-GEMM, 1-deep explicit prefetch. 32co x 128pos, 2 waves =====
__global__ __launch_bounds__(128) void conv1_mfma(
    const unsigned short* __restrict__ inP,   // [b][4913][256] padded
    const unsigned short* __restrict__ wT,    // [8][256][256]
    const float* __restrict__ bias,
    unsigned short* __restrict__ outP)        // [b][4913][256] padded
{
    const int bx = blockIdx.x;
    const int b = bx >> 5, ptile = bx & 31;
    const int t = ptile >> 1, h0 = (ptile & 1) * 8;
    const int co0 = blockIdx.y << 5;
    const int lane = threadIdx.x & 63, wv = threadIdx.x >> 6;
    const int lr = lane & 15, lg = lane >> 4;

    const unsigned short* inB = inP + (size_t)b * PROWS * 256;

    const unsigned short* xptr[4];
#pragma unroll
    for (int ni = 0; ni < 4; ++ni) {
        int pbase = t * PT + (h0 + wv * 4 + ni) * 17 + lr;
        xptr[ni] = inB + (size_t)pbase * 256 + lg * 8;
    }
    const unsigned short* aptr[2];
#pragma unroll
    for (int mi = 0; mi < 2; ++mi)
        aptr[mi] = wT + (size_t)(co0 + mi * 16 + lr) * 256 + lg * 8;

    f32x4 acc[2][4];
#pragma unroll
    for (int mi = 0; mi < 2; ++mi)
#pragma unroll
        for (int ni = 0; ni < 4; ++ni) acc[mi][ni] = (f32x4){0.f, 0.f, 0.f, 0.f};

#define LOADSTEP1(S, F) do {                                                    \
        const int tap_ = (S) >> 3, kc_ = (S) & 7;                               \
        const int td_ = (((tap_ >> 2) * PT) + (((tap_ >> 1) & 1) * 17)          \
                         + (tap_ & 1)) * 256;                                   \
        const int wd_ = tap_ * 65536;                                           \
        const int ko_ = kc_ * 32;                                               \
        (F).a0 = *(const bf16x8*)(aptr[0] + wd_ + ko_);                         \
        (F).a1 = *(const bf16x8*)(aptr[1] + wd_ + ko_);                         \
        (F).x0 = *(const bf16x8*)(xptr[0] + td_ + ko_);                         \
        (F).x1 = *(const bf16x8*)(xptr[1] + td_ + ko_);                         \
        (F).x2 = *(const bf16x8*)(xptr[2] + td_ + ko_);                         \
        (F).x3 = *(const bf16x8*)(xptr[3] + td_ + ko_);                         \
    } while (0)

    Frag6 cur;
    LOADSTEP1(0, cur);
#pragma unroll
    for (int s = 0; s < 64; ++s) {
        Frag6 nxt;
        if (s < 63) LOADSTEP1(s + 1, nxt);
        acc[0][0] = __builtin_amdgcn_mfma_f32_16x16x32_bf16(cur.a0, cur.x0, acc[0][0], 0, 0, 0);
        acc[0][1] = __builtin_amdgcn_mfma_f32_16x16x32_bf16(cur.a0, cur.x1, acc[0][1], 0, 0, 0);
        acc[0][2] = __builtin_amdgcn_mfma_f32_16x16x32_bf16(cur.a0, cur.x2, acc[0][2], 0, 0, 0);
        acc[0][3] = __builtin_amdgcn_mfma_f32_16x16x32_bf16(cur.a0, cur.x3, acc[0][3], 0, 0, 0);
        acc[1][0] = __builtin_amdgcn_mfma_f32_16x16x32_bf16(cur.a1, cur.x0, acc[1][0], 0, 0, 0);
        acc[1][1] = __builtin_amdgcn_mfma_f32_16x16x32_bf16(cur.a1, cur.x1, acc[1][1], 0, 0, 0);
        acc[1][2] = __builtin_amdgcn_mfma_f32_16x16x32_bf16(cur.a1, cur.x2, acc[1][2], 0, 0, 0);
        acc[1][3] = __builtin_amdgcn_mfma_f32_16x16x32_bf16(cur.a1, cur.x3, acc[1][3], 0, 0, 0);
        if (s < 63) cur = nxt;
    }
#undef LOADSTEP1

#pragma unroll
    for (int ni = 0; ni < 4; ++ni) {
        const int hh = h0 + wv * 4 + ni;
        const size_t orow = (size_t)b * PROWS + (t + 1) * PT + (hh + 1) * 17 + (lr + 1);
#pragma unroll
        for (int mi = 0; mi < 2; ++mi) {
            const int cob = co0 + mi * 16 + lg * 4;
            unsigned short v4[4];
#pragma unroll
            for (int r = 0; r < 4; ++r)
                v4[r] = f2b(elu_f(acc[mi][ni][r] + bias[cob + r]));
            *(ushort4*)&outP[orow * 256 + cob] = *(ushort4*)v4;
        }
    }
}

// ===== conv2: padded tap-GEMM + gate, 1-deep prefetch. 16 pairs x 128pos, 2 waves =====
__global__ __launch_bounds__(128) void conv2_mfma(
    const unsigned short* __restrict__ inP,   // o1P padded
    const unsigned short* __restrict__ wT,    // [8][512][256] permuted
    const float* __restrict__ bias,           // [512]
    float* __restrict__ resf,                 // [b][256][4096]
    unsigned short* __restrict__ elub)        // padded [b][4913][256]
{
    const int bx = blockIdx.x;
    const int b = bx >> 5, ptile = bx & 31;
    const int t = ptile >> 1, h0 = (ptile & 1) * 8;
    const int c0 = blockIdx.y << 4;
    const int wrow0 = blockIdx.y << 5;
    const int lane = threadIdx.x & 63, wv = threadIdx.x >> 6;
    const int lr = lane & 15, lg = lane >> 4;

    const unsigned short* inB = inP + (size_t)b * PROWS * 256;

    const unsigned short* xptr[4];
#pragma unroll
    for (int ni = 0; ni < 4; ++ni) {
        int pbase = t * PT + (h0 + wv * 4 + ni) * 17 + lr;
        xptr[ni] = inB + (size_t)pbase * 256 + lg * 8;
    }
    const unsigned short* aptr[2];
#pragma unroll
    for (int mi = 0; mi < 2; ++mi)
        aptr[mi] = wT + (size_t)(wrow0 + mi * 16 + lr) * 256 + lg * 8;

    f32x4 acc[2][4];
#pragma unroll
    for (int mi = 0; mi < 2; ++mi)
#pragma unroll
        for (int ni = 0; ni < 4; ++ni) acc[mi][ni] = (f32x4){0.f, 0.f, 0.f, 0.f};

#define LOADSTEP2(S, F) do {                                                    \
        const int tap_ = (S) >> 3, kc_ = (S) & 7;                               \
        const int td_ = (((tap_ >> 2) * PT) + (((tap_ >> 1) & 1) * 17)          \
                         + (tap_ & 1)) * 256;                                   \
        const int wd_ = tap_ * 131072;                                          \
        const int ko_ = kc_ * 32;                                               \
        (F).a0 = *(const bf16x8*)(aptr[0] + wd_ + ko_);                         \
        (F).a1 = *(const bf16x8*)(aptr[1] + wd_ + ko_);                         \
        (F).x0 = *(const bf16x8*)(xptr[0] + td_ + ko_);                         \
        (F).x1 = *(const bf16x8*)(xptr[1] + td_ + ko_);                         \
        (F).x2 = *(const bf16x8*)(xptr[2] + td_ + ko_);                         \
        (F).x3 = *(const bf16x8*)(xptr[3] + td_ + ko_);                         \
    } while (0)

    Frag6 cur;
    LOADSTEP2(0, cur);
#pragma unroll
    for (int s = 0; s < 64; ++s) {
        Frag6 nxt;
        if (s < 63) LOADSTEP2(s + 1, nxt);
        acc[0][0] = __builtin_amdgcn_mfma_f32_16x16x32_bf16(cur.a0, cur.x0, acc[0][0], 0, 0, 0);
        acc[0][1] = __builtin_amdgcn_mfma_f32_16x16x32_bf16(cur.a0, cur.x1, acc[0][1], 0, 0, 0);
        acc[0][2] = __builtin_amdgcn_mfma_f32_16x16x32_bf16(cur.a0, cur.x2, acc[0][2], 0, 0, 0);
        acc[0][3] = __builtin_amdgcn_mfma_f32_16x16x32_bf16(cur.a0, cur.x3, acc[0][3], 0, 0, 0);
        acc[1][0] = __builtin_amdgcn_mfma_f32_16x16x32_bf16(cur.a1, cur.x0, acc[1][0], 0, 0, 0);
        acc[1][1] = __builtin_amdgcn_mfma_f32_16x16x32_bf16(cur.a1, cur.x1, acc[1][1], 0, 0, 0);
        acc[1][2] = __builtin_amdgcn_mfma_f32_16x16x32_bf16(cur.a1, cur.x2, acc[1][2], 0, 0, 0);
        acc[1][3] = __builtin_amdgcn_mfma_f32_16x16x32_bf16(cur.a1, cur.x3, acc[1][3], 0, 0, 0);
        if (s < 63) cur = nxt;
    }
#undef LOADSTEP2

    // epilogue: a = acc[0], g = acc[1]
#pragma unroll
    for (int ni = 0; ni < 4; ++ni) {
        const int hh = h0 + wv * 4 + ni;
        const int s = (t << 8) + (hh << 4) + lr;
        const size_t prow = (size_t)b * PROWS + (t + 1) * PT + (hh + 1) * 17 + (lr + 1);
        unsigned short e4[4];
#pragma unroll
        for (int r = 0; r < 4; ++r) {
            const int co = c0 + lg * 4 + r;
            float av = acc[0][ni][r] + bias[co];
            float gv = acc[1][ni][r] + bias[co + 256];
            float add = av / (1.0f + expf(-gv));
            size_t ridx = (((size_t)(b * 256 + co)) << 12) + s;
            float rn = resf[ridx] + add;
            resf[ridx] = rn;
            e4[r] = f2b(elu_f(rn));
        }
        *(ushort4*)&elub[prow * 256 + c0 + lg * 4] = *(ushort4*)e4;
    }
}

// ===== pack: xq[b][s][320] = bf16(res | orig | pos | 0) =====
__global__ __launch_bounds__(256) void pack_kernel(
    const float* __restrict__ res, const float* __restrict__ orig,
    unsigned short* __restrict__ xq)
{
    const int b = blockIdx.x >> 5;
    const int s0 = (blockIdx.x & 31) << 7;
    const int cg = blockIdx.y;
    const int tid = threadIdx.x;
    const int s = s0 + (tid & 127);
    const int c0 = cg * 32 + (tid >> 7) * 16;

    unsigned short xv[16];
    if (cg < 8) {
#pragma unroll
        for (int cc = 0; cc < 16; ++cc) {
            int c = c0 + cc;
            float v = res[(size_t)((b * 256 + c) << 12) + s];
            xv[cc] = f2b(v);
        }
    } else if (cg == 8) {
#pragma unroll
        for (int cc = 0; cc < 16; ++cc) {
            int c = c0 + cc;
            float v;
            if (c < 259)      v = orig[(size_t)((b * 3 + (c - 256)) << 12) + s];
            else if (c == 259) v = -0.5f + (float)(s >> 8) * 0.0625f;
            else if (c == 260) v = -0.5f + (float)((s >> 4) & 15) * 0.0625f;
            else if (c == 261) v = -0.5f + (float)(s & 15) * 0.0625f;
            else               v = 0.0f;
            xv[cc] = f2b(v);
        }
    } else {
#pragma unroll
        for (int cc = 0; cc < 16; ++cc) xv[cc] = 0;
    }
    unsigned short* xp = &xq[((size_t)(b << 12) + s) * 320 + c0];
    *(ushort4*)(xp)      = *(ushort4*)&xv[0];
    *(ushort4*)(xp + 4)  = *(ushort4*)&xv[4];
    *(ushort4*)(xp + 8)  = *(ushort4*)&xv[8];
    *(ushort4*)(xp + 12) = *(ushort4*)&xv[12];
}

// ===== wcvt2: pack qkv weights [192][320] (zero-pad) + attn/resc/out weights -> bf16 =====
__global__ __launch_bounds__(256) void wcvt2_kernel(
    const float* __restrict__ qw, const float* __restrict__ kw,
    const float* __restrict__ vw, const float* __restrict__ aw,
    const float* __restrict__ rw, const float* __restrict__ ow,
    unsigned short* __restrict__ wqkv, unsigned short* __restrict__ awb,
    unsigned short* __restrict__ rwb, unsigned short* __restrict__ owb)
{
    int idx = blockIdx.x * 256 + threadIdx.x;
    if (idx < 61440) {
        int r = idx / 320, c = idx - r * 320;
        float v = 0.0f;
        if (c < 262) {
            if (r < 16)       v = qw[r * 262 + c];
            else if (r < 32)  v = kw[(r - 16) * 262 + c];
            else if (r < 160) v = vw[(r - 32) * 262 + c];
        }
        wqkv[idx] = f2b(v);
    } else if (idx < 61440 + 32768) {
        int j = idx - 61440; awb[j] = f2b(aw[j]);
    } else if (idx < 61440 + 32768 + 65536) {
        int j = idx - 61440 - 32768; rwb[j] = f2b(rw[j]);
    } else if (idx < 61440 + 32768 + 131072) {
        int j = idx - 61440 - 98304; owb[j] = f2b(ow[j]);
    }
}

// ===== qkv GEMM: [192][320] @ [s][320]^T ; q,k -> bf16 [s][16]; v -> bf16 [vc][s] =====
__global__ __launch_bounds__(256) void qkv_gemm(
    const unsigned short* __restrict__ Wb, const unsigned short* __restrict__ Xt,
    const float* __restrict__ qb, const float* __restrict__ kb,
    const float* __restrict__ vb,
    unsigned short* __restrict__ qbt, unsigned short* __restrict__ kbt,
    unsigned short* __restrict__ vbt)
{
    const int b = blockIdx.x >> 5;
    const int s0 = (blockIdx.x & 31) << 7;
    const int co0 = blockIdx.y << 6;
    const int lane = threadIdx.x & 63, wv = threadIdx.x >> 6;
    const int lr = lane & 15, lg = lane >> 4;

    f32x4 acc[4][2];
#pragma unroll
    for (int mi = 0; mi < 4; ++mi)
#pragma unroll
        for (int ni = 0; ni < 2; ++ni) acc[mi][ni] = (f32x4){0.f, 0.f, 0.f, 0.f};

    const unsigned short* wp = Wb + (size_t)co0 * 320 + lg * 8;
    const unsigned short* xp = Xt + ((size_t)(b << 12) + s0 + wv * 32) * 320 + lg * 8;

#pragma unroll
    for (int kc = 0; kc < 10; ++kc) {
        int ko = kc * 32;
        bf16x8 a[4], x[2];
#pragma unroll
        for (int mi = 0; mi < 4; ++mi)
            a[mi] = *(const bf16x8*)(wp + (size_t)(mi * 16 + lr) * 320 + ko);
#pragma unroll
        for (int ni = 0; ni < 2; ++ni)
            x[ni] = *(const bf16x8*)(xp + (size_t)(ni * 16 + lr) * 320 + ko);
#pragma unroll
        for (int mi = 0; mi < 4; ++mi)
#pragma unroll
            for (int ni = 0; ni < 2; ++ni)
                acc[mi][ni] = __builtin_amdgcn_mfma_f32_16x16x32_bf16(
                    a[mi], x[ni], acc[mi][ni], 0, 0, 0);
    }
#pragma unroll
    for (int mi = 0; mi < 4; ++mi)
#pragma unroll
    for (int ni = 0; ni < 2; ++ni)
#pragma unroll
    for (int r = 0; r < 4; ++r) {
        int co = co0 + mi * 16 + lg * 4 + r;
        if (co >= 160) continue;
        int s = s0 + wv * 32 + ni * 16 + lr;
        float bias = (co < 16) ? qb[co] : ((co < 32) ? kb[co - 16] : vb[co - 32]);
        float v = acc[mi][ni][r] + bias;
        if (co < 16)      qbt[((size_t)(b << 12) + s) * 16 + co] = f2b(v);
        else if (co < 32) kbt[((size_t)(b << 12) + s) * 16 + (co - 16)] = f2b(v);
        else              vbt[((size_t)((b << 7) + (co - 32)) << 12) + s] = f2b(v);
    }
}

// ===== attention partial: MFMA QK^T + in-register softmax (swapped operands) =====
__global__ __launch_bounds__(256) void attn_part2(
    const unsigned short* __restrict__ qbt, const unsigned short* __restrict__ kbt,
    const unsigned short* __restrict__ vbt,
    float* __restrict__ pacc, float* __restrict__ pml)
{
    const int bx = blockIdx.x;
    const int b = bx >> 8;
    const int qt = (bx >> 2) & 63;
    const int seg = bx & 3;
    const int q0 = qt << 6;
    const int nch = (qt >> 1) + 1;
    const int c_lo = seg << 3;
    if (c_lo >= nch) return;
    const int c_hi = min(c_lo + 8, nch);

    __shared__ unsigned short sK[128 * 16];
    __shared__ unsigned short sP[4][16 * 136];

    const int tid = threadIdx.x;
    const int lane = tid & 63, wv = tid >> 6;
    const int lr = lane & 15, lg = lane >> 4;
    const int qa = q0 + wv * 16 + lr;
    const float scale = 1.0f / sqrtf(259.0f);

    bf16x8 qf = (bf16x8){0, 0, 0, 0, 0, 0, 0, 0};
    if (lg < 2)
        qf = *(const bf16x8*)(qbt + ((size_t)(b << 12) + qa) * 16 + lg * 8);

    f32x4 oacc[8];
#pragma unroll
    for (int vct = 0; vct < 8; ++vct) oacc[vct] = (f32x4){0.f, 0.f, 0.f, 0.f};
    float m = -1e30f, l = 0.0f;

    unsigned short* myP = &sP[wv][0];

    for (int kc = c_lo; kc < c_hi; ++kc) {
        const int kv0 = kc << 7;
        __syncthreads();
        *(bf16x8*)&sK[(tid >> 1) * 16 + (tid & 1) * 8] =
            *(const bf16x8*)(kbt + ((size_t)(b << 12) + kv0 + (tid >> 1)) * 16 + (tid & 1) * 8);
        __syncthreads();

        f32x4 sc[8];
#pragma unroll
        for (int kvt = 0; kvt < 8; ++kvt) {
            bf16x8 af = (bf16x8){0, 0, 0, 0, 0, 0, 0, 0};
            if (lg < 2)
                af = *(const bf16x8*)&sK[(kvt * 16 + lr) * 16 + lg * 8];
            sc[kvt] = __builtin_amdgcn_mfma_f32_16x16x32_bf16(
                af, qf, (f32x4){0.f, 0.f, 0.f, 0.f}, 0, 0, 0);
        }
        float mc = -1e30f;
#pragma unroll
        for (int kvt = 0; kvt < 8; ++kvt) {
#pragma unroll
            for (int r = 0; r < 4; ++r) {
                int kv = kv0 + kvt * 16 + lg * 4 + r;
                float s = (kv < qa) ? sc[kvt][r] * scale : -1e30f;
                sc[kvt][r] = s;
                mc = fmaxf(mc, s);
            }
        }
        mc = fmaxf(mc, __shfl_xor(mc, 16, 64));
        mc = fmaxf(mc, __shfl_xor(mc, 32, 64));
        float mn = fmaxf(m, mc);
        float fac = __expf(m - mn);
        float ls = 0.0f;
#pragma unroll
        for (int kvt = 0; kvt < 8; ++kvt) {
#pragma unroll
            for (int e = 0; e < 2; ++e) {
                float s0v = sc[kvt][2 * e];
                float s1v = sc[kvt][2 * e + 1];
                float p0 = (s0v <= -1e29f) ? 0.f : __expf(s0v - mn);
                float p1 = (s1v <= -1e29f) ? 0.f : __expf(s1v - mn);
                ls += p0 + p1;
                unsigned int pk = (unsigned int)f2b(p0) | ((unsigned int)f2b(p1) << 16);
                int kv = kvt * 16 + lg * 4 + 2 * e;
                *(unsigned int*)&myP[lr * 136 + kv] = pk;
            }
        }
        ls += __shfl_xor(ls, 16, 64);
        ls += __shfl_xor(ls, 32, 64);
        l = l * fac + ls;
        m = mn;
#pragma unroll
        for (int vct = 0; vct < 8; ++vct) {
            oacc[vct][0] *= fac; oacc[vct][1] *= fac;
            oacc[vct][2] *= fac; oacc[vct][3] *= fac;
        }
#pragma unroll
        for (int ks = 0; ks < 4; ++ks) {
            bf16x8 pf = *(const bf16x8*)&myP[lr * 136 + ks * 32 + lg * 8];
#pragma unroll
            for (int vct = 0; vct < 8; ++vct) {
                bf16x8 vf = *(const bf16x8*)(vbt +
                    ((size_t)((b << 7) + vct * 16 + lr) << 12) + kv0 + ks * 32 + lg * 8);
                oacc[vct] = __builtin_amdgcn_mfma_f32_16x16x32_bf16(
                    vf, pf, oacc[vct], 0, 0, 0);
            }
        }
    }

    const int a_ = qt >> 4;
    const int slot = b * 160 + 8 * a_ * (a_ + 1) + (qt & 15) * (a_ + 1) + seg;
    float* ap = pacc + (size_t)slot * 8192;
#pragma unroll
    for (int vct = 0; vct < 8; ++vct)
        *(f32x4*)&ap[(wv * 16 + lr) * 128 + vct * 16 + lg * 4] = oacc[vct];
    if (lg == 0) {
        pml[slot * 128 + (wv * 16 + lr) * 2]     = m;
        pml[slot * 128 + (wv * 16 + lr) * 2 + 1] = l;
    }
}

// ===== attention combine =====
__global__ __launch_bounds__(256) void attn_combine2(
    const float* __restrict__ pacc, const float* __restrict__ pml,
    unsigned short* __restrict__ attEb)
{
    const int bx = blockIdx.x;
    const int b = bx >> 7;
    const int qt = (bx >> 1) & 63;
    const int half = bx & 1;
    const int a_ = qt >> 4;
    const int nseg_alloc = a_ + 1;
    const int nch = (qt >> 1) + 1;
    const int nseg = (nch + 7) >> 3;
    const int base = b * 160 + 8 * a_ * (a_ + 1) + (qt & 15) * nseg_alloc;
    const int tid = threadIdx.x;
    const int qq = (tid >> 3) + half * 32;
    const int vg = tid & 7;

    float mi_[4], li_[4];
    float m = -1e30f;
    for (int i = 0; i < nseg; ++i) {
        mi_[i] = pml[(base + i) * 128 + qq * 2];
        li_[i] = pml[(base + i) * 128 + qq * 2 + 1];
        m = fmaxf(m, mi_[i]);
    }
    float w[4];
    float l = 0.f;
    for (int i = 0; i < nseg; ++i) {
        float wi = (mi_[i] <= -1e29f) ? 0.f : __expf(mi_[i] - m);
        w[i] = wi;
        l += wi * li_[i];
    }
    float inv = (l > 0.f) ? 1.f / l : 0.f;
    int q = (qt << 6) + qq;
#pragma unroll
    for (int v4 = 0; v4 < 4; ++v4) {
        int vc = vg * 16 + v4 * 4;
        float o0 = 0.f, o1 = 0.f, o2 = 0.f, o3 = 0.f;
        for (int i = 0; i < nseg; ++i) {
            f32x4 a = *(const f32x4*)(pacc + (size_t)(base + i) * 8192 + qq * 128 + vc);
            o0 = fmaf(w[i], a[0], o0);
            o1 = fmaf(w[i], a[1], o1);
            o2 = fmaf(w[i], a[2], o2);
            o3 = fmaf(w[i], a[3], o3);
        }
        unsigned short r0 = f2b(elu_f(o0 * inv));
        unsigned short r1 = f2b(elu_f(o1 * inv));
        unsigned short r2 = f2b(elu_f(o2 * inv));
        unsigned short r3 = f2b(elu_f(o3 * inv));
        ushort4 pk = {r0, r1, r2, r3};
        *(ushort4*)&attEb[((size_t)(b << 12) + q) * 128 + vc] = pk;
    }
}

// ===== final_ab GEMM: sum2b = bf16(elu( elu(W1@attEb+b1) + elu(W2@eluP+b2) )) =====
__global__ __launch_bounds__(256) void final_ab_gemm(
    const unsigned short* __restrict__ W1b, const unsigned short* __restrict__ W2b,
    const unsigned short* __restrict__ X1, const unsigned short* __restrict__ X2,
    const float* __restrict__ b1, const float* __restrict__ b2,
    unsigned short* __restrict__ sum2b)
{
    const int b = blockIdx.x >> 5;
    const int s0 = (blockIdx.x & 31) << 7;
    const int co0 = blockIdx.y << 6;
    const int lane = threadIdx.x & 63, wv = threadIdx.x >> 6;
    const int lr = lane & 15, lg = lane >> 4;

    f32x4 acc1[4][2], acc2[4][2];
#pragma unroll
    for (int mi = 0; mi < 4; ++mi)
#pragma unroll
        for (int ni = 0; ni < 2; ++ni) {
            acc1[mi][ni] = (f32x4){0.f, 0.f, 0.f, 0.f};
            acc2[mi][ni] = (f32x4){0.f, 0.f, 0.f, 0.f};
        }

    {
        const unsigned short* wp = W1b + (size_t)co0 * 128 + lg * 8;
        const unsigned short* xp = X1 + ((size_t)(b << 12) + s0 + wv * 32) * 128 + lg * 8;
#pragma unroll
        for (int kc = 0; kc < 4; ++kc) {
            int ko = kc * 32;
            bf16x8 a[4], x[2];
#pragma unroll
            for (int mi = 0; mi < 4; ++mi)
                a[mi] = *(const bf16x8*)(wp + (size_t)(mi * 16 + lr) * 128 + ko);
#pragma unroll
            for (int ni = 0; ni < 2; ++ni)
                x[ni] = *(const bf16x8*)(xp + (size_t)(ni * 16 + lr) * 128 + ko);
#pragma unroll
            for (int mi = 0; mi < 4; ++mi)
#pragma unroll
                for (int ni = 0; ni < 2; ++ni)
                    acc1[mi][ni] = __builtin_amdgcn_mfma_f32_16x16x32_bf16(
                        a[mi], x[ni], acc1[mi][ni], 0, 0, 0);
        }
    }
    {
        const unsigned short* wp = W2b + (size_t)co0 * 256 + lg * 8;
        const unsigned short* xp2[2];
#pragma unroll
        for (int ni = 0; ni < 2; ++ni) {
            int u = (s0 >> 4) + wv * 2 + ni;
            int tt = u >> 4, hh = u & 15;
            xp2[ni] = X2 + ((size_t)b * PROWS + (tt + 1) * PT + (hh + 1) * 17 + (lr + 1)) * 256 + lg * 8;
        }
#pragma unroll
        for (int kc = 0; kc < 8; ++kc) {
            int ko = kc * 32;
            bf16x8 a[4], x[2];
#pragma unroll
            for (int mi = 0; mi < 4; ++mi)
                a[mi] = *(const bf16x8*)(wp + (size_t)(mi * 16 + lr) * 256 + ko);
#pragma unroll
            for (int ni = 0; ni < 2; ++ni)
                x[ni] = *(const bf16x8*)(xp2[ni] + ko);
#pragma unroll
            for (int mi = 0; mi < 4; ++mi)
#pragma unroll
                for (int ni = 0; ni < 2; ++ni)
                    acc2[mi][ni] = __builtin_amdgcn_mfma_f32_16x16x32_bf16(
                        a[mi], x[ni], acc2[mi][ni], 0, 0, 0);
        }
    }
#pragma unroll
    for (int mi = 0; mi < 4; ++mi)
#pragma unroll
    for (int ni = 0; ni < 2; ++ni)
#pragma unroll
    for (int r = 0; r < 4; ++r) {
        int co = co0 + mi * 16 + lg * 4 + r;
        int s = s0 + wv * 32 + ni * 16 + lr;
        float v1 = elu_f(acc1[mi][ni][r] + b1[co]);
        float v2 = elu_f(acc2[mi][ni][r] + b2[co]);
        sum2b[((size_t)(b << 12) + s) * 256 + co] = f2b(elu_f(v1 + v2));
    }
}

// ===== final_c GEMM: out = elu(outW@sum2b + out_b), fp32 [b][256][4096] =====
__global__ __launch_bounds__(256) void final_c_gemm(
    const unsigned short* __restrict__ Wb, const unsigned short* __restrict__ Xt,
    const float* __restrict__ bias, float* __restrict__ out)
{
    const int b = blockIdx.x >> 5;
    const int s0 = (blockIdx.x & 31) << 7;
    const int co0 = blockIdx.y << 6;
    const int lane = threadIdx.x & 63, wv = threadIdx.x >> 6;
    const int lr = lane & 15, lg = lane >> 4;

    f32x4 acc[4][2];
#pragma unroll
    for (int mi = 0; mi < 4; ++mi)
#pragma unroll
        for (int ni = 0; ni < 2; ++ni) acc[mi][ni] = (f32x4){0.f, 0.f, 0.f, 0.f};

    const unsigned short* wp = Wb + (size_t)co0 * 256 + lg * 8;
    const unsigned short* xp = Xt + ((size_t)(b << 12) + s0 + wv * 32) * 256 + lg * 8;
#pragma unroll
    for (int kc = 0; kc < 8; ++kc) {
        int ko = kc * 32;
        bf16x8 a[4], x[2];
#pragma unroll
        for (int mi = 0; mi < 4; ++mi)
            a[mi] = *(const bf16x8*)(wp + (size_t)(mi * 16 + lr) * 256 + ko);
#pragma unroll
        for (int ni = 0; ni < 2; ++ni)
            x[ni] = *(const bf16x8*)(xp + (size_t)(ni * 16 + lr) * 256 + ko);
#pragma unroll
        for (int mi = 0; mi < 4; ++mi)
#pragma unroll
            for (int ni = 0; ni < 2; ++ni)
                acc[mi][ni] = __builtin_amdgcn_mfma_f32_16x16x32_bf16(
                    a[mi], x[ni], acc[mi][ni], 0, 0, 0);
    }
#pragma unroll
    for (int mi = 0; mi < 4; ++mi)
#pragma unroll
    for (int ni = 0; ni < 2; ++ni)
#pragma unroll
    for (int r = 0; r < 4; ++r) {
        int co = co0 + mi * 16 + lg * 4 + r;
        int s = s0 + wv * 32 + ni * 16 + lr;
        out[((size_t)(b * 256 + co) << 12) + s] = elu_f(acc[mi][ni][r] + bias[co]);
    }
}

extern "C" void kernel_launch(void* const* d_in, const int* in_sizes, int n_in,
                              void* d_out, int out_size, void* d_ws, size_t ws_size,
                              hipStream_t stream) {
    const float* x      = (const float*)d_in[0];
    const float* orig   = (const float*)d_in[1];
    const float* rb_w1  = (const float*)d_in[2];
    const float* rb_b1  = (const float*)d_in[3];
    const float* rb_w2  = (const float*)d_in[4];
    const float* rb_b2  = (const float*)d_in[5];
    const float* q_w    = (const float*)d_in[6];
    const float* q_b    = (const float*)d_in[7];
    const float* k_w    = (const float*)d_in[8];
    const float* k_b    = (const float*)d_in[9];
    const float* v_w    = (const float*)d_in[10];
    const float* v_b    = (const float*)d_in[11];
    const float* attn_w = (const float*)d_in[12];
    const float* attn_b = (const float*)d_in[13];
    const float* resc_w = (const float*)d_in[14];
    const float* resc_b = (const float*)d_in[15];
    const float* out_w  = (const float*)d_in[16];
    const float* out_b  = (const float*)d_in[17];
    float* out = (float*)d_out;

    char* base = (char*)d_ws;
    // layout (bytes):
    float*          res   = (float*)(base);                          // 0..8MB  [b][c][s] fp32
    unsigned short* elubP = (unsigned short*)(base + (8u << 20));    // 8..13MB  padded [b][4913][256]
    unsigned short* o1P   = (unsigned short*)(base + (13u << 20));   // 13..18MB padded
    unsigned short* w1t   = (unsigned short*)(base + (18u << 20));   // 18..22MB
    unsigned short* w2t   = (unsigned short*)(base + (22u << 20));   // 22..30MB
    // aliases after conv loop:
    unsigned short* vbt   = o1P;                                     // 2MB @13MB
    unsigned short* attEb = (unsigned short*)(base + (15u << 20));   // 2MB @15MB
    unsigned short* sum2b = w1t;                                     // 4MB @18MB
    unsigned short* xqkvB = w2t;                                     // 5MB @22MB (dead after qkv_gemm)
    float*          pacc  = (float*)(base + (22u << 20));            // 10MB @22MB (alias over xqkvB)
    unsigned short* qbt   = (unsigned short*)(base + (32u << 20));            // 256KB
    unsigned short* kbt   = (unsigned short*)(base + (32u << 20) + 262144);   // 256KB
    unsigned short* wqkvB = (unsigned short*)(base + (32u << 20) + 524288);   // 120KB
    unsigned short* attnWb= (unsigned short*)(base + (32u << 20) + 655360);   // 64KB
    unsigned short* rescWb= (unsigned short*)(base + (32u << 20) + 720896);   // 128KB
    unsigned short* outWb = (unsigned short*)(base + (32u << 20) + 851968);   // 128KB
    float*          pml   = (float*)(base + (32u << 20) + 983040);           // 160KB

    const int nz = (2 * PROWS * 256 * 2) / 16;   // uint4 count per padded buffer
    zero2_kernel<<<(nz + 255) / 256, 256, 0, stream>>>(
        (uint4*)elubP, (uint4*)o1P, nz);

    hipMemcpyAsync(res, x, (size_t)2097152 * sizeof(float),
                   hipMemcpyDeviceToDevice, stream);
    prep_t<<<dim3(64, 8), 256, 0, stream>>>(x, elubP);
    wcvt_kernel<<<16384, 256, 0, stream>>>(rb_w1, rb_w2, w1t, w2t);

    for (int i = 0; i < 4; ++i) {
        conv1_mfma<<<dim3(64, 8), 128, 0, stream>>>(
            elubP, w1t + (size_t)i * 524288, rb_b1 + i * 256, o1P);
        conv2_mfma<<<dim3(64, 16), 128, 0, stream>>>(
            o1P, w2t + (size_t)i * 1048576, rb_b2 + i * 512, res, elubP);
    }

    pack_kernel<<<dim3(64, 10), 256, 0, stream>>>(res, orig, xqkvB);
    wcvt2_kernel<<<880, 256, 0, stream>>>(q_w, k_w, v_w, attn_w, resc_w, out_w,
                                          wqkvB, attnWb, rescWb, outWb);

    qkv_gemm<<<dim3(64, 3), 256, 0, stream>>>(wqkvB, xqkvB, q_b, k_b, v_b,
                                              qbt, kbt, vbt);

    attn_part2<<<512, 256, 0, stream>>>(qbt, kbt, vbt, pacc, pml);
    attn_combine2<<<256, 256, 0, stream>>>(pacc, pml, attEb);

    final_ab_gemm<<<dim3(64, 4), 256, 0, stream>>>(
        attnWb, rescWb, attEb, elubP, attn_b, resc_b, sum2b);

    final_c_gemm<<<dim3(64, 4), 256, 0, stream>>>(outWb, sum2b, out_b, out);
}

// Round 10
// 424.025 us; speedup vs baseline: 11.2402x; 1.6563x over previous
//
#include <hip/hip_runtime.h>
#include <math.h>

#define SEQ 4096
#define CIN 256
#define PROWS 4913   // 17*17*17 padded spatial rows
#define PT 289       // 17*17
#define LROW 40      // ushorts per LDS row (80 B)
#define NROWS 170    // 2*5*17 halo rows per 64-pos tile

typedef __attribute__((ext_vector_type(8))) short bf16x8;
typedef __attribute__((ext_vector_type(4))) float f32x4;

__device__ __forceinline__ float elu_f(float x) {
    return x > 0.0f ? x : (expf(x) - 1.0f);
}
__device__ __forceinline__ unsigned short f2b(float f) {
    unsigned int u = __float_as_uint(f);
    return (unsigned short)((u + 0x7FFFu + ((u >> 16) & 1u)) >> 16);
}

// ===== zero2: clear both padded activation buffers (halo must be 0) =====
__global__ __launch_bounds__(256) void zero2_kernel(
    uint4* __restrict__ p1, uint4* __restrict__ p2, int n)
{
    int i = blockIdx.x * 256 + threadIdx.x;
    if (i < n) {
        p1[i] = (uint4){0, 0, 0, 0};
        p2[i] = (uint4){0, 0, 0, 0};
    }
}

// ===== prep_t: elubP[b][padded pos][256] = bf16(elu(x)) =====
__global__ __launch_bounds__(256) void prep_t(
    const float* __restrict__ x, unsigned short* __restrict__ elub)
{
    const int b = blockIdx.x >> 5;
    const int s0 = (blockIdx.x & 31) << 7;
    const int cg = blockIdx.y;
    const int tid = threadIdx.x;
    const int s = s0 + (tid & 127);
    const int c0 = cg * 32 + (tid >> 7) * 16;
    const int tt = s >> 8, hh = (s >> 4) & 15, ww = s & 15;
    const size_t prow = (size_t)b * PROWS + (tt + 1) * PT + (hh + 1) * 17 + (ww + 1);
    unsigned short ev[16];
#pragma unroll
    for (int cc = 0; cc < 16; ++cc) {
        float v = x[(((size_t)(b * 256 + c0 + cc)) << 12) + s];
        ev[cc] = f2b(elu_f(v));
    }
    unsigned short* ep = &elub[prow * 256 + c0];
    *(ushort4*)(ep)      = *(ushort4*)&ev[0];
    *(ushort4*)(ep + 4)  = *(ushort4*)&ev[4];
    *(ushort4*)(ep + 8)  = *(ushort4*)&ev[8];
    *(ushort4*)(ep + 12) = *(ushort4*)&ev[12];
}

// ===== wcvt: conv weights -> bf16 in MFMA FRAGMENT order =====
// w1t: frag = (tap*8+kc)*16 + mt ; element: lane l, e -> co = mt*16+(l&15),
//      ci = kc*32+(l>>4)*8+e. 1 KB per fragment, contiguous.
// w2t: frag = (tap*8+kc)*32 + mt ; W-row r' = mt*16+(l&15) pair-permuted.
__global__ __launch_bounds__(256) void wcvt_kernel(
    const float* __restrict__ w1, const float* __restrict__ w2,
    unsigned short* __restrict__ w1t, unsigned short* __restrict__ w2t)
{
    int idx = blockIdx.x * 256 + threadIdx.x;
    if (idx < 2097152) {
        int layer = idx >> 19;
        int rem = idx & 0x7FFFF;
        int frag = rem >> 9;
        int l = (rem >> 3) & 63;
        int e = rem & 7;
        int ks = frag >> 4, mt = frag & 15;
        int tap = ks >> 3, kc = ks & 7;
        int co = mt * 16 + (l & 15);
        int ci = kc * 32 + (l >> 4) * 8 + e;
        w1t[idx] = f2b(w1[(((size_t)(layer * 256 + co)) * 256 + ci) * 8 + tap]);
    }
    if (idx < 4194304) {
        int layer = idx >> 20;
        int rem = idx & 0xFFFFF;
        int frag = rem >> 9;
        int l = (rem >> 3) & 63;
        int e = rem & 7;
        int ks = frag >> 5, mt = frag & 31;
        int tap = ks >> 3, kc = ks & 7;
        int rp = mt * 16 + (l & 15);
        int grp = rp >> 5, sub = rp & 31;
        int co = (sub < 16) ? (grp * 16 + sub) : (256 + grp * 16 + (sub - 16));
        int ci = kc * 32 + (l >> 4) * 8 + e;
        w2t[idx] = f2b(w2[(((size_t)(layer * 512 + co)) * 256 + ci) * 8 + tap]);
    }
}

// ===== conv1: LDS-staged tap-GEMM. block 256thr = 64co x 64pos (4 waves, 1 h-row each) =====
__global__ __launch_bounds__(256) void conv1_mfma(
    const unsigned short* __restrict__ inP,    // [b][4913][256] padded
    const unsigned short* __restrict__ wfrag,  // fragment-order weights
    const float* __restrict__ bias,
    unsigned short* __restrict__ outP)         // [b][4913][256] padded
{
    __shared__ unsigned short sX[NROWS * LROW];   // 13.6 KB

    const int bx = blockIdx.x;
    const int b = bx >> 6, ptile = bx & 63;
    const int t = ptile >> 2, h0 = (ptile & 3) << 2;
    const int mt0 = blockIdx.y << 2;
    const int tid = threadIdx.x;
    const int lane = tid & 63, wv = tid >> 6;
    const int lr = lane & 15, lg = lane >> 4;

    const unsigned short* inB = inP + (size_t)b * PROWS * 256;

    f32x4 acc[4];
#pragma unroll
    for (int mi = 0; mi < 4; ++mi) acc[mi] = (f32x4){0.f, 0.f, 0.f, 0.f};

    for (int kc = 0; kc < 8; ++kc) {
        const int ci0 = kc << 5;
        __syncthreads();
#pragma unroll
        for (int rnd = 0; rnd < 3; ++rnd) {
            int task = tid + (rnd << 8);
            int row = task >> 2, q = task & 3;
            if (row < NROWS) {
                int dt = row / 85, rem = row - dt * 85;
                int dh = rem / 17, dw = rem - dh * 17;
                int prow = (t + dt) * PT + (h0 + dh) * 17 + dw;
                *(bf16x8*)&sX[row * LROW + (q << 3)] =
                    *(const bf16x8*)(inB + (size_t)prow * 256 + ci0 + (q << 3));
            }
        }
        __syncthreads();
#pragma unroll
        for (int tap = 0; tap < 8; ++tap) {
            const unsigned short* wp = wfrag +
                ((size_t)((((tap << 3) + kc) << 4) + mt0) << 9) + (lane << 3);
            bf16x8 a0 = *(const bf16x8*)(wp);
            bf16x8 a1 = *(const bf16x8*)(wp + 512);
            bf16x8 a2 = *(const bf16x8*)(wp + 1024);
            bf16x8 a3 = *(const bf16x8*)(wp + 1536);
            const int rb = (tap >> 2) * 85 + (wv + ((tap >> 1) & 1)) * 17 + (tap & 1);
            bf16x8 xb = *(const bf16x8*)&sX[(rb + lr) * LROW + (lg << 3)];
            acc[0] = __builtin_amdgcn_mfma_f32_16x16x32_bf16(a0, xb, acc[0], 0, 0, 0);
            acc[1] = __builtin_amdgcn_mfma_f32_16x16x32_bf16(a1, xb, acc[1], 0, 0, 0);
            acc[2] = __builtin_amdgcn_mfma_f32_16x16x32_bf16(a2, xb, acc[2], 0, 0, 0);
            acc[3] = __builtin_amdgcn_mfma_f32_16x16x32_bf16(a3, xb, acc[3], 0, 0, 0);
        }
    }
    const size_t orow = (size_t)b * PROWS + (t + 1) * PT + (h0 + wv + 1) * 17 + (lr + 1);
#pragma unroll
    for (int mi = 0; mi < 4; ++mi) {
        const int cob = ((mt0 + mi) << 4) + (lg << 2);
        unsigned short v4[4];
#pragma unroll
        for (int r = 0; r < 4; ++r)
            v4[r] = f2b(elu_f(acc[mi][r] + bias[cob + r]));
        *(ushort4*)&outP[orow * 256 + cob] = *(ushort4*)v4;
    }
}

// ===== conv2: LDS-staged tap-GEMM + gate. block 256thr = 64 W-rows x 64pos =====
__global__ __launch_bounds__(256) void conv2_mfma(
    const unsigned short* __restrict__ inP,    // o1P padded
    const unsigned short* __restrict__ wfrag,  // fragment-order, pair-permuted
    const float* __restrict__ bias,            // [512]
    float* __restrict__ resf,                  // [b][256][4096]
    unsigned short* __restrict__ elub)         // padded [b][4913][256]
{
    __shared__ unsigned short sX[NROWS * LROW];

    const int bx = blockIdx.x;
    const int b = bx >> 6, ptile = bx & 63;
    const int t = ptile >> 2, h0 = (ptile & 3) << 2;
    const int mt0 = blockIdx.y << 2;
    const int tid = threadIdx.x;
    const int lane = tid & 63, wv = tid >> 6;
    const int lr = lane & 15, lg = lane >> 4;

    const unsigned short* inB = inP + (size_t)b * PROWS * 256;

    f32x4 acc[4];
#pragma unroll
    for (int mi = 0; mi < 4; ++mi) acc[mi] = (f32x4){0.f, 0.f, 0.f, 0.f};

    for (int kc = 0; kc < 8; ++kc) {
        const int ci0 = kc << 5;
        __syncthreads();
#pragma unroll
        for (int rnd = 0; rnd < 3; ++rnd) {
            int task = tid + (rnd << 8);
            int row = task >> 2, q = task & 3;
            if (row < NROWS) {
                int dt = row / 85, rem = row - dt * 85;
                int dh = rem / 17, dw = rem - dh * 17;
                int prow = (t + dt) * PT + (h0 + dh) * 17 + dw;
                *(bf16x8*)&sX[row * LROW + (q << 3)] =
                    *(const bf16x8*)(inB + (size_t)prow * 256 + ci0 + (q << 3));
            }
        }
        __syncthreads();
#pragma unroll
        for (int tap = 0; tap < 8; ++tap) {
            const unsigned short* wp = wfrag +
                ((size_t)((((tap << 3) + kc) << 5) + mt0) << 9) + (lane << 3);
            bf16x8 a0 = *(const bf16x8*)(wp);
            bf16x8 a1 = *(const bf16x8*)(wp + 512);
            bf16x8 a2 = *(const bf16x8*)(wp + 1024);
            bf16x8 a3 = *(const bf16x8*)(wp + 1536);
            const int rb = (tap >> 2) * 85 + (wv + ((tap >> 1) & 1)) * 17 + (tap & 1);
            bf16x8 xb = *(const bf16x8*)&sX[(rb + lr) * LROW + (lg << 3)];
            acc[0] = __builtin_amdgcn_mfma_f32_16x16x32_bf16(a0, xb, acc[0], 0, 0, 0);
            acc[1] = __builtin_amdgcn_mfma_f32_16x16x32_bf16(a1, xb, acc[1], 0, 0, 0);
            acc[2] = __builtin_amdgcn_mfma_f32_16x16x32_bf16(a2, xb, acc[2], 0, 0, 0);
            acc[3] = __builtin_amdgcn_mfma_f32_16x16x32_bf16(a3, xb, acc[3], 0, 0, 0);
        }
    }
    // epilogue: tiles (2p, 2p+1) = (a, g) for channels (mt0/2 + p)*16 + lg*4 + r
    const int s = (t << 8) + ((h0 + wv) << 4) + lr;
    const size_t prow = (size_t)b * PROWS + (t + 1) * PT + (h0 + wv + 1) * 17 + (lr + 1);
#pragma unroll
    for (int p = 0; p < 2; ++p) {
        const int chb = (((mt0 >> 1) + p) << 4) + (lg << 2);
        unsigned short e4[4];
#pragma unroll
        for (int r = 0; r < 4; ++r) {
            const int ch = chb + r;
            float av = acc[2 * p][r] + bias[ch];
            float gv = acc[2 * p + 1][r] + bias[ch + 256];
            float add = av / (1.0f + expf(-gv));
            size_t ridx = (((size_t)(b * 256 + ch)) << 12) + s;
            float rn = resf[ridx] + add;
            resf[ridx] = rn;
            e4[r] = f2b(elu_f(rn));
        }
        *(ushort4*)&elub[prow * 256 + chb] = *(ushort4*)e4;
    }
}

// ===== pack: xq[b][s][320] = bf16(res | orig | pos | 0) =====
__global__ __launch_bounds__(256) void pack_kernel(
    const float* __restrict__ res, const float* __restrict__ orig,
    unsigned short* __restrict__ xq)
{
    const int b = blockIdx.x >> 5;
    const int s0 = (blockIdx.x & 31) << 7;
    const int cg = blockIdx.y;
    const int tid = threadIdx.x;
    const int s = s0 + (tid & 127);
    const int c0 = cg * 32 + (tid >> 7) * 16;

    unsigned short xv[16];
    if (cg < 8) {
#pragma unroll
        for (int cc = 0; cc < 16; ++cc) {
            int c = c0 + cc;
            float v = res[(size_t)((b * 256 + c) << 12) + s];
            xv[cc] = f2b(v);
        }
    } else if (cg == 8) {
#pragma unroll
        for (int cc = 0; cc < 16; ++cc) {
            int c = c0 + cc;
            float v;
            if (c < 259)      v = orig[(size_t)((b * 3 + (c - 256)) << 12) + s];
            else if (c == 259) v = -0.5f + (float)(s >> 8) * 0.0625f;
            else if (c == 260) v = -0.5f + (float)((s >> 4) & 15) * 0.0625f;
            else if (c == 261) v = -0.5f + (float)(s & 15) * 0.0625f;
            else               v = 0.0f;
            xv[cc] = f2b(v);
        }
    } else {
#pragma unroll
        for (int cc = 0; cc < 16; ++cc) xv[cc] = 0;
    }
    unsigned short* xp = &xq[((size_t)(b << 12) + s) * 320 + c0];
    *(ushort4*)(xp)      = *(ushort4*)&xv[0];
    *(ushort4*)(xp + 4)  = *(ushort4*)&xv[4];
    *(ushort4*)(xp + 8)  = *(ushort4*)&xv[8];
    *(ushort4*)(xp + 12) = *(ushort4*)&xv[12];
}

// ===== wcvt2: pack qkv weights [192][320] (zero-pad) + attn/resc/out weights -> bf16 =====
__global__ __launch_bounds__(256) void wcvt2_kernel(
    const float* __restrict__ qw, const float* __restrict__ kw,
    const float* __restrict__ vw, const float* __restrict__ aw,
    const float* __restrict__ rw, const float* __restrict__ ow,
    unsigned short* __restrict__ wqkv, unsigned short* __restrict__ awb,
    unsigned short* __restrict__ rwb, unsigned short* __restrict__ owb)
{
    int idx = blockIdx.x * 256 + threadIdx.x;
    if (idx < 61440) {
        int r = idx / 320, c = idx - r * 320;
        float v = 0.0f;
        if (c < 262) {
            if (r < 16)       v = qw[r * 262 + c];
            else if (r < 32)  v = kw[(r - 16) * 262 + c];
            else if (r < 160) v = vw[(r - 32) * 262 + c];
        }
        wqkv[idx] = f2b(v);
    } else if (idx < 61440 + 32768) {
        int j = idx - 61440; awb[j] = f2b(aw[j]);
    } else if (idx < 61440 + 32768 + 65536) {
        int j = idx - 61440 - 32768; rwb[j] = f2b(rw[j]);
    } else if (idx < 61440 + 32768 + 131072) {
        int j = idx - 61440 - 98304; owb[j] = f2b(ow[j]);
    }
}

// ===== qkv GEMM: [192][320] @ [s][320]^T ; q,k -> bf16 [s][16]; v -> bf16 [vc][s] =====
__global__ __launch_bounds__(256) void qkv_gemm(
    const unsigned short* __restrict__ Wb, const unsigned short* __restrict__ Xt,
    const float* __restrict__ qb, const float* __restrict__ kb,
    const float* __restrict__ vb,
    unsigned short* __restrict__ qbt, unsigned short* __restrict__ kbt,
    unsigned short* __restrict__ vbt)
{
    const int b = blockIdx.x >> 5;
    const int s0 = (blockIdx.x & 31) << 7;
    const int co0 = blockIdx.y << 6;
    const int lane = threadIdx.x & 63, wv = threadIdx.x >> 6;
    const int lr = lane & 15, lg = lane >> 4;

    f32x4 acc[4][2];
#pragma unroll
    for (int mi = 0; mi < 4; ++mi)
#pragma unroll
        for (int ni = 0; ni < 2; ++ni) acc[mi][ni] = (f32x4){0.f, 0.f, 0.f, 0.f};

    const unsigned short* wp = Wb + (size_t)co0 * 320 + lg * 8;
    const unsigned short* xp = Xt + ((size_t)(b << 12) + s0 + wv * 32) * 320 + lg * 8;

#pragma unroll
    for (int kc = 0; kc < 10; ++kc) {
        int ko = kc * 32;
        bf16x8 a[4], x[2];
#pragma unroll
        for (int mi = 0; mi < 4; ++mi)
            a[mi] = *(const bf16x8*)(wp + (size_t)(mi * 16 + lr) * 320 + ko);
#pragma unroll
        for (int ni = 0; ni < 2; ++ni)
            x[ni] = *(const bf16x8*)(xp + (size_t)(ni * 16 + lr) * 320 + ko);
#pragma unroll
        for (int mi = 0; mi < 4; ++mi)
#pragma unroll
            for (int ni = 0; ni < 2; ++ni)
                acc[mi][ni] = __builtin_amdgcn_mfma_f32_16x16x32_bf16(
                    a[mi], x[ni], acc[mi][ni], 0, 0, 0);
    }
#pragma unroll
    for (int mi = 0; mi < 4; ++mi)
#pragma unroll
    for (int ni = 0; ni < 2; ++ni)
#pragma unroll
    for (int r = 0; r < 4; ++r) {
        int co = co0 + mi * 16 + lg * 4 + r;
        if (co >= 160) continue;
        int s = s0 + wv * 32 + ni * 16 + lr;
        float bias = (co < 16) ? qb[co] : ((co < 32) ? kb[co - 16] : vb[co - 32]);
        float v = acc[mi][ni][r] + bias;
        if (co < 16)      qbt[((size_t)(b << 12) + s) * 16 + co] = f2b(v);
        else if (co < 32) kbt[((size_t)(b << 12) + s) * 16 + (co - 16)] = f2b(v);
        else              vbt[((size_t)((b << 7) + (co - 32)) << 12) + s] = f2b(v);
    }
}

// ===== attention partial: MFMA QK^T + in-register softmax (swapped operands) =====
__global__ __launch_bounds__(256) void attn_part2(
    const unsigned short* __restrict__ qbt, const unsigned short* __restrict__ kbt,
    const unsigned short* __restrict__ vbt,
    float* __restrict__ pacc, float* __restrict__ pml)
{
    const int bx = blockIdx.x;
    const int b = bx >> 8;
    const int qt = (bx >> 2) & 63;
    const int seg = bx & 3;
    const int q0 = qt << 6;
    const int nch = (qt >> 1) + 1;
    const int c_lo = seg << 3;
    if (c_lo >= nch) return;
    const int c_hi = min(c_lo + 8, nch);

    __shared__ unsigned short sK[128 * 16];
    __shared__ unsigned short sP[4][16 * 136];

    const int tid = threadIdx.x;
    const int lane = tid & 63, wv = tid >> 6;
    const int lr = lane & 15, lg = lane >> 4;
    const int qa = q0 + wv * 16 + lr;
    const float scale = 1.0f / sqrtf(259.0f);

    bf16x8 qf = (bf16x8){0, 0, 0, 0, 0, 0, 0, 0};
    if (lg < 2)
        qf = *(const bf16x8*)(qbt + ((size_t)(b << 12) + qa) * 16 + lg * 8);

    f32x4 oacc[8];
#pragma unroll
    for (int vct = 0; vct < 8; ++vct) oacc[vct] = (f32x4){0.f, 0.f, 0.f, 0.f};
    float m = -1e30f, l = 0.0f;

    unsigned short* myP = &sP[wv][0];

    for (int kc = c_lo; kc < c_hi; ++kc) {
        const int kv0 = kc << 7;
        __syncthreads();
        *(bf16x8*)&sK[(tid >> 1) * 16 + (tid & 1) * 8] =
            *(const bf16x8*)(kbt + ((size_t)(b << 12) + kv0 + (tid >> 1)) * 16 + (tid & 1) * 8);
        __syncthreads();

        f32x4 sc[8];
#pragma unroll
        for (int kvt = 0; kvt < 8; ++kvt) {
            bf16x8 af = (bf16x8){0, 0, 0, 0, 0, 0, 0, 0};
            if (lg < 2)
                af = *(const bf16x8*)&sK[(kvt * 16 + lr) * 16 + lg * 8];
            sc[kvt] = __builtin_amdgcn_mfma_f32_16x16x32_bf16(
                af, qf, (f32x4){0.f, 0.f, 0.f, 0.f}, 0, 0, 0);
        }
        float mc = -1e30f;
#pragma unroll
        for (int kvt = 0; kvt < 8; ++kvt) {
#pragma unroll
            for (int r = 0; r < 4; ++r) {
                int kv = kv0 + kvt * 16 + lg * 4 + r;
                float s = (kv < qa) ? sc[kvt][r] * scale : -1e30f;
                sc[kvt][r] = s;
                mc = fmaxf(mc, s);
            }
        }
        mc = fmaxf(mc, __shfl_xor(mc, 16, 64));
        mc = fmaxf(mc, __shfl_xor(mc, 32, 64));
        float mn = fmaxf(m, mc);
        float fac = __expf(m - mn);
        float ls = 0.0f;
#pragma unroll
        for (int kvt = 0; kvt < 8; ++kvt) {
#pragma unroll
            for (int e = 0; e < 2; ++e) {
                float s0v = sc[kvt][2 * e];
                float s1v = sc[kvt][2 * e + 1];
                float p0 = (s0v <= -1e29f) ? 0.f : __expf(s0v - mn);
                float p1 = (s1v <= -1e29f) ? 0.f : __expf(s1v - mn);
                ls += p0 + p1;
                unsigned int pk = (unsigned int)f2b(p0) | ((unsigned int)f2b(p1) << 16);
                int kv = kvt * 16 + lg * 4 + 2 * e;
                *(unsigned int*)&myP[lr * 136 + kv] = pk;
            }
        }
        ls += __shfl_xor(ls, 16, 64);
        ls += __shfl_xor(ls, 32, 64);
        l = l * fac + ls;
        m = mn;
#pragma unroll
        for (int vct = 0; vct < 8; ++vct) {
            oacc[vct][0] *= fac; oacc[vct][1] *= fac;
            oacc[vct][2] *= fac; oacc[vct][3] *= fac;
        }
#pragma unroll
        for (int ks = 0; ks < 4; ++ks) {
            bf16x8 pf = *(const bf16x8*)&myP[lr * 136 + ks * 32 + lg * 8];
#pragma unroll
            for (int vct = 0; vct < 8; ++vct) {
                bf16x8 vf = *(const bf16x8*)(vbt +
                    ((size_t)((b << 7) + vct * 16 + lr) << 12) + kv0 + ks * 32 + lg * 8);
                oacc[vct] = __builtin_amdgcn_mfma_f32_16x16x32_bf16(
                    vf, pf, oacc[vct], 0, 0, 0);
            }
        }
    }

    const int a_ = qt >> 4;
    const int slot = b * 160 + 8 * a_ * (a_ + 1) + (qt & 15) * (a_ + 1) + seg;
    float* ap = pacc + (size_t)slot * 8192;
#pragma unroll
    for (int vct = 0; vct < 8; ++vct)
        *(f32x4*)&ap[(wv * 16 + lr) * 128 + vct * 16 + lg * 4] = oacc[vct];
    if (lg == 0) {
        pml[slot * 128 + (wv * 16 + lr) * 2]     = m;
        pml[slot * 128 + (wv * 16 + lr) * 2 + 1] = l;
    }
}

// ===== attention combine =====
__global__ __launch_bounds__(256) void attn_combine2(
    const float* __restrict__ pacc, const float* __restrict__ pml,
    unsigned short* __restrict__ attEb)
{
    const int bx = blockIdx.x;
    const int b = bx >> 7;
    const int qt = (bx >> 1) & 63;
    const int half = bx & 1;
    const int a_ = qt >> 4;
    const int nseg_alloc = a_ + 1;
    const int nch = (qt >> 1) + 1;
    const int nseg = (nch + 7) >> 3;
    const int base = b * 160 + 8 * a_ * (a_ + 1) + (qt & 15) * nseg_alloc;
    const int tid = threadIdx.x;
    const int qq = (tid >> 3) + half * 32;
    const int vg = tid & 7;

    float mi_[4], li_[4];
    float m = -1e30f;
    for (int i = 0; i < nseg; ++i) {
        mi_[i] = pml[(base + i) * 128 + qq * 2];
        li_[i] = pml[(base + i) * 128 + qq * 2 + 1];
        m = fmaxf(m, mi_[i]);
    }
    float w[4];
    float l = 0.f;
    for (int i = 0; i < nseg; ++i) {
        float wi = (mi_[i] <= -1e29f) ? 0.f : __expf(mi_[i] - m);
        w[i] = wi;
        l += wi * li_[i];
    }
    float inv = (l > 0.f) ? 1.f / l : 0.f;
    int q = (qt << 6) + qq;
#pragma unroll
    for (int v4 = 0; v4 < 4; ++v4) {
        int vc = vg * 16 + v4 * 4;
        float o0 = 0.f, o1 = 0.f, o2 = 0.f, o3 = 0.f;
        for (int i = 0; i < nseg; ++i) {
            f32x4 a = *(const f32x4*)(pacc + (size_t)(base + i) * 8192 + qq * 128 + vc);
            o0 = fmaf(w[i], a[0], o0);
            o1 = fmaf(w[i], a[1], o1);
            o2 = fmaf(w[i], a[2], o2);
            o3 = fmaf(w[i], a[3], o3);
        }
        unsigned short r0 = f2b(elu_f(o0 * inv));
        unsigned short r1 = f2b(elu_f(o1 * inv));
        unsigned short r2 = f2b(elu_f(o2 * inv));
        unsigned short r3 = f2b(elu_f(o3 * inv));
        ushort4 pk = {r0, r1, r2, r3};
        *(ushort4*)&attEb[((size_t)(b << 12) + q) * 128 + vc] = pk;
    }
}

// ===== final_ab GEMM: sum2b = bf16(elu( elu(W1@attEb+b1) + elu(W2@eluP+b2) )) =====
__global__ __launch_bounds__(256) void final_ab_gemm(
    const unsigned short* __restrict__ W1b, const unsigned short* __restrict__ W2b,
    const unsigned short* __restrict__ X1, const unsigned short* __restrict__ X2,
    const float* __restrict__ b1, const float* __restrict__ b2,
    unsigned short* __restrict__ sum2b)
{
    const int b = blockIdx.x >> 5;
    const int s0 = (blockIdx.x & 31) << 7;
    const int co0 = blockIdx.y << 6;
    const int lane = threadIdx.x & 63, wv = threadIdx.x >> 6;
    const int lr = lane & 15, lg = lane >> 4;

    f32x4 acc1[4][2], acc2[4][2];
#pragma unroll
    for (int mi = 0; mi < 4; ++mi)
#pragma unroll
        for (int ni = 0; ni < 2; ++ni) {
            acc1[mi][ni] = (f32x4){0.f, 0.f, 0.f, 0.f};
            acc2[mi][ni] = (f32x4){0.f, 0.f, 0.f, 0.f};
        }

    {
        const unsigned short* wp = W1b + (size_t)co0 * 128 + lg * 8;
        const unsigned short* xp = X1 + ((size_t)(b << 12) + s0 + wv * 32) * 128 + lg * 8;
#pragma unroll
        for (int kc = 0; kc < 4; ++kc) {
            int ko = kc * 32;
            bf16x8 a[4], x[2];
#pragma unroll
            for (int mi = 0; mi < 4; ++mi)
                a[mi] = *(const bf16x8*)(wp + (size_t)(mi * 16 + lr) * 128 + ko);
#pragma unroll
            for (int ni = 0; ni < 2; ++ni)
                x[ni] = *(const bf16x8*)(xp + (size_t)(ni * 16 + lr) * 128 + ko);
#pragma unroll
            for (int mi = 0; mi < 4; ++mi)
#pragma unroll
                for (int ni = 0; ni < 2; ++ni)
                    acc1[mi][ni] = __builtin_amdgcn_mfma_f32_16x16x32_bf16(
                        a[mi], x[ni], acc1[mi][ni], 0, 0, 0);
        }
    }
    {
        const unsigned short* wp = W2b + (size_t)co0 * 256 + lg * 8;
        const unsigned short* xp2[2];
#pragma unroll
        for (int ni = 0; ni < 2; ++ni) {
            int u = (s0 >> 4) + wv * 2 + ni;
            int tt = u >> 4, hh = u & 15;
            xp2[ni] = X2 + ((size_t)b * PROWS + (tt + 1) * PT + (hh + 1) * 17 + (lr + 1)) * 256 + lg * 8;
        }
#pragma unroll
        for (int kc = 0; kc < 8; ++kc) {
            int ko = kc * 32;
            bf16x8 a[4], x[2];
#pragma unroll
            for (int mi = 0; mi < 4; ++mi)
                a[mi] = *(const bf16x8*)(wp + (size_t)(mi * 16 + lr) * 256 + ko);
#pragma unroll
            for (int ni = 0; ni < 2; ++ni)
                x[ni] = *(const bf16x8*)(xp2[ni] + ko);
#pragma unroll
            for (int mi = 0; mi < 4; ++mi)
#pragma unroll
                for (int ni = 0; ni < 2; ++ni)
                    acc2[mi][ni] = __builtin_amdgcn_mfma_f32_16x16x32_bf16(
                        a[mi], x[ni], acc2[mi][ni], 0, 0, 0);
        }
    }
#pragma unroll
    for (int mi = 0; mi < 4; ++mi)
#pragma unroll
    for (int ni = 0; ni < 2; ++ni)
#pragma unroll
    for (int r = 0; r < 4; ++r) {
        int co = co0 + mi * 16 + lg * 4 + r;
        int s = s0 + wv * 32 + ni * 16 + lr;
        float v1 = elu_f(acc1[mi][ni][r] + b1[co]);
        float v2 = elu_f(acc2[mi][ni][r] + b2[co]);
        sum2b[((size_t)(b << 12) + s) * 256 + co] = f2b(elu_f(v1 + v2));
    }
}

// ===== final_c GEMM: out = elu(outW@sum2b + out_b), fp32 [b][256][4096] =====
__global__ __launch_bounds__(256) void final_c_gemm(
    const unsigned short* __restrict__ Wb, const unsigned short* __restrict__ Xt,
    const float* __restrict__ bias, float* __restrict__ out)
{
    const int b = blockIdx.x >> 5;
    const int s0 = (blockIdx.x & 31) << 7;
    const int co0 = blockIdx.y << 6;
    const int lane = threadIdx.x & 63, wv = threadIdx.x >> 6;
    const int lr = lane & 15, lg = lane >> 4;

    f32x4 acc[4][2];
#pragma unroll
    for (int mi = 0; mi < 4; ++mi)
#pragma unroll
        for (int ni = 0; ni < 2; ++ni) acc[mi][ni] = (f32x4){0.f, 0.f, 0.f, 0.f};

    const unsigned short* wp = Wb + (size_t)co0 * 256 + lg * 8;
    const unsigned short* xp = Xt + ((size_t)(b << 12) + s0 + wv * 32) * 256 + lg * 8;
#pragma unroll
    for (int kc = 0; kc < 8; ++kc) {
        int ko = kc * 32;
        bf16x8 a[4], x[2];
#pragma unroll
        for (int mi = 0; mi < 4; ++mi)
            a[mi] = *(const bf16x8*)(wp + (size_t)(mi * 16 + lr) * 256 + ko);
#pragma unroll
        for (int ni = 0; ni < 2; ++ni)
            x[ni] = *(const bf16x8*)(xp + (size_t)(ni * 16 + lr) * 256 + ko);
#pragma unroll
        for (int mi = 0; mi < 4; ++mi)
#pragma unroll
            for (int ni = 0; ni < 2; ++ni)
                acc[mi][ni] = __builtin_amdgcn_mfma_f32_16x16x32_bf16(
                    a[mi], x[ni], acc[mi][ni], 0, 0, 0);
    }
#pragma unroll
    for (int mi = 0; mi < 4; ++mi)
#pragma unroll
    for (int ni = 0; ni < 2; ++ni)
#pragma unroll
    for (int r = 0; r < 4; ++r) {
        int co = co0 + mi * 16 + lg * 4 + r;
        int s = s0 + wv * 32 + ni * 16 + lr;
        out[((size_t)(b * 256 + co) << 12) + s] = elu_f(acc[mi][ni][r] + bias[co]);
    }
}

extern "C" void kernel_launch(void* const* d_in, const int* in_sizes, int n_in,
                              void* d_out, int out_size, void* d_ws, size_t ws_size,
                              hipStream_t stream) {
    const float* x      = (const float*)d_in[0];
    const float* orig   = (const float*)d_in[1];
    const float* rb_w1  = (const float*)d_in[2];
    const float* rb_b1  = (const float*)d_in[3];
    const float* rb_w2  = (const float*)d_in[4];
    const float* rb_b2  = (const float*)d_in[5];
    const float* q_w    = (const float*)d_in[6];
    const float* q_b    = (const float*)d_in[7];
    const float* k_w    = (const float*)d_in[8];
    const float* k_b    = (const float*)d_in[9];
    const float* v_w    = (const float*)d_in[10];
    const float* v_b    = (const float*)d_in[11];
    const float* attn_w = (const float*)d_in[12];
    const float* attn_b = (const float*)d_in[13];
    const float* resc_w = (const float*)d_in[14];
    const float* resc_b = (const float*)d_in[15];
    const float* out_w  = (const float*)d_in[16];
    const float* out_b  = (const float*)d_in[17];
    float* out = (float*)d_out;

    char* base = (char*)d_ws;
    // layout (bytes):
    float*          res   = (float*)(base);                          // 0..8MB  [b][c][s] fp32
    unsigned short* elubP = (unsigned short*)(base + (8u << 20));    // 8..13MB  padded [b][4913][256]
    unsigned short* o1P   = (unsigned short*)(base + (13u << 20));   // 13..18MB padded
    unsigned short* w1t   = (unsigned short*)(base + (18u << 20));   // 18..22MB fragment-order
    unsigned short* w2t   = (unsigned short*)(base + (22u << 20));   // 22..30MB fragment-order
    // aliases after conv loop:
    unsigned short* vbt   = o1P;                                     // 2MB @13MB
    unsigned short* attEb = (unsigned short*)(base + (15u << 20));   // 2MB @15MB
    unsigned short* sum2b = w1t;                                     // 4MB @18MB
    unsigned short* xqkvB = w2t;                                     // 5MB @22MB (dead after qkv_gemm)
    float*          pacc  = (float*)(base + (22u << 20));            // 10MB @22MB (alias over xqkvB)
    unsigned short* qbt   = (unsigned short*)(base + (32u << 20));            // 256KB
    unsigned short* kbt   = (unsigned short*)(base + (32u << 20) + 262144);   // 256KB
    unsigned short* wqkvB = (unsigned short*)(base + (32u << 20) + 524288);   // 120KB
    unsigned short* attnWb= (unsigned short*)(base + (32u << 20) + 655360);   // 64KB
    unsigned short* rescWb= (unsigned short*)(base + (32u << 20) + 720896);   // 128KB
    unsigned short* outWb = (unsigned short*)(base + (32u << 20) + 851968);   // 128KB
    float*          pml   = (float*)(base + (32u << 20) + 983040);           // 160KB

    const int nz = (2 * PROWS * 256 * 2) / 16;   // uint4 count per padded buffer
    zero2_kernel<<<(nz + 255) / 256, 256, 0, stream>>>(
        (uint4*)elubP, (uint4*)o1P, nz);

    hipMemcpyAsync(res, x, (size_t)2097152 * sizeof(float),
                   hipMemcpyDeviceToDevice, stream);
    prep_t<<<dim3(64, 8), 256, 0, stream>>>(x, elubP);
    wcvt_kernel<<<16384, 256, 0, stream>>>(rb_w1, rb_w2, w1t, w2t);

    for (int i = 0; i < 4; ++i) {
        conv1_mfma<<<dim3(128, 4), 256, 0, stream>>>(
            elubP, w1t + (size_t)i * 524288, rb_b1 + i * 256, o1P);
        conv2_mfma<<<dim3(128, 8), 256, 0, stream>>>(
            o1P, w2t + (size_t)i * 1048576, rb_b2 + i * 512, res, elubP);
    }

    pack_kernel<<<dim3(64, 10), 256, 0, stream>>>(res, orig, xqkvB);
    wcvt2_kernel<<<880, 256, 0, stream>>>(q_w, k_w, v_w, attn_w, resc_w, out_w,
                                          wqkvB, attnWb, rescWb, outWb);

    qkv_gemm<<<dim3(64, 3), 256, 0, stream>>>(wqkvB, xqkvB, q_b, k_b, v_b,
                                              qbt, kbt, vbt);

    attn_part2<<<512, 256, 0, stream>>>(qbt, kbt, vbt, pacc, pml);
    attn_combine2<<<256, 256, 0, stream>>>(pacc, pml, attEb);

    final_ab_gemm<<<dim3(64, 4), 256, 0, stream>>>(
        attnWb, rescWb, attEb, elubP, attn_b, resc_b, sum2b);

    final_c_gemm<<<dim3(64, 4), 256, 0, stream>>>(outWb, sum2b, out_b, out);
}